// Round 2
// baseline (1089.602 us; speedup 1.0000x reference)
//
#include <hip/hip_runtime.h>
#include <math.h>

// ============================================================================
// DoubleJpeg round 9: convM latency fixes:
//  (1) A-fragment prefetch depth 2 (avn/avn2), taps 0-1 issued BEFORE staging
//      so L2 latency hides under stage+barrier; per-tap wait now covered by
//      ~155 MFMA-cycles of work (was 77 vs ~200cyc L2 latency -> stall).
//  (2) LDS XOR-swizzle (64B/px, was 80B padded): slot16 = px*4 + (q^s(px)),
//      s(px)=(px+(px>>2))&3. B-reads 2-way (free), staging writes uniform.
//      conv1b LDS 43520->34816 => 3->4 blocks/CU.
//  (3) conv3a NT=2, grid (4,64,4): 512->1024 blocks (was 2 blocks/CU).
// ============================================================================

typedef __attribute__((ext_vector_type(8))) _Float16 f16x8;
typedef __attribute__((ext_vector_type(4))) float f32x4;

#define GAMMA_F 1.0e6f

__device__ __forceinline__ unsigned short f2h(float f) {
  _Float16 h = (_Float16)f;
  union { _Float16 h; unsigned short u; } x; x.h = h; return x.u;
}
__device__ __forceinline__ float h2f(unsigned short u) {
  union { unsigned short u; _Float16 h; } x; x.u = u; return (float)x.h;
}

// ---------------------------------------------------------------- DCT kernel
__global__ __launch_bounds__(256) void k_dct(const float* __restrict__ x,
                                             const float* __restrict__ basis,
                                             float* __restrict__ xd) {
  __shared__ float bT[4096];
  __shared__ float pix[4][64];
  int tid = threadIdx.x;
  for (int e = tid; e < 4096; e += 256)
    bT[e] = basis[(e & 63) * 64 + (e >> 6)];
  __syncthreads();
  int w = tid >> 6, lane = tid & 63;
  int b = blockIdx.x >> 3;
  int br = ((blockIdx.x & 7) << 2) + w;
  const float* xb = x + (size_t)b * 65536;
  float* xdb = xd + (size_t)b * 65536;
  for (int bc = 0; bc < 32; ++bc) {
    __syncthreads();
    pix[w][lane] = xb[(br * 8 + (lane >> 3)) * 256 + bc * 8 + (lane & 7)];
    __syncthreads();
    float acc = 0.f;
#pragma unroll
    for (int p = 0; p < 64; ++p)
      acc = fmaf(bT[p * 64 + lane], pix[w][p], acc);
    xdb[lane * 1024 + br * 32 + bc] = acc;
  }
}

// ------------------------------- counting soft histogram (no atomics) -> feat
__global__ __launch_bounds__(256) void k_hist(const float* __restrict__ xd,
                                              float* __restrict__ feat) {
  __shared__ float px[1024];
  __shared__ float part[242];
  __shared__ float tot[121];
  int tid = threadIdx.x;
  int bc = blockIdx.x;
  int b = bc >> 6, c = bc & 63;
  const float* p = xd + (size_t)bc * 1024;
  for (int e = tid; e < 1024; e += 256) px[e] = p[e];
  __syncthreads();
  if (tid < 242) {
    int j = tid >> 1;
    float bj = (float)(j - 60);
    int i0 = (tid & 1) * 512;
    float cnt = 0.f;
    for (int i = i0; i < i0 + 512; ++i) {
      float d = px[i] - bj;
      float step = d > 0.f ? 1.f : 0.f;
      cnt += step;
      if (fabsf(d) < 2e-5f)
        cnt += 1.f / (1.f + expf(-GAMMA_F * d)) - step;
    }
    part[tid] = cnt;
  }
  __syncthreads();
  if (tid < 121) tot[tid] = part[2 * tid] + part[2 * tid + 1];
  __syncthreads();
  if (tid < 120)
    feat[((size_t)b * 120 + tid) * 64 + c] = (tot[tid] - tot[tid + 1]) * (1.f / 1024.f);
}

// --------------- weight prep: fp32 -> fp16, fragment-major layout
// out: wt[((t*(OC/16)+mt)*(IC/32)+icb)*512 + l15*32 + q*8 + j]
//    = w[oc=mt*16+l15][ic=icb*32+q*8+j][t]
__global__ __launch_bounds__(256) void k_prepw(const float* __restrict__ w,
                                               unsigned short* __restrict__ wt,
                                               int OC, int IC) {
  int n = OC * IC * 25;
  int idx = blockIdx.x * 256 + threadIdx.x;
  if (idx >= n) return;
  int j = idx & 7;
  int q = (idx >> 3) & 3;
  int l15 = (idx >> 5) & 15;
  int r = idx >> 9;
  int icb = r % (IC / 32);
  int r2 = r / (IC / 32);
  int mt = r2 % (OC / 16);
  int t = r2 / (OC / 16);
  int oc = mt * 16 + l15;
  int ic = icb * 32 + q * 8 + j;
  wt[idx] = f2h(w[((size_t)oc * IC + ic) * 25 + t]);
}

// ----------------------------------------------- conv1a (CIN=1), direct fp32
__global__ __launch_bounds__(256) void k_conv1a(const float* __restrict__ in,
                                                const float* __restrict__ wgt,
                                                unsigned short* __restrict__ out) {
  __shared__ float tile[20 * 21];
  int tx = threadIdx.x & 15, ty = threadIdx.x >> 4;
  int tileX = (blockIdx.x & 3) * 16, tileY = (blockIdx.x >> 2) * 16;
  int b = blockIdx.y, ocb = blockIdx.z * 8;
  const float* inc = in + (size_t)b * 7680;
  for (int e = threadIdx.x; e < 400; e += 256) {
    int ly = e / 20, lx = e % 20;
    int gy = tileY - 2 + ly, gx = tileX - 2 + lx;
    float v = 0.f;
    if ((unsigned)gy < 120u && (unsigned)gx < 64u) v = inc[gy * 64 + gx];
    tile[ly * 21 + lx] = v;
  }
  __syncthreads();
  float tv[25];
#pragma unroll
  for (int dy = 0; dy < 5; ++dy)
#pragma unroll
    for (int dx = 0; dx < 5; ++dx)
      tv[dy * 5 + dx] = tile[(ty + dy) * 21 + tx + dx];
  float acc[8];
#pragma unroll
  for (int o = 0; o < 8; ++o) {
    const float* wo = wgt + (size_t)(ocb + o) * 25;
    float a = 0.f;
#pragma unroll
    for (int t = 0; t < 25; ++t) a = fmaf(tv[t], wo[t], a);
    acc[o] = a;
  }
  int oy = tileY + ty, ox = tileX + tx;
  if (oy < 120) {
    size_t base = (((size_t)b * 120 + oy) * 64 + ox) * 64 + ocb;
    ushort4 p0, p1;
    p0.x = f2h(acc[0]); p0.y = f2h(acc[1]); p0.z = f2h(acc[2]); p0.w = f2h(acc[3]);
    p1.x = f2h(acc[4]); p1.y = f2h(acc[5]); p1.z = f2h(acc[6]); p1.w = f2h(acc[7]);
    *(ushort4*)(out + base) = p0;
    *(ushort4*)(out + base + 4) = p1;
  }
}

// ---------------------------------------------- MFMA implicit-GEMM 5x5 conv
// NHWC fp16. Wave: 4 M-tiles (64 oc) x NT N-tiles (16 px each).
// LDS: 64B/px XOR-swizzled: slot16 = px*4 + (q ^ ((px+(px>>2))&3)).
//  - B-reads (16 consecutive px, fixed q): each 16B bank-group hit exactly 2x
//    over 16 lanes -> 2-way, free (m136).
//  - staging writes: every 8 consecutive lanes cover all 8 groups -> uniform.
// A-fragments prefetched 2 taps deep; taps 0-1 issued before staging barrier.
template <int CIN, int H, int W, int NT, int OC, bool PREBN>
__global__ __launch_bounds__(256, 4) void k_convM(const unsigned short* __restrict__ in,
                                                  const unsigned short* __restrict__ wt,
                                                  unsigned short* __restrict__ out,
                                                  const float* __restrict__ pst,
                                                  const float* __restrict__ pg,
                                                  const float* __restrict__ pbe) {
  constexpr int XC = W / 16, RPW = NT / XC, WGR = 4 * RPW;
  constexpr int LW = W + 4, LR = WGR + 4, NPX = LR * LW;
  constexpr int MTS = (CIN / 32) * 512;       // per-mt frag stride (halfwords)
  constexpr int TS = (OC / 16) * MTS;         // per-tap frag stride
  __shared__ unsigned short lds[NPX * 32];    // 64B per pixel, swizzled
  int tid = threadIdx.x;
  int w = tid >> 6, lane = tid & 63, l15 = lane & 15, q = lane >> 4;
  int q4 = tid & 3;
  int y0 = blockIdx.x * WGR, b = blockIdx.y, oc0 = blockIdx.z * 64;
  int z4 = blockIdx.z * 4;
  int lofs = (l15 * 4 + q) * 8;
  f32x4 acc[4][NT];
#pragma unroll
  for (int mt = 0; mt < 4; ++mt)
#pragma unroll
    for (int nt = 0; nt < NT; ++nt) acc[mt][nt] = 0.f;

  for (int icb = 0; icb < CIN / 32; ++icb) {
    const unsigned short* wbase = wt + (size_t)icb * 512 + lofs;
    // A-frag prefetch for taps 0,1 — issued before staging so L2 latency
    // hides under the staging loads + barrier.
    f16x8 avn[4], avn2[4];
#pragma unroll
    for (int mt = 0; mt < 4; ++mt) {
      avn[mt]  = *(const f16x8*)(wbase + (size_t)(z4 + mt) * MTS);
      avn2[mt] = *(const f16x8*)(wbase + (size_t)TS + (size_t)(z4 + mt) * MTS);
    }
    float s8[8], a8[8];
    if (PREBN) {
      int cb = icb * 32 + q4 * 8;
#pragma unroll
      for (int j = 0; j < 8; ++j) {
        float m = pst[cb + j], iv = pst[CIN + cb + j];
        s8[j] = pg[cb + j] * iv;
        a8[j] = pbe[cb + j] - m * s8[j];
      }
    }
    __syncthreads();
    for (int e = tid; e < NPX * 4; e += 256) {
      int px = e >> 2;                 // e&3 == q4 (invariant per thread)
      int lr = px / LW, c = px % LW;
      int y = y0 - 2 + lr, x = c - 2;
      f16x8 v = (f16x8)0;
      if ((unsigned)y < (unsigned)H && (unsigned)x < (unsigned)W) {
        v = *(const f16x8*)(in + (((size_t)b * H + y) * W + x) * CIN + icb * 32 + q4 * 8);
        if (PREBN) {
#pragma unroll
          for (int j = 0; j < 8; ++j) {
            float f = fmaf((float)v[j], s8[j], a8[j]);
            v[j] = (_Float16)(f > 0.f ? f : 0.f);
          }
        }
      }
      int sw = (px + (px >> 2)) & 3;
      *(f16x8*)&lds[px * 32 + ((q4 ^ sw) << 3)] = v;
    }
    __syncthreads();
#pragma unroll
    for (int t = 0; t < 25; ++t) {
      int dy = t / 5, dx = t % 5;
      f16x8 avc[4];
#pragma unroll
      for (int mt = 0; mt < 4; ++mt) { avc[mt] = avn[mt]; avn[mt] = avn2[mt]; }
      if (t < 23) {
#pragma unroll
        for (int mt = 0; mt < 4; ++mt)
          avn2[mt] = *(const f16x8*)(wbase + (size_t)(t + 2) * TS + (size_t)(z4 + mt) * MTS);
      }
#pragma unroll
      for (int nt = 0; nt < NT; ++nt) {
        int lr = w * RPW + nt / XC + dy;
        int c = (nt % XC) * 16 + l15 + dx;
        int px = lr * LW + c;
        int sw = (px + (px >> 2)) & 3;
        f16x8 bv = *(const f16x8*)&lds[px * 32 + ((q ^ sw) << 3)];
#pragma unroll
        for (int mt = 0; mt < 4; ++mt)
          acc[mt][nt] = __builtin_amdgcn_mfma_f32_16x16x32_f16(avc[mt], bv, acc[mt][nt], 0, 0, 0);
      }
    }
  }
#pragma unroll
  for (int nt = 0; nt < NT; ++nt) {
    int y = y0 + w * RPW + nt / XC;
    if (y >= H) continue;
    int x = (nt % XC) * 16 + l15;
    size_t pbase = (((size_t)b * H + y) * W + x) * OC + oc0 + q * 4;
#pragma unroll
    for (int mt = 0; mt < 4; ++mt) {
      ushort4 pk;
      pk.x = f2h(acc[mt][nt][0]);
      pk.y = f2h(acc[mt][nt][1]);
      pk.z = f2h(acc[mt][nt][2]);
      pk.w = f2h(acc[mt][nt][3]);
      *(ushort4*)(out + pbase + mt * 16) = pk;
    }
  }
}

// ------------------- BN stats, vectorized f16x8 (fully coalesced 1KB/wave)
template <int C>
__global__ __launch_bounds__(256) void k_bnstatsv(const unsigned short* __restrict__ x,
                                                  float* __restrict__ acc,
                                                  int nIter) {
  constexpr int CV = C / 8, KPB = 256 / CV;
  __shared__ float r1[256][8], r2[256][8];
  int tid = threadIdx.x;
  int cv = tid % CV, kq = tid / CV;
  size_t row0 = (size_t)blockIdx.x * (KPB * nIter) + kq;
  const unsigned short* p = x + row0 * C + cv * 8;
  float s1[8], s2[8];
#pragma unroll
  for (int j = 0; j < 8; ++j) { s1[j] = 0.f; s2[j] = 0.f; }
  for (int it = 0; it < nIter; ++it) {
    f16x8 v = *(const f16x8*)(p + (size_t)it * KPB * C);
#pragma unroll
    for (int j = 0; j < 8; ++j) {
      float f = (float)v[j];
      s1[j] += f;
      s2[j] += f * f;
    }
  }
#pragma unroll
  for (int j = 0; j < 8; ++j) { r1[tid][j] = s1[j]; r2[tid][j] = s2[j]; }
  __syncthreads();
  if (tid < C) {
    int cv0 = tid >> 3, e = tid & 7;
    float t1 = 0.f, t2 = 0.f;
    for (int k = 0; k < KPB; ++k) {
      t1 += r1[k * CV + cv0][e];
      t2 += r2[k * CV + cv0][e];
    }
    atomicAdd(&acc[tid], t1);
    atomicAdd(&acc[C + tid], t2);
  }
}

__global__ __launch_bounds__(256) void k_bnfin(const float* __restrict__ acc,
                                               float* __restrict__ stats,
                                               int C, float invN) {
  int c = threadIdx.x + blockIdx.x * 256;
  if (c >= C) return;
  float m = acc[c] * invN;
  float v = acc[C + c] * invN - m * m;
  stats[c] = m;
  stats[C + c] = rsqrtf(v + 1e-5f);
}

// --------------------------------------- BN+ReLU+maxpool2 NHWC (x8 vec)
template <int C, int H, int W>
__global__ __launch_bounds__(256) void k_brp(const unsigned short* __restrict__ x,
                                             unsigned short* __restrict__ y,
                                             const float* __restrict__ stats,
                                             const float* __restrict__ g,
                                             const float* __restrict__ be) {
  constexpr int OH = H / 2, OW = W / 2, CV = C / 8;
  int idx = blockIdx.x * 256 + threadIdx.x;   // [b][oy][ox][cv]
  int cv = idx % CV;
  int t = idx / CV;
  int ox = t % OW; t /= OW;
  int oy = t % OH;
  int b = t / OH;
  int c0 = cv * 8;
  const unsigned short* p = x + ((size_t)(b * H + oy * 2) * W + ox * 2) * C + c0;
  f16x8 v00 = *(const f16x8*)p;
  f16x8 v01 = *(const f16x8*)(p + C);
  f16x8 v10 = *(const f16x8*)(p + (size_t)W * C);
  f16x8 v11 = *(const f16x8*)(p + (size_t)W * C + C);
  f16x8 r;
#pragma unroll
  for (int j = 0; j < 8; ++j) {
    int c = c0 + j;
    float m = stats[c], iv = stats[C + c], gg = g[c], bb = be[c];
    float f0 = gg * (((float)v00[j] - m) * iv) + bb;
    float f1 = gg * (((float)v01[j] - m) * iv) + bb;
    float f2 = gg * (((float)v10[j] - m) * iv) + bb;
    float f3 = gg * (((float)v11[j] - m) * iv) + bb;
    f0 = f0 > 0.f ? f0 : 0.f;
    f1 = f1 > 0.f ? f1 : 0.f;
    f2 = f2 > 0.f ? f2 : 0.f;
    f3 = f3 > 0.f ? f3 : 0.f;
    float r01 = f0 > f1 ? f0 : f1;
    float r23 = f2 > f3 ? f2 : f3;
    r[j] = (_Float16)(r01 > r23 ? r01 : r23);
  }
  *(f16x8*)(y + (size_t)idx * 8) = r;
}

// ---- stage-3 BN+ReLU+pool + write into batch-major fc1 activations (fp16)
__global__ __launch_bounds__(256) void k_brp3t(const unsigned short* __restrict__ x,
                                               unsigned short* __restrict__ actT,
                                               const float* __restrict__ stats,
                                               const float* __restrict__ g,
                                               const float* __restrict__ be) {
  __shared__ float tile[64 * 65];
  int s = blockIdx.x;
  int oy = s >> 3, ox = s & 7;
  int ci = threadIdx.x & 63, bq = threadIdx.x >> 6;
  for (int cs = 0; cs < 4; ++cs) {
    int c = cs * 64 + ci;
    float m = stats[c], iv = stats[256 + c], gg = g[c], bb = be[c];
    __syncthreads();
    for (int b = bq; b < 64; b += 4) {
      float mx = 0.f;
#pragma unroll
      for (int qq = 0; qq < 4; ++qq) {
        int yy = oy * 2 + (qq >> 1), xx = ox * 2 + (qq & 1);
        float v = h2f(x[((size_t)(b * 30 + yy) * 16 + xx) * 256 + c]);
        v = gg * ((v - m) * iv) + bb;
        v = v > 0.f ? v : 0.f;
        mx = v > mx ? v : mx;
      }
      tile[ci * 65 + b] = mx;
    }
    __syncthreads();
    for (int e = threadIdx.x; e < 4096; e += 256) {
      int cc = e >> 6, bb2 = e & 63;
      actT[(size_t)bb2 * 30784 + 64 + (cs * 64 + cc) * 120 + s] = f2h(tile[cc * 65 + bb2]);
    }
  }
}

// -------------------- q rows of fc inputs + zero fc1 accumulator + BN accums
__global__ __launch_bounds__(256) void k_qinit(const float* __restrict__ q,
                                               unsigned short* __restrict__ actT,
                                               float* __restrict__ in2T,
                                               float* __restrict__ in3T,
                                               float* __restrict__ z1pre,
                                               float* __restrict__ bnacc) {
  int idx = blockIdx.x * 256 + threadIdx.x;
  if (idx < 32000) z1pre[idx] = 0.f;
  else if (idx < 33024) bnacc[idx - 32000] = 0.f;
  if (idx >= 4096) return;
  int b = idx >> 6, i = idx & 63;
  float v = q[idx];
  actT[(size_t)b * 30784 + i] = f2h(v);
  in2T[i * 64 + b] = v;
  in3T[i * 64 + b] = v;
}

// --------------------------------------------------------- fc1 (MFMA GEMM)
__global__ __launch_bounds__(256) void k_fc1m(const unsigned short* __restrict__ actT,
                                              const float* __restrict__ wgt,
                                              float* __restrict__ z1pre) {
  constexpr int IN = 30784;
  constexpr int KSTEPS = IN / 32;   // 962
  __shared__ float part[4][16][64];
  int tid = threadIdx.x;
  int w = tid >> 6, lane = tid & 63, l15 = lane & 15, q = lane >> 4;
  int ob = blockIdx.x * 16;
  int row = ob + l15; if (row > 499) row = 499;
  int kw = blockIdx.y * 4 + w;      // 0..31
  f32x4 acc[4];
#pragma unroll
  for (int nt = 0; nt < 4; ++nt) acc[nt] = 0.f;
  for (int s = kw; s < KSTEPS; s += 32) {
    int k0 = s * 32;
    const float4* wp = (const float4*)(wgt + (size_t)row * IN + k0 + q * 8);
    float4 wa = wp[0], wb = wp[1];
    f16x8 a;
    a[0] = (_Float16)wa.x; a[1] = (_Float16)wa.y;
    a[2] = (_Float16)wa.z; a[3] = (_Float16)wa.w;
    a[4] = (_Float16)wb.x; a[5] = (_Float16)wb.y;
    a[6] = (_Float16)wb.z; a[7] = (_Float16)wb.w;
#pragma unroll
    for (int nt = 0; nt < 4; ++nt) {
      f16x8 bv = *(const f16x8*)(actT + (size_t)(nt * 16 + l15) * IN + k0 + q * 8);
      acc[nt] = __builtin_amdgcn_mfma_f32_16x16x32_f16(a, bv, acc[nt], 0, 0, 0);
    }
  }
#pragma unroll
  for (int nt = 0; nt < 4; ++nt)
#pragma unroll
    for (int reg = 0; reg < 4; ++reg)
      part[w][q * 4 + reg][nt * 16 + l15] = acc[nt][reg];
  __syncthreads();
  for (int e = tid; e < 1024; e += 256) {
    int m = e >> 6, n = e & 63;
    float sum = part[0][m][n] + part[1][m][n] + part[2][m][n] + part[3][m][n];
    int o = ob + m;
    if (o < 500) atomicAdd(&z1pre[o * 64 + n], sum);
  }
}

__global__ __launch_bounds__(256) void k_fc1ep(const float* __restrict__ z1pre,
                                               const float* __restrict__ bias,
                                               float* __restrict__ in2T) {
  int idx = blockIdx.x * 256 + threadIdx.x;
  if (idx >= 500 * 64) return;
  int o = idx >> 6;
  float v = z1pre[idx] + bias[o];
  in2T[idx + 64 * 64] = v > 0.f ? v : 0.f;
}

__global__ __launch_bounds__(256) void k_fc_small(const float* __restrict__ inT,
                                                  const float* __restrict__ wgt,
                                                  const float* __restrict__ bias,
                                                  float* __restrict__ out,
                                                  int IN, int mode) {
  __shared__ float part[4][64];
  int o = blockIdx.x;
  int lane = threadIdx.x & 63, w = threadIdx.x >> 6;
  float acc = 0.f;
  for (int i = w; i < IN; i += 4)
    acc = fmaf(inT[(size_t)i * 64 + lane], wgt[(size_t)o * IN + i], acc);
  part[w][lane] = acc;
  __syncthreads();
  if (threadIdx.x < 64) {
    float s = part[0][lane] + part[1][lane] + part[2][lane] + part[3][lane] + bias[o];
    if (mode == 0) {
      s = s > 0.f ? s : 0.f;
      out[(64 + o) * 64 + lane] = s;
    } else {
      out[lane * 2 + o] = s;
    }
  }
}

// ============================================================================
extern "C" void kernel_launch(void* const* d_in, const int* in_sizes, int n_in,
                              void* d_out, int out_size, void* d_ws, size_t ws_size,
                              hipStream_t stream) {
  const float* x      = (const float*)d_in[0];
  const float* qvec   = (const float*)d_in[1];
  const float* basis  = (const float*)d_in[2];
  const float* w1a    = (const float*)d_in[3];
  const float* g1a    = (const float*)d_in[5];
  const float* be1a   = (const float*)d_in[6];
  const float* w1b    = (const float*)d_in[7];
  const float* g1b    = (const float*)d_in[9];
  const float* be1b   = (const float*)d_in[10];
  const float* w2a    = (const float*)d_in[11];
  const float* g2a    = (const float*)d_in[13];
  const float* be2a   = (const float*)d_in[14];
  const float* w3a    = (const float*)d_in[15];
  const float* g3a    = (const float*)d_in[17];
  const float* be3a   = (const float*)d_in[18];
  const float* fc1w   = (const float*)d_in[19];
  const float* fc1b   = (const float*)d_in[20];
  const float* fc2w   = (const float*)d_in[21];
  const float* fc2b   = (const float*)d_in[22];
  const float* fc3w   = (const float*)d_in[23];
  const float* fc3b   = (const float*)d_in[24];
  float* out = (float*)d_out;

  char* base = (char*)d_ws;
  constexpr size_t ARENA = 62914560;
  char* arenaA = base;
  char* arenaB = base + ARENA;
  char* sm     = base + 2 * ARENA;

  float*          xd   = (float*)arenaA;
  unsigned short* A    = (unsigned short*)arenaA;  // pre1a NHWC [64][120][64][64] (raw)
  unsigned short* P1   = (unsigned short*)arenaA;  // [64][60][32][64]
  unsigned short* P2   = (unsigned short*)arenaA;  // [64][30][16][128]
  unsigned short* actT = (unsigned short*)arenaA;  // [64][30784] fp16

  float*          feat = (float*)arenaB;           // [64][120][64] fp32
  unsigned short* Bb   = (unsigned short*)arenaB;  // pre1b [64][120][64][64]
  unsigned short* C2   = (unsigned short*)arenaB;  // [64][60][32][128]
  unsigned short* D3   = (unsigned short*)arenaB;  // [64][30][16][256]

  float* in2T = (float*)sm;                    // 144,384 B
  float* in3T = (float*)(sm + 144384);         // 144,384 B
  float* z1p  = (float*)(sm + 288768);         // 128,000 B
  float* ACC  = (float*)(sm + 416768);         // 4,096 B
  float* S1A  = (float*)(sm + 420864);
  float* S1B  = (float*)(sm + 421376);
  float* S2A  = (float*)(sm + 421888);
  float* S3A  = (float*)(sm + 422912);
  unsigned short* WT1 = (unsigned short*)(sm + 424960);   // 204,800 B
  unsigned short* WT2 = (unsigned short*)(sm + 834560);   // 409,600 B
  unsigned short* WT3 = (unsigned short*)(sm + 1653760);  // 1,638,400 B

  k_qinit<<<130, 256, 0, stream>>>(qvec, actT, in2T, in3T, z1p, ACC);
  k_prepw<<<400, 256, 0, stream>>>(w1b, WT1, 64, 64);
  k_prepw<<<800, 256, 0, stream>>>(w2a, WT2, 128, 64);
  k_prepw<<<3200, 256, 0, stream>>>(w3a, WT3, 256, 128);

  k_dct<<<64 * 8, 256, 0, stream>>>(x, basis, xd);
  k_hist<<<4096, 256, 0, stream>>>(xd, feat);

  // conv1a (direct) -> A (raw pre-activations), stats over A
  k_conv1a<<<dim3(32, 64, 8), 256, 0, stream>>>(feat, w1a, A);
  k_bnstatsv<64><<<240, 256, 0, stream>>>(A, ACC, 64);
  k_bnfin<<<1, 64, 0, stream>>>(ACC, S1A, 64, 1.f / 491520.f);

  // conv1b (MFMA, PREBN applies BN1a+ReLU during staging) -> Bb
  k_convM<64, 120, 64, 4, 64, true><<<dim3(30, 64, 1), 256, 0, stream>>>(
      A, WT1, Bb, S1A, g1a, be1a);
  k_bnstatsv<64><<<240, 256, 0, stream>>>(Bb, ACC + 128, 64);
  k_bnfin<<<1, 64, 0, stream>>>(ACC + 128, S1B, 64, 1.f / 491520.f);
  k_brp<64, 120, 64><<<3840, 256, 0, stream>>>(Bb, P1, S1B, g1b, be1b);

  // conv2a -> C2, stats, pool -> P2
  k_convM<64, 60, 32, 4, 128, false><<<dim3(8, 64, 2), 256, 0, stream>>>(
      P1, WT2, C2, S1A, g1a, be1a);
  k_bnstatsv<128><<<240, 256, 0, stream>>>(C2, ACC + 256, 32);
  k_bnfin<<<1, 128, 0, stream>>>(ACC + 256, S2A, 128, 1.f / 122880.f);
  k_brp<128, 60, 32><<<1920, 256, 0, stream>>>(C2, P2, S2A, g2a, be2a);

  // conv3a (NT=2 => 1024 blocks, was 512) -> D3, stats, pool+transpose -> actT
  k_convM<128, 30, 16, 2, 256, false><<<dim3(4, 64, 4), 256, 0, stream>>>(
      P2, WT3, D3, S1A, g1a, be1a);
  k_bnstatsv<256><<<240, 256, 0, stream>>>(D3, ACC + 512, 16);
  k_bnfin<<<1, 256, 0, stream>>>(ACC + 512, S3A, 256, 1.f / 30720.f);
  k_qinit<<<130, 256, 0, stream>>>(qvec, actT, in2T, in3T, z1p, ACC);
  k_brp3t<<<120, 256, 0, stream>>>(D3, actT, S3A, g3a, be3a);

  // FC head
  k_fc1m<<<dim3(32, 8), 256, 0, stream>>>(actT, fc1w, z1p);
  k_fc1ep<<<125, 256, 0, stream>>>(z1p, fc1b, in2T);
  k_fc_small<<<500, 256, 0, stream>>>(in2T, fc2w, fc2b, in3T, 564, 0);
  k_fc_small<<<2, 256, 0, stream>>>(in3T, fc3w, fc3b, out, 564, 1);
}

// Round 3
// 1035.153 us; speedup vs baseline: 1.0526x; 1.0526x over previous
//
#include <hip/hip_runtime.h>
#include <math.h>

// ============================================================================
// DoubleJpeg round 10: revert round-9's cross-staging weight hoist (it spilled
// acc -> 697MB scratch traffic, VGPR 104->64, conv1b 157->268us). Keep:
//  (a) 64B/px XOR-swizzled LDS (slot16 = px*4 + (q^((px+(px>>2))&3))):
//      B-reads and staging writes uniform over 8 bank-groups; conv1b LDS
//      43520->34816 => 4 blocks/CU (was 3).
//  (b) conv3a NT=2, grid (4,64,4): 1024 blocks (was 512, 2 blocks/CU).
// convM dataflow = baseline (depth-1 A prefetch, loads after staging barrier,
// VGPR ~104, no spill).
// ============================================================================

typedef __attribute__((ext_vector_type(8))) _Float16 f16x8;
typedef __attribute__((ext_vector_type(4))) float f32x4;

#define GAMMA_F 1.0e6f

__device__ __forceinline__ unsigned short f2h(float f) {
  _Float16 h = (_Float16)f;
  union { _Float16 h; unsigned short u; } x; x.h = h; return x.u;
}
__device__ __forceinline__ float h2f(unsigned short u) {
  union { unsigned short u; _Float16 h; } x; x.u = u; return (float)x.h;
}

// ---------------------------------------------------------------- DCT kernel
__global__ __launch_bounds__(256) void k_dct(const float* __restrict__ x,
                                             const float* __restrict__ basis,
                                             float* __restrict__ xd) {
  __shared__ float bT[4096];
  __shared__ float pix[4][64];
  int tid = threadIdx.x;
  for (int e = tid; e < 4096; e += 256)
    bT[e] = basis[(e & 63) * 64 + (e >> 6)];
  __syncthreads();
  int w = tid >> 6, lane = tid & 63;
  int b = blockIdx.x >> 3;
  int br = ((blockIdx.x & 7) << 2) + w;
  const float* xb = x + (size_t)b * 65536;
  float* xdb = xd + (size_t)b * 65536;
  for (int bc = 0; bc < 32; ++bc) {
    __syncthreads();
    pix[w][lane] = xb[(br * 8 + (lane >> 3)) * 256 + bc * 8 + (lane & 7)];
    __syncthreads();
    float acc = 0.f;
#pragma unroll
    for (int p = 0; p < 64; ++p)
      acc = fmaf(bT[p * 64 + lane], pix[w][p], acc);
    xdb[lane * 1024 + br * 32 + bc] = acc;
  }
}

// ------------------------------- counting soft histogram (no atomics) -> feat
__global__ __launch_bounds__(256) void k_hist(const float* __restrict__ xd,
                                              float* __restrict__ feat) {
  __shared__ float px[1024];
  __shared__ float part[242];
  __shared__ float tot[121];
  int tid = threadIdx.x;
  int bc = blockIdx.x;
  int b = bc >> 6, c = bc & 63;
  const float* p = xd + (size_t)bc * 1024;
  for (int e = tid; e < 1024; e += 256) px[e] = p[e];
  __syncthreads();
  if (tid < 242) {
    int j = tid >> 1;
    float bj = (float)(j - 60);
    int i0 = (tid & 1) * 512;
    float cnt = 0.f;
    for (int i = i0; i < i0 + 512; ++i) {
      float d = px[i] - bj;
      float step = d > 0.f ? 1.f : 0.f;
      cnt += step;
      if (fabsf(d) < 2e-5f)
        cnt += 1.f / (1.f + expf(-GAMMA_F * d)) - step;
    }
    part[tid] = cnt;
  }
  __syncthreads();
  if (tid < 121) tot[tid] = part[2 * tid] + part[2 * tid + 1];
  __syncthreads();
  if (tid < 120)
    feat[((size_t)b * 120 + tid) * 64 + c] = (tot[tid] - tot[tid + 1]) * (1.f / 1024.f);
}

// --------------- weight prep: fp32 -> fp16, fragment-major layout
// out: wt[((t*(OC/16)+mt)*(IC/32)+icb)*512 + l15*32 + q*8 + j]
//    = w[oc=mt*16+l15][ic=icb*32+q*8+j][t]
__global__ __launch_bounds__(256) void k_prepw(const float* __restrict__ w,
                                               unsigned short* __restrict__ wt,
                                               int OC, int IC) {
  int n = OC * IC * 25;
  int idx = blockIdx.x * 256 + threadIdx.x;
  if (idx >= n) return;
  int j = idx & 7;
  int q = (idx >> 3) & 3;
  int l15 = (idx >> 5) & 15;
  int r = idx >> 9;
  int icb = r % (IC / 32);
  int r2 = r / (IC / 32);
  int mt = r2 % (OC / 16);
  int t = r2 / (OC / 16);
  int oc = mt * 16 + l15;
  int ic = icb * 32 + q * 8 + j;
  wt[idx] = f2h(w[((size_t)oc * IC + ic) * 25 + t]);
}

// ----------------------------------------------- conv1a (CIN=1), direct fp32
__global__ __launch_bounds__(256) void k_conv1a(const float* __restrict__ in,
                                                const float* __restrict__ wgt,
                                                unsigned short* __restrict__ out) {
  __shared__ float tile[20 * 21];
  int tx = threadIdx.x & 15, ty = threadIdx.x >> 4;
  int tileX = (blockIdx.x & 3) * 16, tileY = (blockIdx.x >> 2) * 16;
  int b = blockIdx.y, ocb = blockIdx.z * 8;
  const float* inc = in + (size_t)b * 7680;
  for (int e = threadIdx.x; e < 400; e += 256) {
    int ly = e / 20, lx = e % 20;
    int gy = tileY - 2 + ly, gx = tileX - 2 + lx;
    float v = 0.f;
    if ((unsigned)gy < 120u && (unsigned)gx < 64u) v = inc[gy * 64 + gx];
    tile[ly * 21 + lx] = v;
  }
  __syncthreads();
  float tv[25];
#pragma unroll
  for (int dy = 0; dy < 5; ++dy)
#pragma unroll
    for (int dx = 0; dx < 5; ++dx)
      tv[dy * 5 + dx] = tile[(ty + dy) * 21 + tx + dx];
  float acc[8];
#pragma unroll
  for (int o = 0; o < 8; ++o) {
    const float* wo = wgt + (size_t)(ocb + o) * 25;
    float a = 0.f;
#pragma unroll
    for (int t = 0; t < 25; ++t) a = fmaf(tv[t], wo[t], a);
    acc[o] = a;
  }
  int oy = tileY + ty, ox = tileX + tx;
  if (oy < 120) {
    size_t base = (((size_t)b * 120 + oy) * 64 + ox) * 64 + ocb;
    ushort4 p0, p1;
    p0.x = f2h(acc[0]); p0.y = f2h(acc[1]); p0.z = f2h(acc[2]); p0.w = f2h(acc[3]);
    p1.x = f2h(acc[4]); p1.y = f2h(acc[5]); p1.z = f2h(acc[6]); p1.w = f2h(acc[7]);
    *(ushort4*)(out + base) = p0;
    *(ushort4*)(out + base + 4) = p1;
  }
}

// ---------------------------------------------- MFMA implicit-GEMM 5x5 conv
// NHWC fp16. Wave: 4 M-tiles (64 oc) x NT N-tiles (16 px each).
// LDS: 64B/px XOR-swizzled: slot16 = px*4 + (q ^ ((px+(px>>2))&3)).
//  - B-reads (16 consecutive px, fixed q): 8 consecutive px cover all 8
//    bank-groups once -> 2-way over 16 lanes, free (m136).
//  - staging writes: 16 px x 4 q4 uniform over groups.
// Baseline dataflow: depth-1 A prefetch, weight loads AFTER staging barrier
// (keeps acc+avn inside the 128-VGPR cap; round-9's hoist spilled).
template <int CIN, int H, int W, int NT, int OC, bool PREBN>
__global__ __launch_bounds__(256, 4) void k_convM(const unsigned short* __restrict__ in,
                                                  const unsigned short* __restrict__ wt,
                                                  unsigned short* __restrict__ out,
                                                  const float* __restrict__ pst,
                                                  const float* __restrict__ pg,
                                                  const float* __restrict__ pbe) {
  constexpr int XC = W / 16, RPW = NT / XC, WGR = 4 * RPW;
  constexpr int LW = W + 4, LR = WGR + 4, NPX = LR * LW;
  constexpr int MTS = (CIN / 32) * 512;       // per-mt frag stride (halfwords)
  constexpr int TS = (OC / 16) * MTS;         // per-tap frag stride
  __shared__ unsigned short lds[NPX * 32];    // 64B per pixel, swizzled
  int tid = threadIdx.x;
  int w = tid >> 6, lane = tid & 63, l15 = lane & 15, q = lane >> 4;
  int q4 = tid & 3;
  int y0 = blockIdx.x * WGR, b = blockIdx.y, oc0 = blockIdx.z * 64;
  int z4 = blockIdx.z * 4;
  int lofs = (l15 * 4 + q) * 8;
  f32x4 acc[4][NT];
#pragma unroll
  for (int mt = 0; mt < 4; ++mt)
#pragma unroll
    for (int nt = 0; nt < NT; ++nt) acc[mt][nt] = 0.f;

  for (int icb = 0; icb < CIN / 32; ++icb) {
    float s8[8], a8[8];
    if (PREBN) {
      int cb = icb * 32 + q4 * 8;
#pragma unroll
      for (int j = 0; j < 8; ++j) {
        float m = pst[cb + j], iv = pst[CIN + cb + j];
        s8[j] = pg[cb + j] * iv;
        a8[j] = pbe[cb + j] - m * s8[j];
      }
    }
    __syncthreads();
    for (int e = tid; e < NPX * 4; e += 256) {
      int px = e >> 2;                 // e&3 == q4 (invariant per thread)
      int lr = px / LW, c = px % LW;
      int y = y0 - 2 + lr, x = c - 2;
      f16x8 v = (f16x8)0;
      if ((unsigned)y < (unsigned)H && (unsigned)x < (unsigned)W) {
        v = *(const f16x8*)(in + (((size_t)b * H + y) * W + x) * CIN + icb * 32 + q4 * 8);
        if (PREBN) {
#pragma unroll
          for (int j = 0; j < 8; ++j) {
            float f = fmaf((float)v[j], s8[j], a8[j]);
            v[j] = (_Float16)(f > 0.f ? f : 0.f);
          }
        }
      }
      int sw = (px + (px >> 2)) & 3;
      *(f16x8*)&lds[px * 32 + ((q4 ^ sw) << 3)] = v;
    }
    __syncthreads();
    const unsigned short* wbase = wt + (size_t)icb * 512 + lofs;
    f16x8 avn[4];
#pragma unroll
    for (int mt = 0; mt < 4; ++mt)
      avn[mt] = *(const f16x8*)(wbase + (size_t)(z4 + mt) * MTS);
#pragma unroll
    for (int t = 0; t < 25; ++t) {
      int dy = t / 5, dx = t % 5;
      f16x8 avc[4];
#pragma unroll
      for (int mt = 0; mt < 4; ++mt) avc[mt] = avn[mt];
      if (t < 24) {
#pragma unroll
        for (int mt = 0; mt < 4; ++mt)
          avn[mt] = *(const f16x8*)(wbase + (size_t)(t + 1) * TS + (size_t)(z4 + mt) * MTS);
      }
#pragma unroll
      for (int nt = 0; nt < NT; ++nt) {
        int lr = w * RPW + nt / XC + dy;
        int c = (nt % XC) * 16 + l15 + dx;
        int px = lr * LW + c;
        int sw = (px + (px >> 2)) & 3;
        f16x8 bv = *(const f16x8*)&lds[px * 32 + ((q ^ sw) << 3)];
#pragma unroll
        for (int mt = 0; mt < 4; ++mt)
          acc[mt][nt] = __builtin_amdgcn_mfma_f32_16x16x32_f16(avc[mt], bv, acc[mt][nt], 0, 0, 0);
      }
    }
  }
#pragma unroll
  for (int nt = 0; nt < NT; ++nt) {
    int y = y0 + w * RPW + nt / XC;
    if (y >= H) continue;
    int x = (nt % XC) * 16 + l15;
    size_t pbase = (((size_t)b * H + y) * W + x) * OC + oc0 + q * 4;
#pragma unroll
    for (int mt = 0; mt < 4; ++mt) {
      ushort4 pk;
      pk.x = f2h(acc[mt][nt][0]);
      pk.y = f2h(acc[mt][nt][1]);
      pk.z = f2h(acc[mt][nt][2]);
      pk.w = f2h(acc[mt][nt][3]);
      *(ushort4*)(out + pbase + mt * 16) = pk;
    }
  }
}

// ------------------- BN stats, vectorized f16x8 (fully coalesced 1KB/wave)
template <int C>
__global__ __launch_bounds__(256) void k_bnstatsv(const unsigned short* __restrict__ x,
                                                  float* __restrict__ acc,
                                                  int nIter) {
  constexpr int CV = C / 8, KPB = 256 / CV;
  __shared__ float r1[256][8], r2[256][8];
  int tid = threadIdx.x;
  int cv = tid % CV, kq = tid / CV;
  size_t row0 = (size_t)blockIdx.x * (KPB * nIter) + kq;
  const unsigned short* p = x + row0 * C + cv * 8;
  float s1[8], s2[8];
#pragma unroll
  for (int j = 0; j < 8; ++j) { s1[j] = 0.f; s2[j] = 0.f; }
  for (int it = 0; it < nIter; ++it) {
    f16x8 v = *(const f16x8*)(p + (size_t)it * KPB * C);
#pragma unroll
    for (int j = 0; j < 8; ++j) {
      float f = (float)v[j];
      s1[j] += f;
      s2[j] += f * f;
    }
  }
#pragma unroll
  for (int j = 0; j < 8; ++j) { r1[tid][j] = s1[j]; r2[tid][j] = s2[j]; }
  __syncthreads();
  if (tid < C) {
    int cv0 = tid >> 3, e = tid & 7;
    float t1 = 0.f, t2 = 0.f;
    for (int k = 0; k < KPB; ++k) {
      t1 += r1[k * CV + cv0][e];
      t2 += r2[k * CV + cv0][e];
    }
    atomicAdd(&acc[tid], t1);
    atomicAdd(&acc[C + tid], t2);
  }
}

__global__ __launch_bounds__(256) void k_bnfin(const float* __restrict__ acc,
                                               float* __restrict__ stats,
                                               int C, float invN) {
  int c = threadIdx.x + blockIdx.x * 256;
  if (c >= C) return;
  float m = acc[c] * invN;
  float v = acc[C + c] * invN - m * m;
  stats[c] = m;
  stats[C + c] = rsqrtf(v + 1e-5f);
}

// --------------------------------------- BN+ReLU+maxpool2 NHWC (x8 vec)
template <int C, int H, int W>
__global__ __launch_bounds__(256) void k_brp(const unsigned short* __restrict__ x,
                                             unsigned short* __restrict__ y,
                                             const float* __restrict__ stats,
                                             const float* __restrict__ g,
                                             const float* __restrict__ be) {
  constexpr int OH = H / 2, OW = W / 2, CV = C / 8;
  int idx = blockIdx.x * 256 + threadIdx.x;   // [b][oy][ox][cv]
  int cv = idx % CV;
  int t = idx / CV;
  int ox = t % OW; t /= OW;
  int oy = t % OH;
  int b = t / OH;
  int c0 = cv * 8;
  const unsigned short* p = x + ((size_t)(b * H + oy * 2) * W + ox * 2) * C + c0;
  f16x8 v00 = *(const f16x8*)p;
  f16x8 v01 = *(const f16x8*)(p + C);
  f16x8 v10 = *(const f16x8*)(p + (size_t)W * C);
  f16x8 v11 = *(const f16x8*)(p + (size_t)W * C + C);
  f16x8 r;
#pragma unroll
  for (int j = 0; j < 8; ++j) {
    int c = c0 + j;
    float m = stats[c], iv = stats[C + c], gg = g[c], bb = be[c];
    float f0 = gg * (((float)v00[j] - m) * iv) + bb;
    float f1 = gg * (((float)v01[j] - m) * iv) + bb;
    float f2 = gg * (((float)v10[j] - m) * iv) + bb;
    float f3 = gg * (((float)v11[j] - m) * iv) + bb;
    f0 = f0 > 0.f ? f0 : 0.f;
    f1 = f1 > 0.f ? f1 : 0.f;
    f2 = f2 > 0.f ? f2 : 0.f;
    f3 = f3 > 0.f ? f3 : 0.f;
    float r01 = f0 > f1 ? f0 : f1;
    float r23 = f2 > f3 ? f2 : f3;
    r[j] = (_Float16)(r01 > r23 ? r01 : r23);
  }
  *(f16x8*)(y + (size_t)idx * 8) = r;
}

// ---- stage-3 BN+ReLU+pool + write into batch-major fc1 activations (fp16)
__global__ __launch_bounds__(256) void k_brp3t(const unsigned short* __restrict__ x,
                                               unsigned short* __restrict__ actT,
                                               const float* __restrict__ stats,
                                               const float* __restrict__ g,
                                               const float* __restrict__ be) {
  __shared__ float tile[64 * 65];
  int s = blockIdx.x;
  int oy = s >> 3, ox = s & 7;
  int ci = threadIdx.x & 63, bq = threadIdx.x >> 6;
  for (int cs = 0; cs < 4; ++cs) {
    int c = cs * 64 + ci;
    float m = stats[c], iv = stats[256 + c], gg = g[c], bb = be[c];
    __syncthreads();
    for (int b = bq; b < 64; b += 4) {
      float mx = 0.f;
#pragma unroll
      for (int qq = 0; qq < 4; ++qq) {
        int yy = oy * 2 + (qq >> 1), xx = ox * 2 + (qq & 1);
        float v = h2f(x[((size_t)(b * 30 + yy) * 16 + xx) * 256 + c]);
        v = gg * ((v - m) * iv) + bb;
        v = v > 0.f ? v : 0.f;
        mx = v > mx ? v : mx;
      }
      tile[ci * 65 + b] = mx;
    }
    __syncthreads();
    for (int e = threadIdx.x; e < 4096; e += 256) {
      int cc = e >> 6, bb2 = e & 63;
      actT[(size_t)bb2 * 30784 + 64 + (cs * 64 + cc) * 120 + s] = f2h(tile[cc * 65 + bb2]);
    }
  }
}

// -------------------- q rows of fc inputs + zero fc1 accumulator + BN accums
__global__ __launch_bounds__(256) void k_qinit(const float* __restrict__ q,
                                               unsigned short* __restrict__ actT,
                                               float* __restrict__ in2T,
                                               float* __restrict__ in3T,
                                               float* __restrict__ z1pre,
                                               float* __restrict__ bnacc) {
  int idx = blockIdx.x * 256 + threadIdx.x;
  if (idx < 32000) z1pre[idx] = 0.f;
  else if (idx < 33024) bnacc[idx - 32000] = 0.f;
  if (idx >= 4096) return;
  int b = idx >> 6, i = idx & 63;
  float v = q[idx];
  actT[(size_t)b * 30784 + i] = f2h(v);
  in2T[i * 64 + b] = v;
  in3T[i * 64 + b] = v;
}

// --------------------------------------------------------- fc1 (MFMA GEMM)
__global__ __launch_bounds__(256) void k_fc1m(const unsigned short* __restrict__ actT,
                                              const float* __restrict__ wgt,
                                              float* __restrict__ z1pre) {
  constexpr int IN = 30784;
  constexpr int KSTEPS = IN / 32;   // 962
  __shared__ float part[4][16][64];
  int tid = threadIdx.x;
  int w = tid >> 6, lane = tid & 63, l15 = lane & 15, q = lane >> 4;
  int ob = blockIdx.x * 16;
  int row = ob + l15; if (row > 499) row = 499;
  int kw = blockIdx.y * 4 + w;      // 0..31
  f32x4 acc[4];
#pragma unroll
  for (int nt = 0; nt < 4; ++nt) acc[nt] = 0.f;
  for (int s = kw; s < KSTEPS; s += 32) {
    int k0 = s * 32;
    const float4* wp = (const float4*)(wgt + (size_t)row * IN + k0 + q * 8);
    float4 wa = wp[0], wb = wp[1];
    f16x8 a;
    a[0] = (_Float16)wa.x; a[1] = (_Float16)wa.y;
    a[2] = (_Float16)wa.z; a[3] = (_Float16)wa.w;
    a[4] = (_Float16)wb.x; a[5] = (_Float16)wb.y;
    a[6] = (_Float16)wb.z; a[7] = (_Float16)wb.w;
#pragma unroll
    for (int nt = 0; nt < 4; ++nt) {
      f16x8 bv = *(const f16x8*)(actT + (size_t)(nt * 16 + l15) * IN + k0 + q * 8);
      acc[nt] = __builtin_amdgcn_mfma_f32_16x16x32_f16(a, bv, acc[nt], 0, 0, 0);
    }
  }
#pragma unroll
  for (int nt = 0; nt < 4; ++nt)
#pragma unroll
    for (int reg = 0; reg < 4; ++reg)
      part[w][q * 4 + reg][nt * 16 + l15] = acc[nt][reg];
  __syncthreads();
  for (int e = tid; e < 1024; e += 256) {
    int m = e >> 6, n = e & 63;
    float sum = part[0][m][n] + part[1][m][n] + part[2][m][n] + part[3][m][n];
    int o = ob + m;
    if (o < 500) atomicAdd(&z1pre[o * 64 + n], sum);
  }
}

__global__ __launch_bounds__(256) void k_fc1ep(const float* __restrict__ z1pre,
                                               const float* __restrict__ bias,
                                               float* __restrict__ in2T) {
  int idx = blockIdx.x * 256 + threadIdx.x;
  if (idx >= 500 * 64) return;
  int o = idx >> 6;
  float v = z1pre[idx] + bias[o];
  in2T[idx + 64 * 64] = v > 0.f ? v : 0.f;
}

__global__ __launch_bounds__(256) void k_fc_small(const float* __restrict__ inT,
                                                  const float* __restrict__ wgt,
                                                  const float* __restrict__ bias,
                                                  float* __restrict__ out,
                                                  int IN, int mode) {
  __shared__ float part[4][64];
  int o = blockIdx.x;
  int lane = threadIdx.x & 63, w = threadIdx.x >> 6;
  float acc = 0.f;
  for (int i = w; i < IN; i += 4)
    acc = fmaf(inT[(size_t)i * 64 + lane], wgt[(size_t)o * IN + i], acc);
  part[w][lane] = acc;
  __syncthreads();
  if (threadIdx.x < 64) {
    float s = part[0][lane] + part[1][lane] + part[2][lane] + part[3][lane] + bias[o];
    if (mode == 0) {
      s = s > 0.f ? s : 0.f;
      out[(64 + o) * 64 + lane] = s;
    } else {
      out[lane * 2 + o] = s;
    }
  }
}

// ============================================================================
extern "C" void kernel_launch(void* const* d_in, const int* in_sizes, int n_in,
                              void* d_out, int out_size, void* d_ws, size_t ws_size,
                              hipStream_t stream) {
  const float* x      = (const float*)d_in[0];
  const float* qvec   = (const float*)d_in[1];
  const float* basis  = (const float*)d_in[2];
  const float* w1a    = (const float*)d_in[3];
  const float* g1a    = (const float*)d_in[5];
  const float* be1a   = (const float*)d_in[6];
  const float* w1b    = (const float*)d_in[7];
  const float* g1b    = (const float*)d_in[9];
  const float* be1b   = (const float*)d_in[10];
  const float* w2a    = (const float*)d_in[11];
  const float* g2a    = (const float*)d_in[13];
  const float* be2a   = (const float*)d_in[14];
  const float* w3a    = (const float*)d_in[15];
  const float* g3a    = (const float*)d_in[17];
  const float* be3a   = (const float*)d_in[18];
  const float* fc1w   = (const float*)d_in[19];
  const float* fc1b   = (const float*)d_in[20];
  const float* fc2w   = (const float*)d_in[21];
  const float* fc2b   = (const float*)d_in[22];
  const float* fc3w   = (const float*)d_in[23];
  const float* fc3b   = (const float*)d_in[24];
  float* out = (float*)d_out;

  char* base = (char*)d_ws;
  constexpr size_t ARENA = 62914560;
  char* arenaA = base;
  char* arenaB = base + ARENA;
  char* sm     = base + 2 * ARENA;

  float*          xd   = (float*)arenaA;
  unsigned short* A    = (unsigned short*)arenaA;  // pre1a NHWC [64][120][64][64] (raw)
  unsigned short* P1   = (unsigned short*)arenaA;  // [64][60][32][64]
  unsigned short* P2   = (unsigned short*)arenaA;  // [64][30][16][128]
  unsigned short* actT = (unsigned short*)arenaA;  // [64][30784] fp16

  float*          feat = (float*)arenaB;           // [64][120][64] fp32
  unsigned short* Bb   = (unsigned short*)arenaB;  // pre1b [64][120][64][64]
  unsigned short* C2   = (unsigned short*)arenaB;  // [64][60][32][128]
  unsigned short* D3   = (unsigned short*)arenaB;  // [64][30][16][256]

  float* in2T = (float*)sm;                    // 144,384 B
  float* in3T = (float*)(sm + 144384);         // 144,384 B
  float* z1p  = (float*)(sm + 288768);         // 128,000 B
  float* ACC  = (float*)(sm + 416768);         // 4,096 B
  float* S1A  = (float*)(sm + 420864);
  float* S1B  = (float*)(sm + 421376);
  float* S2A  = (float*)(sm + 421888);
  float* S3A  = (float*)(sm + 422912);
  unsigned short* WT1 = (unsigned short*)(sm + 424960);   // 204,800 B
  unsigned short* WT2 = (unsigned short*)(sm + 834560);   // 409,600 B
  unsigned short* WT3 = (unsigned short*)(sm + 1653760);  // 1,638,400 B

  k_qinit<<<130, 256, 0, stream>>>(qvec, actT, in2T, in3T, z1p, ACC);
  k_prepw<<<400, 256, 0, stream>>>(w1b, WT1, 64, 64);
  k_prepw<<<800, 256, 0, stream>>>(w2a, WT2, 128, 64);
  k_prepw<<<3200, 256, 0, stream>>>(w3a, WT3, 256, 128);

  k_dct<<<64 * 8, 256, 0, stream>>>(x, basis, xd);
  k_hist<<<4096, 256, 0, stream>>>(xd, feat);

  // conv1a (direct) -> A (raw pre-activations), stats over A
  k_conv1a<<<dim3(32, 64, 8), 256, 0, stream>>>(feat, w1a, A);
  k_bnstatsv<64><<<240, 256, 0, stream>>>(A, ACC, 64);
  k_bnfin<<<1, 64, 0, stream>>>(ACC, S1A, 64, 1.f / 491520.f);

  // conv1b (MFMA, PREBN applies BN1a+ReLU during staging) -> Bb
  k_convM<64, 120, 64, 4, 64, true><<<dim3(30, 64, 1), 256, 0, stream>>>(
      A, WT1, Bb, S1A, g1a, be1a);
  k_bnstatsv<64><<<240, 256, 0, stream>>>(Bb, ACC + 128, 64);
  k_bnfin<<<1, 64, 0, stream>>>(ACC + 128, S1B, 64, 1.f / 491520.f);
  k_brp<64, 120, 64><<<3840, 256, 0, stream>>>(Bb, P1, S1B, g1b, be1b);

  // conv2a -> C2, stats, pool -> P2
  k_convM<64, 60, 32, 4, 128, false><<<dim3(8, 64, 2), 256, 0, stream>>>(
      P1, WT2, C2, S1A, g1a, be1a);
  k_bnstatsv<128><<<240, 256, 0, stream>>>(C2, ACC + 256, 32);
  k_bnfin<<<1, 128, 0, stream>>>(ACC + 256, S2A, 128, 1.f / 122880.f);
  k_brp<128, 60, 32><<<1920, 256, 0, stream>>>(C2, P2, S2A, g2a, be2a);

  // conv3a (NT=2 => 1024 blocks) -> D3, stats, pool+transpose -> actT
  k_convM<128, 30, 16, 2, 256, false><<<dim3(4, 64, 4), 256, 0, stream>>>(
      P2, WT3, D3, S1A, g1a, be1a);
  k_bnstatsv<256><<<240, 256, 0, stream>>>(D3, ACC + 512, 16);
  k_bnfin<<<1, 256, 0, stream>>>(ACC + 512, S3A, 256, 1.f / 30720.f);
  k_qinit<<<130, 256, 0, stream>>>(qvec, actT, in2T, in3T, z1p, ACC);
  k_brp3t<<<120, 256, 0, stream>>>(D3, actT, S3A, g3a, be3a);

  // FC head
  k_fc1m<<<dim3(32, 8), 256, 0, stream>>>(actT, fc1w, z1p);
  k_fc1ep<<<125, 256, 0, stream>>>(z1p, fc1b, in2T);
  k_fc_small<<<500, 256, 0, stream>>>(in2T, fc2w, fc2b, in3T, 564, 0);
  k_fc_small<<<2, 256, 0, stream>>>(in3T, fc3w, fc3b, out, 564, 1);
}

// Round 4
// 1002.214 us; speedup vs baseline: 1.0872x; 1.0329x over previous
//
#include <hip/hip_runtime.h>
#include <math.h>

// ============================================================================
// DoubleJpeg round 11: back to the VERIFIED 80B-slot convM dataflow (the
// XOR-swizzle was the spill culprit: runtime q^sw(px) addresses can't fold to
// ds_read offset immediates -> ~40 addr VGPRs -> acc spill, 559MB scratch).
// Geometry-only improvements (compile-time, same register structure):
//  (a) conv1b TC=32 col-tiling: 8x32 blocks, NPX 544->432, LDS 43520->34560
//      => 4 blocks/CU (was 3), 21% less halo staging.
//  (b) conv3a NT=2, grid (4,64,4): 1024 blocks (was 512 @ 2 blocks/CU).
// ============================================================================

typedef __attribute__((ext_vector_type(8))) _Float16 f16x8;
typedef __attribute__((ext_vector_type(4))) float f32x4;

#define GAMMA_F 1.0e6f

__device__ __forceinline__ unsigned short f2h(float f) {
  _Float16 h = (_Float16)f;
  union { _Float16 h; unsigned short u; } x; x.h = h; return x.u;
}
__device__ __forceinline__ float h2f(unsigned short u) {
  union { unsigned short u; _Float16 h; } x; x.u = u; return (float)x.h;
}

// ---------------------------------------------------------------- DCT kernel
__global__ __launch_bounds__(256) void k_dct(const float* __restrict__ x,
                                             const float* __restrict__ basis,
                                             float* __restrict__ xd) {
  __shared__ float bT[4096];
  __shared__ float pix[4][64];
  int tid = threadIdx.x;
  for (int e = tid; e < 4096; e += 256)
    bT[e] = basis[(e & 63) * 64 + (e >> 6)];
  __syncthreads();
  int w = tid >> 6, lane = tid & 63;
  int b = blockIdx.x >> 3;
  int br = ((blockIdx.x & 7) << 2) + w;
  const float* xb = x + (size_t)b * 65536;
  float* xdb = xd + (size_t)b * 65536;
  for (int bc = 0; bc < 32; ++bc) {
    __syncthreads();
    pix[w][lane] = xb[(br * 8 + (lane >> 3)) * 256 + bc * 8 + (lane & 7)];
    __syncthreads();
    float acc = 0.f;
#pragma unroll
    for (int p = 0; p < 64; ++p)
      acc = fmaf(bT[p * 64 + lane], pix[w][p], acc);
    xdb[lane * 1024 + br * 32 + bc] = acc;
  }
}

// ------------------------------- counting soft histogram (no atomics) -> feat
__global__ __launch_bounds__(256) void k_hist(const float* __restrict__ xd,
                                              float* __restrict__ feat) {
  __shared__ float px[1024];
  __shared__ float part[242];
  __shared__ float tot[121];
  int tid = threadIdx.x;
  int bc = blockIdx.x;
  int b = bc >> 6, c = bc & 63;
  const float* p = xd + (size_t)bc * 1024;
  for (int e = tid; e < 1024; e += 256) px[e] = p[e];
  __syncthreads();
  if (tid < 242) {
    int j = tid >> 1;
    float bj = (float)(j - 60);
    int i0 = (tid & 1) * 512;
    float cnt = 0.f;
    for (int i = i0; i < i0 + 512; ++i) {
      float d = px[i] - bj;
      float step = d > 0.f ? 1.f : 0.f;
      cnt += step;
      if (fabsf(d) < 2e-5f)
        cnt += 1.f / (1.f + expf(-GAMMA_F * d)) - step;
    }
    part[tid] = cnt;
  }
  __syncthreads();
  if (tid < 121) tot[tid] = part[2 * tid] + part[2 * tid + 1];
  __syncthreads();
  if (tid < 120)
    feat[((size_t)b * 120 + tid) * 64 + c] = (tot[tid] - tot[tid + 1]) * (1.f / 1024.f);
}

// --------------- weight prep: fp32 -> fp16, fragment-major layout
// out: wt[((t*(OC/16)+mt)*(IC/32)+icb)*512 + l15*32 + q*8 + j]
//    = w[oc=mt*16+l15][ic=icb*32+q*8+j][t]
__global__ __launch_bounds__(256) void k_prepw(const float* __restrict__ w,
                                               unsigned short* __restrict__ wt,
                                               int OC, int IC) {
  int n = OC * IC * 25;
  int idx = blockIdx.x * 256 + threadIdx.x;
  if (idx >= n) return;
  int j = idx & 7;
  int q = (idx >> 3) & 3;
  int l15 = (idx >> 5) & 15;
  int r = idx >> 9;
  int icb = r % (IC / 32);
  int r2 = r / (IC / 32);
  int mt = r2 % (OC / 16);
  int t = r2 / (OC / 16);
  int oc = mt * 16 + l15;
  int ic = icb * 32 + q * 8 + j;
  wt[idx] = f2h(w[((size_t)oc * IC + ic) * 25 + t]);
}

// ----------------------------------------------- conv1a (CIN=1), direct fp32
__global__ __launch_bounds__(256) void k_conv1a(const float* __restrict__ in,
                                                const float* __restrict__ wgt,
                                                unsigned short* __restrict__ out) {
  __shared__ float tile[20 * 21];
  int tx = threadIdx.x & 15, ty = threadIdx.x >> 4;
  int tileX = (blockIdx.x & 3) * 16, tileY = (blockIdx.x >> 2) * 16;
  int b = blockIdx.y, ocb = blockIdx.z * 8;
  const float* inc = in + (size_t)b * 7680;
  for (int e = threadIdx.x; e < 400; e += 256) {
    int ly = e / 20, lx = e % 20;
    int gy = tileY - 2 + ly, gx = tileX - 2 + lx;
    float v = 0.f;
    if ((unsigned)gy < 120u && (unsigned)gx < 64u) v = inc[gy * 64 + gx];
    tile[ly * 21 + lx] = v;
  }
  __syncthreads();
  float tv[25];
#pragma unroll
  for (int dy = 0; dy < 5; ++dy)
#pragma unroll
    for (int dx = 0; dx < 5; ++dx)
      tv[dy * 5 + dx] = tile[(ty + dy) * 21 + tx + dx];
  float acc[8];
#pragma unroll
  for (int o = 0; o < 8; ++o) {
    const float* wo = wgt + (size_t)(ocb + o) * 25;
    float a = 0.f;
#pragma unroll
    for (int t = 0; t < 25; ++t) a = fmaf(tv[t], wo[t], a);
    acc[o] = a;
  }
  int oy = tileY + ty, ox = tileX + tx;
  if (oy < 120) {
    size_t base = (((size_t)b * 120 + oy) * 64 + ox) * 64 + ocb;
    ushort4 p0, p1;
    p0.x = f2h(acc[0]); p0.y = f2h(acc[1]); p0.z = f2h(acc[2]); p0.w = f2h(acc[3]);
    p1.x = f2h(acc[4]); p1.y = f2h(acc[5]); p1.z = f2h(acc[6]); p1.w = f2h(acc[7]);
    *(ushort4*)(out + base) = p0;
    *(ushort4*)(out + base + 4) = p1;
  }
}

// ---------------------------------------------- MFMA implicit-GEMM 5x5 conv
// NHWC fp16. Wave: 4 M-tiles (64 oc) x NT N-tiles (16 px each).
// Block covers WGR rows x TC cols (TC <= W; grid x = (H/WGR)*(W/TC)).
// LDS: 80B slot per pixel (slot=px*5+q4): B-reads (5px+q)%8 injective ->
// conflict-free; staging writes ~conflict-free; addresses fold to ds offset
// immediates (runtime-XOR swizzles spill — round 9/10 lesson).
template <int CIN, int H, int W, int TC, int NT, int OC, bool PREBN>
__global__ __launch_bounds__(256, 4) void k_convM(const unsigned short* __restrict__ in,
                                                  const unsigned short* __restrict__ wt,
                                                  unsigned short* __restrict__ out,
                                                  const float* __restrict__ pst,
                                                  const float* __restrict__ pg,
                                                  const float* __restrict__ pbe) {
  constexpr int XC = TC / 16, RPW = NT / XC, WGR = 4 * RPW;
  constexpr int LW = TC + 4, LR = WGR + 4, NPX = LR * LW;
  constexpr int NXC = W / TC;
  constexpr int MTS = (CIN / 32) * 512;       // per-mt frag stride (halfwords)
  constexpr int TS = (OC / 16) * MTS;         // per-tap frag stride
  __shared__ unsigned short lds[NPX * 40];    // 80B per pixel
  int tid = threadIdx.x;
  int w = tid >> 6, lane = tid & 63, l15 = lane & 15, q = lane >> 4;
  int q4 = tid & 3;
  int ry = blockIdx.x / NXC, cx = blockIdx.x % NXC;
  int y0 = ry * WGR, x0 = cx * TC;
  int b = blockIdx.y, oc0 = blockIdx.z * 64;
  int z4 = blockIdx.z * 4;
  int lofs = (l15 * 4 + q) * 8;
  f32x4 acc[4][NT];
#pragma unroll
  for (int mt = 0; mt < 4; ++mt)
#pragma unroll
    for (int nt = 0; nt < NT; ++nt) acc[mt][nt] = 0.f;

  for (int icb = 0; icb < CIN / 32; ++icb) {
    float s8[8], a8[8];
    if (PREBN) {
      int cb = icb * 32 + q4 * 8;
#pragma unroll
      for (int j = 0; j < 8; ++j) {
        float m = pst[cb + j], iv = pst[CIN + cb + j];
        s8[j] = pg[cb + j] * iv;
        a8[j] = pbe[cb + j] - m * s8[j];
      }
    }
    __syncthreads();
    for (int e = tid; e < NPX * 4; e += 256) {
      int px = e >> 2;                 // e&3 == q4 (invariant per thread)
      int lr = px / LW, c = px % LW;
      int y = y0 - 2 + lr, x = x0 - 2 + c;
      f16x8 v = (f16x8)0;
      if ((unsigned)y < (unsigned)H && (unsigned)x < (unsigned)W) {
        v = *(const f16x8*)(in + (((size_t)b * H + y) * W + x) * CIN + icb * 32 + q4 * 8);
        if (PREBN) {
#pragma unroll
          for (int j = 0; j < 8; ++j) {
            float f = fmaf((float)v[j], s8[j], a8[j]);
            v[j] = (_Float16)(f > 0.f ? f : 0.f);
          }
        }
      }
      *(f16x8*)&lds[(size_t)(px * 5 + q4) * 8] = v;
    }
    __syncthreads();
    const unsigned short* wbase = wt + (size_t)icb * 512 + lofs;
    f16x8 avn[4];
#pragma unroll
    for (int mt = 0; mt < 4; ++mt)
      avn[mt] = *(const f16x8*)(wbase + (size_t)(z4 + mt) * MTS);
#pragma unroll
    for (int t = 0; t < 25; ++t) {
      int dy = t / 5, dx = t % 5;
      f16x8 avc[4];
#pragma unroll
      for (int mt = 0; mt < 4; ++mt) avc[mt] = avn[mt];
      if (t < 24) {
#pragma unroll
        for (int mt = 0; mt < 4; ++mt)
          avn[mt] = *(const f16x8*)(wbase + (size_t)(t + 1) * TS + (size_t)(z4 + mt) * MTS);
      }
#pragma unroll
      for (int nt = 0; nt < NT; ++nt) {
        int lr = w * RPW + nt / XC + dy;
        int c = (nt % XC) * 16 + l15 + dx;
        f16x8 bv = *(const f16x8*)&lds[(size_t)((lr * LW + c) * 5 + q) * 8];
#pragma unroll
        for (int mt = 0; mt < 4; ++mt)
          acc[mt][nt] = __builtin_amdgcn_mfma_f32_16x16x32_f16(avc[mt], bv, acc[mt][nt], 0, 0, 0);
      }
    }
  }
#pragma unroll
  for (int nt = 0; nt < NT; ++nt) {
    int y = y0 + w * RPW + nt / XC;
    if (y >= H) continue;
    int x = x0 + (nt % XC) * 16 + l15;
    size_t pbase = (((size_t)b * H + y) * W + x) * OC + oc0 + q * 4;
#pragma unroll
    for (int mt = 0; mt < 4; ++mt) {
      ushort4 pk;
      pk.x = f2h(acc[mt][nt][0]);
      pk.y = f2h(acc[mt][nt][1]);
      pk.z = f2h(acc[mt][nt][2]);
      pk.w = f2h(acc[mt][nt][3]);
      *(ushort4*)(out + pbase + mt * 16) = pk;
    }
  }
}

// ------------------- BN stats, vectorized f16x8 (fully coalesced 1KB/wave)
template <int C>
__global__ __launch_bounds__(256) void k_bnstatsv(const unsigned short* __restrict__ x,
                                                  float* __restrict__ acc,
                                                  int nIter) {
  constexpr int CV = C / 8, KPB = 256 / CV;
  __shared__ float r1[256][8], r2[256][8];
  int tid = threadIdx.x;
  int cv = tid % CV, kq = tid / CV;
  size_t row0 = (size_t)blockIdx.x * (KPB * nIter) + kq;
  const unsigned short* p = x + row0 * C + cv * 8;
  float s1[8], s2[8];
#pragma unroll
  for (int j = 0; j < 8; ++j) { s1[j] = 0.f; s2[j] = 0.f; }
  for (int it = 0; it < nIter; ++it) {
    f16x8 v = *(const f16x8*)(p + (size_t)it * KPB * C);
#pragma unroll
    for (int j = 0; j < 8; ++j) {
      float f = (float)v[j];
      s1[j] += f;
      s2[j] += f * f;
    }
  }
#pragma unroll
  for (int j = 0; j < 8; ++j) { r1[tid][j] = s1[j]; r2[tid][j] = s2[j]; }
  __syncthreads();
  if (tid < C) {
    int cv0 = tid >> 3, e = tid & 7;
    float t1 = 0.f, t2 = 0.f;
    for (int k = 0; k < KPB; ++k) {
      t1 += r1[k * CV + cv0][e];
      t2 += r2[k * CV + cv0][e];
    }
    atomicAdd(&acc[tid], t1);
    atomicAdd(&acc[C + tid], t2);
  }
}

__global__ __launch_bounds__(256) void k_bnfin(const float* __restrict__ acc,
                                               float* __restrict__ stats,
                                               int C, float invN) {
  int c = threadIdx.x + blockIdx.x * 256;
  if (c >= C) return;
  float m = acc[c] * invN;
  float v = acc[C + c] * invN - m * m;
  stats[c] = m;
  stats[C + c] = rsqrtf(v + 1e-5f);
}

// --------------------------------------- BN+ReLU+maxpool2 NHWC (x8 vec)
template <int C, int H, int W>
__global__ __launch_bounds__(256) void k_brp(const unsigned short* __restrict__ x,
                                             unsigned short* __restrict__ y,
                                             const float* __restrict__ stats,
                                             const float* __restrict__ g,
                                             const float* __restrict__ be) {
  constexpr int OH = H / 2, OW = W / 2, CV = C / 8;
  int idx = blockIdx.x * 256 + threadIdx.x;   // [b][oy][ox][cv]
  int cv = idx % CV;
  int t = idx / CV;
  int ox = t % OW; t /= OW;
  int oy = t % OH;
  int b = t / OH;
  int c0 = cv * 8;
  const unsigned short* p = x + ((size_t)(b * H + oy * 2) * W + ox * 2) * C + c0;
  f16x8 v00 = *(const f16x8*)p;
  f16x8 v01 = *(const f16x8*)(p + C);
  f16x8 v10 = *(const f16x8*)(p + (size_t)W * C);
  f16x8 v11 = *(const f16x8*)(p + (size_t)W * C + C);
  f16x8 r;
#pragma unroll
  for (int j = 0; j < 8; ++j) {
    int c = c0 + j;
    float m = stats[c], iv = stats[C + c], gg = g[c], bb = be[c];
    float f0 = gg * (((float)v00[j] - m) * iv) + bb;
    float f1 = gg * (((float)v01[j] - m) * iv) + bb;
    float f2 = gg * (((float)v10[j] - m) * iv) + bb;
    float f3 = gg * (((float)v11[j] - m) * iv) + bb;
    f0 = f0 > 0.f ? f0 : 0.f;
    f1 = f1 > 0.f ? f1 : 0.f;
    f2 = f2 > 0.f ? f2 : 0.f;
    f3 = f3 > 0.f ? f3 : 0.f;
    float r01 = f0 > f1 ? f0 : f1;
    float r23 = f2 > f3 ? f2 : f3;
    r[j] = (_Float16)(r01 > r23 ? r01 : r23);
  }
  *(f16x8*)(y + (size_t)idx * 8) = r;
}

// ---- stage-3 BN+ReLU+pool + write into batch-major fc1 activations (fp16)
__global__ __launch_bounds__(256) void k_brp3t(const unsigned short* __restrict__ x,
                                               unsigned short* __restrict__ actT,
                                               const float* __restrict__ stats,
                                               const float* __restrict__ g,
                                               const float* __restrict__ be) {
  __shared__ float tile[64 * 65];
  int s = blockIdx.x;
  int oy = s >> 3, ox = s & 7;
  int ci = threadIdx.x & 63, bq = threadIdx.x >> 6;
  for (int cs = 0; cs < 4; ++cs) {
    int c = cs * 64 + ci;
    float m = stats[c], iv = stats[256 + c], gg = g[c], bb = be[c];
    __syncthreads();
    for (int b = bq; b < 64; b += 4) {
      float mx = 0.f;
#pragma unroll
      for (int qq = 0; qq < 4; ++qq) {
        int yy = oy * 2 + (qq >> 1), xx = ox * 2 + (qq & 1);
        float v = h2f(x[((size_t)(b * 30 + yy) * 16 + xx) * 256 + c]);
        v = gg * ((v - m) * iv) + bb;
        v = v > 0.f ? v : 0.f;
        mx = v > mx ? v : mx;
      }
      tile[ci * 65 + b] = mx;
    }
    __syncthreads();
    for (int e = threadIdx.x; e < 4096; e += 256) {
      int cc = e >> 6, bb2 = e & 63;
      actT[(size_t)bb2 * 30784 + 64 + (cs * 64 + cc) * 120 + s] = f2h(tile[cc * 65 + bb2]);
    }
  }
}

// -------------------- q rows of fc inputs + zero fc1 accumulator + BN accums
__global__ __launch_bounds__(256) void k_qinit(const float* __restrict__ q,
                                               unsigned short* __restrict__ actT,
                                               float* __restrict__ in2T,
                                               float* __restrict__ in3T,
                                               float* __restrict__ z1pre,
                                               float* __restrict__ bnacc) {
  int idx = blockIdx.x * 256 + threadIdx.x;
  if (idx < 32000) z1pre[idx] = 0.f;
  else if (idx < 33024) bnacc[idx - 32000] = 0.f;
  if (idx >= 4096) return;
  int b = idx >> 6, i = idx & 63;
  float v = q[idx];
  actT[(size_t)b * 30784 + i] = f2h(v);
  in2T[i * 64 + b] = v;
  in3T[i * 64 + b] = v;
}

// --------------------------------------------------------- fc1 (MFMA GEMM)
__global__ __launch_bounds__(256) void k_fc1m(const unsigned short* __restrict__ actT,
                                              const float* __restrict__ wgt,
                                              float* __restrict__ z1pre) {
  constexpr int IN = 30784;
  constexpr int KSTEPS = IN / 32;   // 962
  __shared__ float part[4][16][64];
  int tid = threadIdx.x;
  int w = tid >> 6, lane = tid & 63, l15 = lane & 15, q = lane >> 4;
  int ob = blockIdx.x * 16;
  int row = ob + l15; if (row > 499) row = 499;
  int kw = blockIdx.y * 4 + w;      // 0..31
  f32x4 acc[4];
#pragma unroll
  for (int nt = 0; nt < 4; ++nt) acc[nt] = 0.f;
  for (int s = kw; s < KSTEPS; s += 32) {
    int k0 = s * 32;
    const float4* wp = (const float4*)(wgt + (size_t)row * IN + k0 + q * 8);
    float4 wa = wp[0], wb = wp[1];
    f16x8 a;
    a[0] = (_Float16)wa.x; a[1] = (_Float16)wa.y;
    a[2] = (_Float16)wa.z; a[3] = (_Float16)wa.w;
    a[4] = (_Float16)wb.x; a[5] = (_Float16)wb.y;
    a[6] = (_Float16)wb.z; a[7] = (_Float16)wb.w;
#pragma unroll
    for (int nt = 0; nt < 4; ++nt) {
      f16x8 bv = *(const f16x8*)(actT + (size_t)(nt * 16 + l15) * IN + k0 + q * 8);
      acc[nt] = __builtin_amdgcn_mfma_f32_16x16x32_f16(a, bv, acc[nt], 0, 0, 0);
    }
  }
#pragma unroll
  for (int nt = 0; nt < 4; ++nt)
#pragma unroll
    for (int reg = 0; reg < 4; ++reg)
      part[w][q * 4 + reg][nt * 16 + l15] = acc[nt][reg];
  __syncthreads();
  for (int e = tid; e < 1024; e += 256) {
    int m = e >> 6, n = e & 63;
    float sum = part[0][m][n] + part[1][m][n] + part[2][m][n] + part[3][m][n];
    int o = ob + m;
    if (o < 500) atomicAdd(&z1pre[o * 64 + n], sum);
  }
}

__global__ __launch_bounds__(256) void k_fc1ep(const float* __restrict__ z1pre,
                                               const float* __restrict__ bias,
                                               float* __restrict__ in2T) {
  int idx = blockIdx.x * 256 + threadIdx.x;
  if (idx >= 500 * 64) return;
  int o = idx >> 6;
  float v = z1pre[idx] + bias[o];
  in2T[idx + 64 * 64] = v > 0.f ? v : 0.f;
}

__global__ __launch_bounds__(256) void k_fc_small(const float* __restrict__ inT,
                                                  const float* __restrict__ wgt,
                                                  const float* __restrict__ bias,
                                                  float* __restrict__ out,
                                                  int IN, int mode) {
  __shared__ float part[4][64];
  int o = blockIdx.x;
  int lane = threadIdx.x & 63, w = threadIdx.x >> 6;
  float acc = 0.f;
  for (int i = w; i < IN; i += 4)
    acc = fmaf(inT[(size_t)i * 64 + lane], wgt[(size_t)o * IN + i], acc);
  part[w][lane] = acc;
  __syncthreads();
  if (threadIdx.x < 64) {
    float s = part[0][lane] + part[1][lane] + part[2][lane] + part[3][lane] + bias[o];
    if (mode == 0) {
      s = s > 0.f ? s : 0.f;
      out[(64 + o) * 64 + lane] = s;
    } else {
      out[lane * 2 + o] = s;
    }
  }
}

// ============================================================================
extern "C" void kernel_launch(void* const* d_in, const int* in_sizes, int n_in,
                              void* d_out, int out_size, void* d_ws, size_t ws_size,
                              hipStream_t stream) {
  const float* x      = (const float*)d_in[0];
  const float* qvec   = (const float*)d_in[1];
  const float* basis  = (const float*)d_in[2];
  const float* w1a    = (const float*)d_in[3];
  const float* g1a    = (const float*)d_in[5];
  const float* be1a   = (const float*)d_in[6];
  const float* w1b    = (const float*)d_in[7];
  const float* g1b    = (const float*)d_in[9];
  const float* be1b   = (const float*)d_in[10];
  const float* w2a    = (const float*)d_in[11];
  const float* g2a    = (const float*)d_in[13];
  const float* be2a   = (const float*)d_in[14];
  const float* w3a    = (const float*)d_in[15];
  const float* g3a    = (const float*)d_in[17];
  const float* be3a   = (const float*)d_in[18];
  const float* fc1w   = (const float*)d_in[19];
  const float* fc1b   = (const float*)d_in[20];
  const float* fc2w   = (const float*)d_in[21];
  const float* fc2b   = (const float*)d_in[22];
  const float* fc3w   = (const float*)d_in[23];
  const float* fc3b   = (const float*)d_in[24];
  float* out = (float*)d_out;

  char* base = (char*)d_ws;
  constexpr size_t ARENA = 62914560;
  char* arenaA = base;
  char* arenaB = base + ARENA;
  char* sm     = base + 2 * ARENA;

  float*          xd   = (float*)arenaA;
  unsigned short* A    = (unsigned short*)arenaA;  // pre1a NHWC [64][120][64][64] (raw)
  unsigned short* P1   = (unsigned short*)arenaA;  // [64][60][32][64]
  unsigned short* P2   = (unsigned short*)arenaA;  // [64][30][16][128]
  unsigned short* actT = (unsigned short*)arenaA;  // [64][30784] fp16

  float*          feat = (float*)arenaB;           // [64][120][64] fp32
  unsigned short* Bb   = (unsigned short*)arenaB;  // pre1b [64][120][64][64]
  unsigned short* C2   = (unsigned short*)arenaB;  // [64][60][32][128]
  unsigned short* D3   = (unsigned short*)arenaB;  // [64][30][16][256]

  float* in2T = (float*)sm;                    // 144,384 B
  float* in3T = (float*)(sm + 144384);         // 144,384 B
  float* z1p  = (float*)(sm + 288768);         // 128,000 B
  float* ACC  = (float*)(sm + 416768);         // 4,096 B
  float* S1A  = (float*)(sm + 420864);
  float* S1B  = (float*)(sm + 421376);
  float* S2A  = (float*)(sm + 421888);
  float* S3A  = (float*)(sm + 422912);
  unsigned short* WT1 = (unsigned short*)(sm + 424960);   // 204,800 B
  unsigned short* WT2 = (unsigned short*)(sm + 834560);   // 409,600 B
  unsigned short* WT3 = (unsigned short*)(sm + 1653760);  // 1,638,400 B

  k_qinit<<<130, 256, 0, stream>>>(qvec, actT, in2T, in3T, z1p, ACC);
  k_prepw<<<400, 256, 0, stream>>>(w1b, WT1, 64, 64);
  k_prepw<<<800, 256, 0, stream>>>(w2a, WT2, 128, 64);
  k_prepw<<<3200, 256, 0, stream>>>(w3a, WT3, 256, 128);

  k_dct<<<64 * 8, 256, 0, stream>>>(x, basis, xd);
  k_hist<<<4096, 256, 0, stream>>>(xd, feat);

  // conv1a (direct) -> A (raw pre-activations), stats over A
  k_conv1a<<<dim3(32, 64, 8), 256, 0, stream>>>(feat, w1a, A);
  k_bnstatsv<64><<<240, 256, 0, stream>>>(A, ACC, 64);
  k_bnfin<<<1, 64, 0, stream>>>(ACC, S1A, 64, 1.f / 491520.f);

  // conv1b (MFMA, TC=32: 8x32 blocks, LDS 34560 => 4 blocks/CU) -> Bb
  k_convM<64, 120, 64, 32, 4, 64, true><<<dim3(30, 64, 1), 256, 0, stream>>>(
      A, WT1, Bb, S1A, g1a, be1a);
  k_bnstatsv<64><<<240, 256, 0, stream>>>(Bb, ACC + 128, 64);
  k_bnfin<<<1, 64, 0, stream>>>(ACC + 128, S1B, 64, 1.f / 491520.f);
  k_brp<64, 120, 64><<<3840, 256, 0, stream>>>(Bb, P1, S1B, g1b, be1b);

  // conv2a -> C2, stats, pool -> P2
  k_convM<64, 60, 32, 32, 4, 128, false><<<dim3(8, 64, 2), 256, 0, stream>>>(
      P1, WT2, C2, S1A, g1a, be1a);
  k_bnstatsv<128><<<240, 256, 0, stream>>>(C2, ACC + 256, 32);
  k_bnfin<<<1, 128, 0, stream>>>(ACC + 256, S2A, 128, 1.f / 122880.f);
  k_brp<128, 60, 32><<<1920, 256, 0, stream>>>(C2, P2, S2A, g2a, be2a);

  // conv3a (NT=2 => 1024 blocks, LDS 19200) -> D3, stats, pool+transpose
  k_convM<128, 30, 16, 16, 2, 256, false><<<dim3(4, 64, 4), 256, 0, stream>>>(
      P2, WT3, D3, S1A, g1a, be1a);
  k_bnstatsv<256><<<240, 256, 0, stream>>>(D3, ACC + 512, 16);
  k_bnfin<<<1, 256, 0, stream>>>(ACC + 512, S3A, 256, 1.f / 30720.f);
  k_qinit<<<130, 256, 0, stream>>>(qvec, actT, in2T, in3T, z1p, ACC);
  k_brp3t<<<120, 256, 0, stream>>>(D3, actT, S3A, g3a, be3a);

  // FC head
  k_fc1m<<<dim3(32, 8), 256, 0, stream>>>(actT, fc1w, z1p);
  k_fc1ep<<<125, 256, 0, stream>>>(z1p, fc1b, in2T);
  k_fc_small<<<500, 256, 0, stream>>>(in2T, fc2w, fc2b, in3T, 564, 0);
  k_fc_small<<<2, 256, 0, stream>>>(in3T, fc3w, fc3b, out, 564, 1);
}

// Round 5
// 935.700 us; speedup vs baseline: 1.1645x; 1.0711x over previous
//
#include <hip/hip_runtime.h>
#include <math.h>

// ============================================================================
// DoubleJpeg round 12: EXACT round-8 (945us) convM body + configs restored.
// Root-cause note: any convM variant whose LDS fits 4 blocks/CU (34816B:
// r2 swizzle, r3 swizzle, r4 TC=32 -- and round-8's own conv2a!) compiles to
// VGPR=64 (allocator targets 4 blocks/CU occupancy; acc alone needs 64) and
// spills ~500MB of scratch traffic. Fix: __launch_bounds__(256,3) raises the
// per-wave budget to ~170 regs -> no spill; conv2a can still reach 4 blocks
// at ~104 regs. conv1b (LDS 43520, 3 blocks) unchanged structurally.
// Also: conv3a NT=2 grid(4,64,4) -> 1024 blocks (was 512 = 2/CU grid-starved).
// ============================================================================

typedef __attribute__((ext_vector_type(8))) _Float16 f16x8;
typedef __attribute__((ext_vector_type(4))) float f32x4;

#define GAMMA_F 1.0e6f

__device__ __forceinline__ unsigned short f2h(float f) {
  _Float16 h = (_Float16)f;
  union { _Float16 h; unsigned short u; } x; x.h = h; return x.u;
}
__device__ __forceinline__ float h2f(unsigned short u) {
  union { unsigned short u; _Float16 h; } x; x.u = u; return (float)x.h;
}

// ---------------------------------------------------------------- DCT kernel
__global__ __launch_bounds__(256) void k_dct(const float* __restrict__ x,
                                             const float* __restrict__ basis,
                                             float* __restrict__ xd) {
  __shared__ float bT[4096];
  __shared__ float pix[4][64];
  int tid = threadIdx.x;
  for (int e = tid; e < 4096; e += 256)
    bT[e] = basis[(e & 63) * 64 + (e >> 6)];
  __syncthreads();
  int w = tid >> 6, lane = tid & 63;
  int b = blockIdx.x >> 3;
  int br = ((blockIdx.x & 7) << 2) + w;
  const float* xb = x + (size_t)b * 65536;
  float* xdb = xd + (size_t)b * 65536;
  for (int bc = 0; bc < 32; ++bc) {
    __syncthreads();
    pix[w][lane] = xb[(br * 8 + (lane >> 3)) * 256 + bc * 8 + (lane & 7)];
    __syncthreads();
    float acc = 0.f;
#pragma unroll
    for (int p = 0; p < 64; ++p)
      acc = fmaf(bT[p * 64 + lane], pix[w][p], acc);
    xdb[lane * 1024 + br * 32 + bc] = acc;
  }
}

// ------------------------------- counting soft histogram (no atomics) -> feat
__global__ __launch_bounds__(256) void k_hist(const float* __restrict__ xd,
                                              float* __restrict__ feat) {
  __shared__ float px[1024];
  __shared__ float part[242];
  __shared__ float tot[121];
  int tid = threadIdx.x;
  int bc = blockIdx.x;
  int b = bc >> 6, c = bc & 63;
  const float* p = xd + (size_t)bc * 1024;
  for (int e = tid; e < 1024; e += 256) px[e] = p[e];
  __syncthreads();
  if (tid < 242) {
    int j = tid >> 1;
    float bj = (float)(j - 60);
    int i0 = (tid & 1) * 512;
    float cnt = 0.f;
    for (int i = i0; i < i0 + 512; ++i) {
      float d = px[i] - bj;
      float step = d > 0.f ? 1.f : 0.f;
      cnt += step;
      if (fabsf(d) < 2e-5f)
        cnt += 1.f / (1.f + expf(-GAMMA_F * d)) - step;
    }
    part[tid] = cnt;
  }
  __syncthreads();
  if (tid < 121) tot[tid] = part[2 * tid] + part[2 * tid + 1];
  __syncthreads();
  if (tid < 120)
    feat[((size_t)b * 120 + tid) * 64 + c] = (tot[tid] - tot[tid + 1]) * (1.f / 1024.f);
}

// --------------- weight prep: fp32 -> fp16, fragment-major layout
// out: wt[((t*(OC/16)+mt)*(IC/32)+icb)*512 + l15*32 + q*8 + j]
//    = w[oc=mt*16+l15][ic=icb*32+q*8+j][t]
__global__ __launch_bounds__(256) void k_prepw(const float* __restrict__ w,
                                               unsigned short* __restrict__ wt,
                                               int OC, int IC) {
  int n = OC * IC * 25;
  int idx = blockIdx.x * 256 + threadIdx.x;
  if (idx >= n) return;
  int j = idx & 7;
  int q = (idx >> 3) & 3;
  int l15 = (idx >> 5) & 15;
  int r = idx >> 9;
  int icb = r % (IC / 32);
  int r2 = r / (IC / 32);
  int mt = r2 % (OC / 16);
  int t = r2 / (OC / 16);
  int oc = mt * 16 + l15;
  int ic = icb * 32 + q * 8 + j;
  wt[idx] = f2h(w[((size_t)oc * IC + ic) * 25 + t]);
}

// ----------------------------------------------- conv1a (CIN=1), direct fp32
__global__ __launch_bounds__(256) void k_conv1a(const float* __restrict__ in,
                                                const float* __restrict__ wgt,
                                                unsigned short* __restrict__ out) {
  __shared__ float tile[20 * 21];
  int tx = threadIdx.x & 15, ty = threadIdx.x >> 4;
  int tileX = (blockIdx.x & 3) * 16, tileY = (blockIdx.x >> 2) * 16;
  int b = blockIdx.y, ocb = blockIdx.z * 8;
  const float* inc = in + (size_t)b * 7680;
  for (int e = threadIdx.x; e < 400; e += 256) {
    int ly = e / 20, lx = e % 20;
    int gy = tileY - 2 + ly, gx = tileX - 2 + lx;
    float v = 0.f;
    if ((unsigned)gy < 120u && (unsigned)gx < 64u) v = inc[gy * 64 + gx];
    tile[ly * 21 + lx] = v;
  }
  __syncthreads();
  float tv[25];
#pragma unroll
  for (int dy = 0; dy < 5; ++dy)
#pragma unroll
    for (int dx = 0; dx < 5; ++dx)
      tv[dy * 5 + dx] = tile[(ty + dy) * 21 + tx + dx];
  float acc[8];
#pragma unroll
  for (int o = 0; o < 8; ++o) {
    const float* wo = wgt + (size_t)(ocb + o) * 25;
    float a = 0.f;
#pragma unroll
    for (int t = 0; t < 25; ++t) a = fmaf(tv[t], wo[t], a);
    acc[o] = a;
  }
  int oy = tileY + ty, ox = tileX + tx;
  if (oy < 120) {
    size_t base = (((size_t)b * 120 + oy) * 64 + ox) * 64 + ocb;
    ushort4 p0, p1;
    p0.x = f2h(acc[0]); p0.y = f2h(acc[1]); p0.z = f2h(acc[2]); p0.w = f2h(acc[3]);
    p1.x = f2h(acc[4]); p1.y = f2h(acc[5]); p1.z = f2h(acc[6]); p1.w = f2h(acc[7]);
    *(ushort4*)(out + base) = p0;
    *(ushort4*)(out + base + 4) = p1;
  }
}

// ---------------------------------------------- MFMA implicit-GEMM 5x5 conv
// NHWC fp16. Wave: 4 M-tiles (64 oc) x NT N-tiles (16 px each).
// LDS: 80B slot per pixel (slot=px*5+q4): B-reads (5px+q)%8 injective ->
// conflict-free; staging writes ~conflict-free. Weights fragment-major ->
// each A-frag load is 1KB contiguous. Addresses fold to ds offset immediates.
// launch_bounds(256,3): ~170-reg budget so the W=32 geometry (LDS 34816,
// 4 blocks/CU) doesn't get strangled to 64 arch VGPRs + scratch spill.
template <int CIN, int H, int W, int NT, int OC, bool PREBN>
__global__ __launch_bounds__(256, 3) void k_convM(const unsigned short* __restrict__ in,
                                                  const unsigned short* __restrict__ wt,
                                                  unsigned short* __restrict__ out,
                                                  const float* __restrict__ pst,
                                                  const float* __restrict__ pg,
                                                  const float* __restrict__ pbe) {
  constexpr int XC = W / 16, RPW = NT / XC, WGR = 4 * RPW;
  constexpr int LW = W + 4, LR = WGR + 4, NPX = LR * LW;
  constexpr int MTS = (CIN / 32) * 512;       // per-mt frag stride (halfwords)
  constexpr int TS = (OC / 16) * MTS;         // per-tap frag stride
  __shared__ unsigned short lds[NPX * 40];    // 80B per pixel
  int tid = threadIdx.x;
  int w = tid >> 6, lane = tid & 63, l15 = lane & 15, q = lane >> 4;
  int q4 = tid & 3;
  int y0 = blockIdx.x * WGR, b = blockIdx.y, oc0 = blockIdx.z * 64;
  int z4 = blockIdx.z * 4;
  int lofs = (l15 * 4 + q) * 8;
  f32x4 acc[4][NT];
#pragma unroll
  for (int mt = 0; mt < 4; ++mt)
#pragma unroll
    for (int nt = 0; nt < NT; ++nt) acc[mt][nt] = 0.f;

  for (int icb = 0; icb < CIN / 32; ++icb) {
    float s8[8], a8[8];
    if (PREBN) {
      int cb = icb * 32 + q4 * 8;
#pragma unroll
      for (int j = 0; j < 8; ++j) {
        float m = pst[cb + j], iv = pst[CIN + cb + j];
        s8[j] = pg[cb + j] * iv;
        a8[j] = pbe[cb + j] - m * s8[j];
      }
    }
    __syncthreads();
    for (int e = tid; e < NPX * 4; e += 256) {
      int px = e >> 2;                 // e&3 == q4 (invariant per thread)
      int lr = px / LW, c = px % LW;
      int y = y0 - 2 + lr, x = c - 2;
      f16x8 v = (f16x8)0;
      if ((unsigned)y < (unsigned)H && (unsigned)x < (unsigned)W) {
        v = *(const f16x8*)(in + (((size_t)b * H + y) * W + x) * CIN + icb * 32 + q4 * 8);
        if (PREBN) {
#pragma unroll
          for (int j = 0; j < 8; ++j) {
            float f = fmaf((float)v[j], s8[j], a8[j]);
            v[j] = (_Float16)(f > 0.f ? f : 0.f);
          }
        }
      }
      *(f16x8*)&lds[(size_t)(px * 5 + q4) * 8] = v;
    }
    __syncthreads();
    const unsigned short* wbase = wt + (size_t)icb * 512 + lofs;
    f16x8 avn[4];
#pragma unroll
    for (int mt = 0; mt < 4; ++mt)
      avn[mt] = *(const f16x8*)(wbase + (size_t)(z4 + mt) * MTS);
#pragma unroll
    for (int t = 0; t < 25; ++t) {
      int dy = t / 5, dx = t % 5;
      f16x8 avc[4];
#pragma unroll
      for (int mt = 0; mt < 4; ++mt) avc[mt] = avn[mt];
      if (t < 24) {
#pragma unroll
        for (int mt = 0; mt < 4; ++mt)
          avn[mt] = *(const f16x8*)(wbase + (size_t)(t + 1) * TS + (size_t)(z4 + mt) * MTS);
      }
#pragma unroll
      for (int nt = 0; nt < NT; ++nt) {
        int lr = w * RPW + nt / XC + dy;
        int c = (nt % XC) * 16 + l15 + dx;
        f16x8 bv = *(const f16x8*)&lds[(size_t)((lr * LW + c) * 5 + q) * 8];
#pragma unroll
        for (int mt = 0; mt < 4; ++mt)
          acc[mt][nt] = __builtin_amdgcn_mfma_f32_16x16x32_f16(avc[mt], bv, acc[mt][nt], 0, 0, 0);
      }
    }
  }
#pragma unroll
  for (int nt = 0; nt < NT; ++nt) {
    int y = y0 + w * RPW + nt / XC;
    if (y >= H) continue;
    int x = (nt % XC) * 16 + l15;
    size_t pbase = (((size_t)b * H + y) * W + x) * OC + oc0 + q * 4;
#pragma unroll
    for (int mt = 0; mt < 4; ++mt) {
      ushort4 pk;
      pk.x = f2h(acc[mt][nt][0]);
      pk.y = f2h(acc[mt][nt][1]);
      pk.z = f2h(acc[mt][nt][2]);
      pk.w = f2h(acc[mt][nt][3]);
      *(ushort4*)(out + pbase + mt * 16) = pk;
    }
  }
}

// ------------------- BN stats, vectorized f16x8 (fully coalesced 1KB/wave)
template <int C>
__global__ __launch_bounds__(256) void k_bnstatsv(const unsigned short* __restrict__ x,
                                                  float* __restrict__ acc,
                                                  int nIter) {
  constexpr int CV = C / 8, KPB = 256 / CV;
  __shared__ float r1[256][8], r2[256][8];
  int tid = threadIdx.x;
  int cv = tid % CV, kq = tid / CV;
  size_t row0 = (size_t)blockIdx.x * (KPB * nIter) + kq;
  const unsigned short* p = x + row0 * C + cv * 8;
  float s1[8], s2[8];
#pragma unroll
  for (int j = 0; j < 8; ++j) { s1[j] = 0.f; s2[j] = 0.f; }
  for (int it = 0; it < nIter; ++it) {
    f16x8 v = *(const f16x8*)(p + (size_t)it * KPB * C);
#pragma unroll
    for (int j = 0; j < 8; ++j) {
      float f = (float)v[j];
      s1[j] += f;
      s2[j] += f * f;
    }
  }
#pragma unroll
  for (int j = 0; j < 8; ++j) { r1[tid][j] = s1[j]; r2[tid][j] = s2[j]; }
  __syncthreads();
  if (tid < C) {
    int cv0 = tid >> 3, e = tid & 7;
    float t1 = 0.f, t2 = 0.f;
    for (int k = 0; k < KPB; ++k) {
      t1 += r1[k * CV + cv0][e];
      t2 += r2[k * CV + cv0][e];
    }
    atomicAdd(&acc[tid], t1);
    atomicAdd(&acc[C + tid], t2);
  }
}

__global__ __launch_bounds__(256) void k_bnfin(const float* __restrict__ acc,
                                               float* __restrict__ stats,
                                               int C, float invN) {
  int c = threadIdx.x + blockIdx.x * 256;
  if (c >= C) return;
  float m = acc[c] * invN;
  float v = acc[C + c] * invN - m * m;
  stats[c] = m;
  stats[C + c] = rsqrtf(v + 1e-5f);
}

// --------------------------------------- BN+ReLU+maxpool2 NHWC (x8 vec)
template <int C, int H, int W>
__global__ __launch_bounds__(256) void k_brp(const unsigned short* __restrict__ x,
                                             unsigned short* __restrict__ y,
                                             const float* __restrict__ stats,
                                             const float* __restrict__ g,
                                             const float* __restrict__ be) {
  constexpr int OH = H / 2, OW = W / 2, CV = C / 8;
  int idx = blockIdx.x * 256 + threadIdx.x;   // [b][oy][ox][cv]
  int cv = idx % CV;
  int t = idx / CV;
  int ox = t % OW; t /= OW;
  int oy = t % OH;
  int b = t / OH;
  int c0 = cv * 8;
  const unsigned short* p = x + ((size_t)(b * H + oy * 2) * W + ox * 2) * C + c0;
  f16x8 v00 = *(const f16x8*)p;
  f16x8 v01 = *(const f16x8*)(p + C);
  f16x8 v10 = *(const f16x8*)(p + (size_t)W * C);
  f16x8 v11 = *(const f16x8*)(p + (size_t)W * C + C);
  f16x8 r;
#pragma unroll
  for (int j = 0; j < 8; ++j) {
    int c = c0 + j;
    float m = stats[c], iv = stats[C + c], gg = g[c], bb = be[c];
    float f0 = gg * (((float)v00[j] - m) * iv) + bb;
    float f1 = gg * (((float)v01[j] - m) * iv) + bb;
    float f2 = gg * (((float)v10[j] - m) * iv) + bb;
    float f3 = gg * (((float)v11[j] - m) * iv) + bb;
    f0 = f0 > 0.f ? f0 : 0.f;
    f1 = f1 > 0.f ? f1 : 0.f;
    f2 = f2 > 0.f ? f2 : 0.f;
    f3 = f3 > 0.f ? f3 : 0.f;
    float r01 = f0 > f1 ? f0 : f1;
    float r23 = f2 > f3 ? f2 : f3;
    r[j] = (_Float16)(r01 > r23 ? r01 : r23);
  }
  *(f16x8*)(y + (size_t)idx * 8) = r;
}

// ---- stage-3 BN+ReLU+pool + write into batch-major fc1 activations (fp16)
__global__ __launch_bounds__(256) void k_brp3t(const unsigned short* __restrict__ x,
                                               unsigned short* __restrict__ actT,
                                               const float* __restrict__ stats,
                                               const float* __restrict__ g,
                                               const float* __restrict__ be) {
  __shared__ float tile[64 * 65];
  int s = blockIdx.x;
  int oy = s >> 3, ox = s & 7;
  int ci = threadIdx.x & 63, bq = threadIdx.x >> 6;
  for (int cs = 0; cs < 4; ++cs) {
    int c = cs * 64 + ci;
    float m = stats[c], iv = stats[256 + c], gg = g[c], bb = be[c];
    __syncthreads();
    for (int b = bq; b < 64; b += 4) {
      float mx = 0.f;
#pragma unroll
      for (int qq = 0; qq < 4; ++qq) {
        int yy = oy * 2 + (qq >> 1), xx = ox * 2 + (qq & 1);
        float v = h2f(x[((size_t)(b * 30 + yy) * 16 + xx) * 256 + c]);
        v = gg * ((v - m) * iv) + bb;
        v = v > 0.f ? v : 0.f;
        mx = v > mx ? v : mx;
      }
      tile[ci * 65 + b] = mx;
    }
    __syncthreads();
    for (int e = threadIdx.x; e < 4096; e += 256) {
      int cc = e >> 6, bb2 = e & 63;
      actT[(size_t)bb2 * 30784 + 64 + (cs * 64 + cc) * 120 + s] = f2h(tile[cc * 65 + bb2]);
    }
  }
}

// -------------------- q rows of fc inputs + zero fc1 accumulator + BN accums
__global__ __launch_bounds__(256) void k_qinit(const float* __restrict__ q,
                                               unsigned short* __restrict__ actT,
                                               float* __restrict__ in2T,
                                               float* __restrict__ in3T,
                                               float* __restrict__ z1pre,
                                               float* __restrict__ bnacc) {
  int idx = blockIdx.x * 256 + threadIdx.x;
  if (idx < 32000) z1pre[idx] = 0.f;
  else if (idx < 33024) bnacc[idx - 32000] = 0.f;
  if (idx >= 4096) return;
  int b = idx >> 6, i = idx & 63;
  float v = q[idx];
  actT[(size_t)b * 30784 + i] = f2h(v);
  in2T[i * 64 + b] = v;
  in3T[i * 64 + b] = v;
}

// --------------------------------------------------------- fc1 (MFMA GEMM)
__global__ __launch_bounds__(256) void k_fc1m(const unsigned short* __restrict__ actT,
                                              const float* __restrict__ wgt,
                                              float* __restrict__ z1pre) {
  constexpr int IN = 30784;
  constexpr int KSTEPS = IN / 32;   // 962
  __shared__ float part[4][16][64];
  int tid = threadIdx.x;
  int w = tid >> 6, lane = tid & 63, l15 = lane & 15, q = lane >> 4;
  int ob = blockIdx.x * 16;
  int row = ob + l15; if (row > 499) row = 499;
  int kw = blockIdx.y * 4 + w;      // 0..31
  f32x4 acc[4];
#pragma unroll
  for (int nt = 0; nt < 4; ++nt) acc[nt] = 0.f;
  for (int s = kw; s < KSTEPS; s += 32) {
    int k0 = s * 32;
    const float4* wp = (const float4*)(wgt + (size_t)row * IN + k0 + q * 8);
    float4 wa = wp[0], wb = wp[1];
    f16x8 a;
    a[0] = (_Float16)wa.x; a[1] = (_Float16)wa.y;
    a[2] = (_Float16)wa.z; a[3] = (_Float16)wa.w;
    a[4] = (_Float16)wb.x; a[5] = (_Float16)wb.y;
    a[6] = (_Float16)wb.z; a[7] = (_Float16)wb.w;
#pragma unroll
    for (int nt = 0; nt < 4; ++nt) {
      f16x8 bv = *(const f16x8*)(actT + (size_t)(nt * 16 + l15) * IN + k0 + q * 8);
      acc[nt] = __builtin_amdgcn_mfma_f32_16x16x32_f16(a, bv, acc[nt], 0, 0, 0);
    }
  }
#pragma unroll
  for (int nt = 0; nt < 4; ++nt)
#pragma unroll
    for (int reg = 0; reg < 4; ++reg)
      part[w][q * 4 + reg][nt * 16 + l15] = acc[nt][reg];
  __syncthreads();
  for (int e = tid; e < 1024; e += 256) {
    int m = e >> 6, n = e & 63;
    float sum = part[0][m][n] + part[1][m][n] + part[2][m][n] + part[3][m][n];
    int o = ob + m;
    if (o < 500) atomicAdd(&z1pre[o * 64 + n], sum);
  }
}

__global__ __launch_bounds__(256) void k_fc1ep(const float* __restrict__ z1pre,
                                               const float* __restrict__ bias,
                                               float* __restrict__ in2T) {
  int idx = blockIdx.x * 256 + threadIdx.x;
  if (idx >= 500 * 64) return;
  int o = idx >> 6;
  float v = z1pre[idx] + bias[o];
  in2T[idx + 64 * 64] = v > 0.f ? v : 0.f;
}

__global__ __launch_bounds__(256) void k_fc_small(const float* __restrict__ inT,
                                                  const float* __restrict__ wgt,
                                                  const float* __restrict__ bias,
                                                  float* __restrict__ out,
                                                  int IN, int mode) {
  __shared__ float part[4][64];
  int o = blockIdx.x;
  int lane = threadIdx.x & 63, w = threadIdx.x >> 6;
  float acc = 0.f;
  for (int i = w; i < IN; i += 4)
    acc = fmaf(inT[(size_t)i * 64 + lane], wgt[(size_t)o * IN + i], acc);
  part[w][lane] = acc;
  __syncthreads();
  if (threadIdx.x < 64) {
    float s = part[0][lane] + part[1][lane] + part[2][lane] + part[3][lane] + bias[o];
    if (mode == 0) {
      s = s > 0.f ? s : 0.f;
      out[(64 + o) * 64 + lane] = s;
    } else {
      out[lane * 2 + o] = s;
    }
  }
}

// ============================================================================
extern "C" void kernel_launch(void* const* d_in, const int* in_sizes, int n_in,
                              void* d_out, int out_size, void* d_ws, size_t ws_size,
                              hipStream_t stream) {
  const float* x      = (const float*)d_in[0];
  const float* qvec   = (const float*)d_in[1];
  const float* basis  = (const float*)d_in[2];
  const float* w1a    = (const float*)d_in[3];
  const float* g1a    = (const float*)d_in[5];
  const float* be1a   = (const float*)d_in[6];
  const float* w1b    = (const float*)d_in[7];
  const float* g1b    = (const float*)d_in[9];
  const float* be1b   = (const float*)d_in[10];
  const float* w2a    = (const float*)d_in[11];
  const float* g2a    = (const float*)d_in[13];
  const float* be2a   = (const float*)d_in[14];
  const float* w3a    = (const float*)d_in[15];
  const float* g3a    = (const float*)d_in[17];
  const float* be3a   = (const float*)d_in[18];
  const float* fc1w   = (const float*)d_in[19];
  const float* fc1b   = (const float*)d_in[20];
  const float* fc2w   = (const float*)d_in[21];
  const float* fc2b   = (const float*)d_in[22];
  const float* fc3w   = (const float*)d_in[23];
  const float* fc3b   = (const float*)d_in[24];
  float* out = (float*)d_out;

  char* base = (char*)d_ws;
  constexpr size_t ARENA = 62914560;
  char* arenaA = base;
  char* arenaB = base + ARENA;
  char* sm     = base + 2 * ARENA;

  float*          xd   = (float*)arenaA;
  unsigned short* A    = (unsigned short*)arenaA;  // pre1a NHWC [64][120][64][64] (raw)
  unsigned short* P1   = (unsigned short*)arenaA;  // [64][60][32][64]
  unsigned short* P2   = (unsigned short*)arenaA;  // [64][30][16][128]
  unsigned short* actT = (unsigned short*)arenaA;  // [64][30784] fp16

  float*          feat = (float*)arenaB;           // [64][120][64] fp32
  unsigned short* Bb   = (unsigned short*)arenaB;  // pre1b [64][120][64][64]
  unsigned short* C2   = (unsigned short*)arenaB;  // [64][60][32][128]
  unsigned short* D3   = (unsigned short*)arenaB;  // [64][30][16][256]

  float* in2T = (float*)sm;                    // 144,384 B
  float* in3T = (float*)(sm + 144384);         // 144,384 B
  float* z1p  = (float*)(sm + 288768);         // 128,000 B
  float* ACC  = (float*)(sm + 416768);         // 4,096 B
  float* S1A  = (float*)(sm + 420864);
  float* S1B  = (float*)(sm + 421376);
  float* S2A  = (float*)(sm + 421888);
  float* S3A  = (float*)(sm + 422912);
  unsigned short* WT1 = (unsigned short*)(sm + 424960);   // 204,800 B
  unsigned short* WT2 = (unsigned short*)(sm + 834560);   // 409,600 B
  unsigned short* WT3 = (unsigned short*)(sm + 1653760);  // 1,638,400 B

  k_qinit<<<130, 256, 0, stream>>>(qvec, actT, in2T, in3T, z1p, ACC);
  k_prepw<<<400, 256, 0, stream>>>(w1b, WT1, 64, 64);
  k_prepw<<<800, 256, 0, stream>>>(w2a, WT2, 128, 64);
  k_prepw<<<3200, 256, 0, stream>>>(w3a, WT3, 256, 128);

  k_dct<<<64 * 8, 256, 0, stream>>>(x, basis, xd);
  k_hist<<<4096, 256, 0, stream>>>(xd, feat);

  // conv1a (direct) -> A (raw pre-activations), stats over A
  k_conv1a<<<dim3(32, 64, 8), 256, 0, stream>>>(feat, w1a, A);
  k_bnstatsv<64><<<240, 256, 0, stream>>>(A, ACC, 64);
  k_bnfin<<<1, 64, 0, stream>>>(ACC, S1A, 64, 1.f / 491520.f);

  // conv1b (MFMA, PREBN applies BN1a+ReLU during staging) -> Bb
  k_convM<64, 120, 64, 4, 64, true><<<dim3(30, 64, 1), 256, 0, stream>>>(
      A, WT1, Bb, S1A, g1a, be1a);
  k_bnstatsv<64><<<240, 256, 0, stream>>>(Bb, ACC + 128, 64);
  k_bnfin<<<1, 64, 0, stream>>>(ACC + 128, S1B, 64, 1.f / 491520.f);
  k_brp<64, 120, 64><<<3840, 256, 0, stream>>>(Bb, P1, S1B, g1b, be1b);

  // conv2a -> C2, stats, pool -> P2
  k_convM<64, 60, 32, 4, 128, false><<<dim3(8, 64, 2), 256, 0, stream>>>(
      P1, WT2, C2, S1A, g1a, be1a);
  k_bnstatsv<128><<<240, 256, 0, stream>>>(C2, ACC + 256, 32);
  k_bnfin<<<1, 128, 0, stream>>>(ACC + 256, S2A, 128, 1.f / 122880.f);
  k_brp<128, 60, 32><<<1920, 256, 0, stream>>>(C2, P2, S2A, g2a, be2a);

  // conv3a (NT=2 => 1024 blocks, was 512 grid-starved) -> D3
  k_convM<128, 30, 16, 2, 256, false><<<dim3(4, 64, 4), 256, 0, stream>>>(
      P2, WT3, D3, S1A, g1a, be1a);
  k_bnstatsv<256><<<240, 256, 0, stream>>>(D3, ACC + 512, 16);
  k_bnfin<<<1, 256, 0, stream>>>(ACC + 512, S3A, 256, 1.f / 30720.f);
  k_qinit<<<130, 256, 0, stream>>>(qvec, actT, in2T, in3T, z1p, ACC);
  k_brp3t<<<120, 256, 0, stream>>>(D3, actT, S3A, g3a, be3a);

  // FC head
  k_fc1m<<<dim3(32, 8), 256, 0, stream>>>(actT, fc1w, z1p);
  k_fc1ep<<<125, 256, 0, stream>>>(z1p, fc1b, in2T);
  k_fc_small<<<500, 256, 0, stream>>>(in2T, fc2w, fc2b, in3T, 564, 0);
  k_fc_small<<<2, 256, 0, stream>>>(in3T, fc3w, fc3b, out, 564, 1);
}

// Round 6
// 931.721 us; speedup vs baseline: 1.1695x; 1.0043x over previous
//
#include <hip/hip_runtime.h>
#include <math.h>

// ============================================================================
// DoubleJpeg round 13: depth-2 A-fragment prefetch INSIDE the tap loop
// (initial 2 tap-loads issued after the staging barrier — no live range
// across staging, unlike round 9's failed hoist). With launch_bounds(256,3)
// the ~170-reg budget holds acc(64)+avn(16)+avn2(16) without spill
// (round-12 proved (256,4) was the spill trigger, not the dataflow).
// Per-tap weight-load latency now covered by ~2 taps of MFMA issue.
// ============================================================================

typedef __attribute__((ext_vector_type(8))) _Float16 f16x8;
typedef __attribute__((ext_vector_type(4))) float f32x4;

#define GAMMA_F 1.0e6f

__device__ __forceinline__ unsigned short f2h(float f) {
  _Float16 h = (_Float16)f;
  union { _Float16 h; unsigned short u; } x; x.h = h; return x.u;
}
__device__ __forceinline__ float h2f(unsigned short u) {
  union { unsigned short u; _Float16 h; } x; x.u = u; return (float)x.h;
}

// ---------------------------------------------------------------- DCT kernel
__global__ __launch_bounds__(256) void k_dct(const float* __restrict__ x,
                                             const float* __restrict__ basis,
                                             float* __restrict__ xd) {
  __shared__ float bT[4096];
  __shared__ float pix[4][64];
  int tid = threadIdx.x;
  for (int e = tid; e < 4096; e += 256)
    bT[e] = basis[(e & 63) * 64 + (e >> 6)];
  __syncthreads();
  int w = tid >> 6, lane = tid & 63;
  int b = blockIdx.x >> 3;
  int br = ((blockIdx.x & 7) << 2) + w;
  const float* xb = x + (size_t)b * 65536;
  float* xdb = xd + (size_t)b * 65536;
  for (int bc = 0; bc < 32; ++bc) {
    __syncthreads();
    pix[w][lane] = xb[(br * 8 + (lane >> 3)) * 256 + bc * 8 + (lane & 7)];
    __syncthreads();
    float acc = 0.f;
#pragma unroll
    for (int p = 0; p < 64; ++p)
      acc = fmaf(bT[p * 64 + lane], pix[w][p], acc);
    xdb[lane * 1024 + br * 32 + bc] = acc;
  }
}

// ------------------------------- counting soft histogram (no atomics) -> feat
__global__ __launch_bounds__(256) void k_hist(const float* __restrict__ xd,
                                              float* __restrict__ feat) {
  __shared__ float px[1024];
  __shared__ float part[242];
  __shared__ float tot[121];
  int tid = threadIdx.x;
  int bc = blockIdx.x;
  int b = bc >> 6, c = bc & 63;
  const float* p = xd + (size_t)bc * 1024;
  for (int e = tid; e < 1024; e += 256) px[e] = p[e];
  __syncthreads();
  if (tid < 242) {
    int j = tid >> 1;
    float bj = (float)(j - 60);
    int i0 = (tid & 1) * 512;
    float cnt = 0.f;
    for (int i = i0; i < i0 + 512; ++i) {
      float d = px[i] - bj;
      float step = d > 0.f ? 1.f : 0.f;
      cnt += step;
      if (fabsf(d) < 2e-5f)
        cnt += 1.f / (1.f + expf(-GAMMA_F * d)) - step;
    }
    part[tid] = cnt;
  }
  __syncthreads();
  if (tid < 121) tot[tid] = part[2 * tid] + part[2 * tid + 1];
  __syncthreads();
  if (tid < 120)
    feat[((size_t)b * 120 + tid) * 64 + c] = (tot[tid] - tot[tid + 1]) * (1.f / 1024.f);
}

// --------------- weight prep: fp32 -> fp16, fragment-major layout
// out: wt[((t*(OC/16)+mt)*(IC/32)+icb)*512 + l15*32 + q*8 + j]
//    = w[oc=mt*16+l15][ic=icb*32+q*8+j][t]
__global__ __launch_bounds__(256) void k_prepw(const float* __restrict__ w,
                                               unsigned short* __restrict__ wt,
                                               int OC, int IC) {
  int n = OC * IC * 25;
  int idx = blockIdx.x * 256 + threadIdx.x;
  if (idx >= n) return;
  int j = idx & 7;
  int q = (idx >> 3) & 3;
  int l15 = (idx >> 5) & 15;
  int r = idx >> 9;
  int icb = r % (IC / 32);
  int r2 = r / (IC / 32);
  int mt = r2 % (OC / 16);
  int t = r2 / (OC / 16);
  int oc = mt * 16 + l15;
  int ic = icb * 32 + q * 8 + j;
  wt[idx] = f2h(w[((size_t)oc * IC + ic) * 25 + t]);
}

// ----------------------------------------------- conv1a (CIN=1), direct fp32
__global__ __launch_bounds__(256) void k_conv1a(const float* __restrict__ in,
                                                const float* __restrict__ wgt,
                                                unsigned short* __restrict__ out) {
  __shared__ float tile[20 * 21];
  int tx = threadIdx.x & 15, ty = threadIdx.x >> 4;
  int tileX = (blockIdx.x & 3) * 16, tileY = (blockIdx.x >> 2) * 16;
  int b = blockIdx.y, ocb = blockIdx.z * 8;
  const float* inc = in + (size_t)b * 7680;
  for (int e = threadIdx.x; e < 400; e += 256) {
    int ly = e / 20, lx = e % 20;
    int gy = tileY - 2 + ly, gx = tileX - 2 + lx;
    float v = 0.f;
    if ((unsigned)gy < 120u && (unsigned)gx < 64u) v = inc[gy * 64 + gx];
    tile[ly * 21 + lx] = v;
  }
  __syncthreads();
  float tv[25];
#pragma unroll
  for (int dy = 0; dy < 5; ++dy)
#pragma unroll
    for (int dx = 0; dx < 5; ++dx)
      tv[dy * 5 + dx] = tile[(ty + dy) * 21 + tx + dx];
  float acc[8];
#pragma unroll
  for (int o = 0; o < 8; ++o) {
    const float* wo = wgt + (size_t)(ocb + o) * 25;
    float a = 0.f;
#pragma unroll
    for (int t = 0; t < 25; ++t) a = fmaf(tv[t], wo[t], a);
    acc[o] = a;
  }
  int oy = tileY + ty, ox = tileX + tx;
  if (oy < 120) {
    size_t base = (((size_t)b * 120 + oy) * 64 + ox) * 64 + ocb;
    ushort4 p0, p1;
    p0.x = f2h(acc[0]); p0.y = f2h(acc[1]); p0.z = f2h(acc[2]); p0.w = f2h(acc[3]);
    p1.x = f2h(acc[4]); p1.y = f2h(acc[5]); p1.z = f2h(acc[6]); p1.w = f2h(acc[7]);
    *(ushort4*)(out + base) = p0;
    *(ushort4*)(out + base + 4) = p1;
  }
}

// ---------------------------------------------- MFMA implicit-GEMM 5x5 conv
// NHWC fp16. Wave: 4 M-tiles (64 oc) x NT N-tiles (16 px each).
// LDS: 80B slot per pixel (slot=px*5+q4): B-reads (5px+q)%8 injective ->
// conflict-free; staging writes ~conflict-free; addresses fold to ds offset
// immediates. launch_bounds(256,3): ~170-reg budget (the (256,4) bound was
// the r2-r4 spill trigger). Depth-2 A prefetch inside the tap loop.
template <int CIN, int H, int W, int NT, int OC, bool PREBN>
__global__ __launch_bounds__(256, 3) void k_convM(const unsigned short* __restrict__ in,
                                                  const unsigned short* __restrict__ wt,
                                                  unsigned short* __restrict__ out,
                                                  const float* __restrict__ pst,
                                                  const float* __restrict__ pg,
                                                  const float* __restrict__ pbe) {
  constexpr int XC = W / 16, RPW = NT / XC, WGR = 4 * RPW;
  constexpr int LW = W + 4, LR = WGR + 4, NPX = LR * LW;
  constexpr int MTS = (CIN / 32) * 512;       // per-mt frag stride (halfwords)
  constexpr int TS = (OC / 16) * MTS;         // per-tap frag stride
  __shared__ unsigned short lds[NPX * 40];    // 80B per pixel
  int tid = threadIdx.x;
  int w = tid >> 6, lane = tid & 63, l15 = lane & 15, q = lane >> 4;
  int q4 = tid & 3;
  int y0 = blockIdx.x * WGR, b = blockIdx.y, oc0 = blockIdx.z * 64;
  int z4 = blockIdx.z * 4;
  int lofs = (l15 * 4 + q) * 8;
  f32x4 acc[4][NT];
#pragma unroll
  for (int mt = 0; mt < 4; ++mt)
#pragma unroll
    for (int nt = 0; nt < NT; ++nt) acc[mt][nt] = 0.f;

  for (int icb = 0; icb < CIN / 32; ++icb) {
    float s8[8], a8[8];
    if (PREBN) {
      int cb = icb * 32 + q4 * 8;
#pragma unroll
      for (int j = 0; j < 8; ++j) {
        float m = pst[cb + j], iv = pst[CIN + cb + j];
        s8[j] = pg[cb + j] * iv;
        a8[j] = pbe[cb + j] - m * s8[j];
      }
    }
    __syncthreads();
    for (int e = tid; e < NPX * 4; e += 256) {
      int px = e >> 2;                 // e&3 == q4 (invariant per thread)
      int lr = px / LW, c = px % LW;
      int y = y0 - 2 + lr, x = c - 2;
      f16x8 v = (f16x8)0;
      if ((unsigned)y < (unsigned)H && (unsigned)x < (unsigned)W) {
        v = *(const f16x8*)(in + (((size_t)b * H + y) * W + x) * CIN + icb * 32 + q4 * 8);
        if (PREBN) {
#pragma unroll
          for (int j = 0; j < 8; ++j) {
            float f = fmaf((float)v[j], s8[j], a8[j]);
            v[j] = (_Float16)(f > 0.f ? f : 0.f);
          }
        }
      }
      *(f16x8*)&lds[(size_t)(px * 5 + q4) * 8] = v;
    }
    __syncthreads();
    // Depth-2 A-fragment prefetch, issued AFTER the staging barrier so the
    // live range never crosses the staging loop (r9's hoist spilled).
    const unsigned short* wbase = wt + (size_t)icb * 512 + lofs;
    f16x8 avn[4], avn2[4];
#pragma unroll
    for (int mt = 0; mt < 4; ++mt) {
      avn[mt]  = *(const f16x8*)(wbase + (size_t)(z4 + mt) * MTS);
      avn2[mt] = *(const f16x8*)(wbase + (size_t)TS + (size_t)(z4 + mt) * MTS);
    }
#pragma unroll
    for (int t = 0; t < 25; ++t) {
      int dy = t / 5, dx = t % 5;
      f16x8 avc[4];
#pragma unroll
      for (int mt = 0; mt < 4; ++mt) { avc[mt] = avn[mt]; avn[mt] = avn2[mt]; }
      if (t < 23) {
#pragma unroll
        for (int mt = 0; mt < 4; ++mt)
          avn2[mt] = *(const f16x8*)(wbase + (size_t)(t + 2) * TS + (size_t)(z4 + mt) * MTS);
      }
#pragma unroll
      for (int nt = 0; nt < NT; ++nt) {
        int lr = w * RPW + nt / XC + dy;
        int c = (nt % XC) * 16 + l15 + dx;
        f16x8 bv = *(const f16x8*)&lds[(size_t)((lr * LW + c) * 5 + q) * 8];
#pragma unroll
        for (int mt = 0; mt < 4; ++mt)
          acc[mt][nt] = __builtin_amdgcn_mfma_f32_16x16x32_f16(avc[mt], bv, acc[mt][nt], 0, 0, 0);
      }
    }
  }
#pragma unroll
  for (int nt = 0; nt < NT; ++nt) {
    int y = y0 + w * RPW + nt / XC;
    if (y >= H) continue;
    int x = (nt % XC) * 16 + l15;
    size_t pbase = (((size_t)b * H + y) * W + x) * OC + oc0 + q * 4;
#pragma unroll
    for (int mt = 0; mt < 4; ++mt) {
      ushort4 pk;
      pk.x = f2h(acc[mt][nt][0]);
      pk.y = f2h(acc[mt][nt][1]);
      pk.z = f2h(acc[mt][nt][2]);
      pk.w = f2h(acc[mt][nt][3]);
      *(ushort4*)(out + pbase + mt * 16) = pk;
    }
  }
}

// ------------------- BN stats, vectorized f16x8 (fully coalesced 1KB/wave)
template <int C>
__global__ __launch_bounds__(256) void k_bnstatsv(const unsigned short* __restrict__ x,
                                                  float* __restrict__ acc,
                                                  int nIter) {
  constexpr int CV = C / 8, KPB = 256 / CV;
  __shared__ float r1[256][8], r2[256][8];
  int tid = threadIdx.x;
  int cv = tid % CV, kq = tid / CV;
  size_t row0 = (size_t)blockIdx.x * (KPB * nIter) + kq;
  const unsigned short* p = x + row0 * C + cv * 8;
  float s1[8], s2[8];
#pragma unroll
  for (int j = 0; j < 8; ++j) { s1[j] = 0.f; s2[j] = 0.f; }
  for (int it = 0; it < nIter; ++it) {
    f16x8 v = *(const f16x8*)(p + (size_t)it * KPB * C);
#pragma unroll
    for (int j = 0; j < 8; ++j) {
      float f = (float)v[j];
      s1[j] += f;
      s2[j] += f * f;
    }
  }
#pragma unroll
  for (int j = 0; j < 8; ++j) { r1[tid][j] = s1[j]; r2[tid][j] = s2[j]; }
  __syncthreads();
  if (tid < C) {
    int cv0 = tid >> 3, e = tid & 7;
    float t1 = 0.f, t2 = 0.f;
    for (int k = 0; k < KPB; ++k) {
      t1 += r1[k * CV + cv0][e];
      t2 += r2[k * CV + cv0][e];
    }
    atomicAdd(&acc[tid], t1);
    atomicAdd(&acc[C + tid], t2);
  }
}

__global__ __launch_bounds__(256) void k_bnfin(const float* __restrict__ acc,
                                               float* __restrict__ stats,
                                               int C, float invN) {
  int c = threadIdx.x + blockIdx.x * 256;
  if (c >= C) return;
  float m = acc[c] * invN;
  float v = acc[C + c] * invN - m * m;
  stats[c] = m;
  stats[C + c] = rsqrtf(v + 1e-5f);
}

// --------------------------------------- BN+ReLU+maxpool2 NHWC (x8 vec)
template <int C, int H, int W>
__global__ __launch_bounds__(256) void k_brp(const unsigned short* __restrict__ x,
                                             unsigned short* __restrict__ y,
                                             const float* __restrict__ stats,
                                             const float* __restrict__ g,
                                             const float* __restrict__ be) {
  constexpr int OH = H / 2, OW = W / 2, CV = C / 8;
  int idx = blockIdx.x * 256 + threadIdx.x;   // [b][oy][ox][cv]
  int cv = idx % CV;
  int t = idx / CV;
  int ox = t % OW; t /= OW;
  int oy = t % OH;
  int b = t / OH;
  int c0 = cv * 8;
  const unsigned short* p = x + ((size_t)(b * H + oy * 2) * W + ox * 2) * C + c0;
  f16x8 v00 = *(const f16x8*)p;
  f16x8 v01 = *(const f16x8*)(p + C);
  f16x8 v10 = *(const f16x8*)(p + (size_t)W * C);
  f16x8 v11 = *(const f16x8*)(p + (size_t)W * C + C);
  f16x8 r;
#pragma unroll
  for (int j = 0; j < 8; ++j) {
    int c = c0 + j;
    float m = stats[c], iv = stats[C + c], gg = g[c], bb = be[c];
    float f0 = gg * (((float)v00[j] - m) * iv) + bb;
    float f1 = gg * (((float)v01[j] - m) * iv) + bb;
    float f2 = gg * (((float)v10[j] - m) * iv) + bb;
    float f3 = gg * (((float)v11[j] - m) * iv) + bb;
    f0 = f0 > 0.f ? f0 : 0.f;
    f1 = f1 > 0.f ? f1 : 0.f;
    f2 = f2 > 0.f ? f2 : 0.f;
    f3 = f3 > 0.f ? f3 : 0.f;
    float r01 = f0 > f1 ? f0 : f1;
    float r23 = f2 > f3 ? f2 : f3;
    r[j] = (_Float16)(r01 > r23 ? r01 : r23);
  }
  *(f16x8*)(y + (size_t)idx * 8) = r;
}

// ---- stage-3 BN+ReLU+pool + write into batch-major fc1 activations (fp16)
__global__ __launch_bounds__(256) void k_brp3t(const unsigned short* __restrict__ x,
                                               unsigned short* __restrict__ actT,
                                               const float* __restrict__ stats,
                                               const float* __restrict__ g,
                                               const float* __restrict__ be) {
  __shared__ float tile[64 * 65];
  int s = blockIdx.x;
  int oy = s >> 3, ox = s & 7;
  int ci = threadIdx.x & 63, bq = threadIdx.x >> 6;
  for (int cs = 0; cs < 4; ++cs) {
    int c = cs * 64 + ci;
    float m = stats[c], iv = stats[256 + c], gg = g[c], bb = be[c];
    __syncthreads();
    for (int b = bq; b < 64; b += 4) {
      float mx = 0.f;
#pragma unroll
      for (int qq = 0; qq < 4; ++qq) {
        int yy = oy * 2 + (qq >> 1), xx = ox * 2 + (qq & 1);
        float v = h2f(x[((size_t)(b * 30 + yy) * 16 + xx) * 256 + c]);
        v = gg * ((v - m) * iv) + bb;
        v = v > 0.f ? v : 0.f;
        mx = v > mx ? v : mx;
      }
      tile[ci * 65 + b] = mx;
    }
    __syncthreads();
    for (int e = threadIdx.x; e < 4096; e += 256) {
      int cc = e >> 6, bb2 = e & 63;
      actT[(size_t)bb2 * 30784 + 64 + (cs * 64 + cc) * 120 + s] = f2h(tile[cc * 65 + bb2]);
    }
  }
}

// -------------------- q rows of fc inputs + zero fc1 accumulator + BN accums
__global__ __launch_bounds__(256) void k_qinit(const float* __restrict__ q,
                                               unsigned short* __restrict__ actT,
                                               float* __restrict__ in2T,
                                               float* __restrict__ in3T,
                                               float* __restrict__ z1pre,
                                               float* __restrict__ bnacc) {
  int idx = blockIdx.x * 256 + threadIdx.x;
  if (idx < 32000) z1pre[idx] = 0.f;
  else if (idx < 33024) bnacc[idx - 32000] = 0.f;
  if (idx >= 4096) return;
  int b = idx >> 6, i = idx & 63;
  float v = q[idx];
  actT[(size_t)b * 30784 + i] = f2h(v);
  in2T[i * 64 + b] = v;
  in3T[i * 64 + b] = v;
}

// --------------------------------------------------------- fc1 (MFMA GEMM)
__global__ __launch_bounds__(256) void k_fc1m(const unsigned short* __restrict__ actT,
                                              const float* __restrict__ wgt,
                                              float* __restrict__ z1pre) {
  constexpr int IN = 30784;
  constexpr int KSTEPS = IN / 32;   // 962
  __shared__ float part[4][16][64];
  int tid = threadIdx.x;
  int w = tid >> 6, lane = tid & 63, l15 = lane & 15, q = lane >> 4;
  int ob = blockIdx.x * 16;
  int row = ob + l15; if (row > 499) row = 499;
  int kw = blockIdx.y * 4 + w;      // 0..31
  f32x4 acc[4];
#pragma unroll
  for (int nt = 0; nt < 4; ++nt) acc[nt] = 0.f;
  for (int s = kw; s < KSTEPS; s += 32) {
    int k0 = s * 32;
    const float4* wp = (const float4*)(wgt + (size_t)row * IN + k0 + q * 8);
    float4 wa = wp[0], wb = wp[1];
    f16x8 a;
    a[0] = (_Float16)wa.x; a[1] = (_Float16)wa.y;
    a[2] = (_Float16)wa.z; a[3] = (_Float16)wa.w;
    a[4] = (_Float16)wb.x; a[5] = (_Float16)wb.y;
    a[6] = (_Float16)wb.z; a[7] = (_Float16)wb.w;
#pragma unroll
    for (int nt = 0; nt < 4; ++nt) {
      f16x8 bv = *(const f16x8*)(actT + (size_t)(nt * 16 + l15) * IN + k0 + q * 8);
      acc[nt] = __builtin_amdgcn_mfma_f32_16x16x32_f16(a, bv, acc[nt], 0, 0, 0);
    }
  }
#pragma unroll
  for (int nt = 0; nt < 4; ++nt)
#pragma unroll
    for (int reg = 0; reg < 4; ++reg)
      part[w][q * 4 + reg][nt * 16 + l15] = acc[nt][reg];
  __syncthreads();
  for (int e = tid; e < 1024; e += 256) {
    int m = e >> 6, n = e & 63;
    float sum = part[0][m][n] + part[1][m][n] + part[2][m][n] + part[3][m][n];
    int o = ob + m;
    if (o < 500) atomicAdd(&z1pre[o * 64 + n], sum);
  }
}

__global__ __launch_bounds__(256) void k_fc1ep(const float* __restrict__ z1pre,
                                               const float* __restrict__ bias,
                                               float* __restrict__ in2T) {
  int idx = blockIdx.x * 256 + threadIdx.x;
  if (idx >= 500 * 64) return;
  int o = idx >> 6;
  float v = z1pre[idx] + bias[o];
  in2T[idx + 64 * 64] = v > 0.f ? v : 0.f;
}

__global__ __launch_bounds__(256) void k_fc_small(const float* __restrict__ inT,
                                                  const float* __restrict__ wgt,
                                                  const float* __restrict__ bias,
                                                  float* __restrict__ out,
                                                  int IN, int mode) {
  __shared__ float part[4][64];
  int o = blockIdx.x;
  int lane = threadIdx.x & 63, w = threadIdx.x >> 6;
  float acc = 0.f;
  for (int i = w; i < IN; i += 4)
    acc = fmaf(inT[(size_t)i * 64 + lane], wgt[(size_t)o * IN + i], acc);
  part[w][lane] = acc;
  __syncthreads();
  if (threadIdx.x < 64) {
    float s = part[0][lane] + part[1][lane] + part[2][lane] + part[3][lane] + bias[o];
    if (mode == 0) {
      s = s > 0.f ? s : 0.f;
      out[(64 + o) * 64 + lane] = s;
    } else {
      out[lane * 2 + o] = s;
    }
  }
}

// ============================================================================
extern "C" void kernel_launch(void* const* d_in, const int* in_sizes, int n_in,
                              void* d_out, int out_size, void* d_ws, size_t ws_size,
                              hipStream_t stream) {
  const float* x      = (const float*)d_in[0];
  const float* qvec   = (const float*)d_in[1];
  const float* basis  = (const float*)d_in[2];
  const float* w1a    = (const float*)d_in[3];
  const float* g1a    = (const float*)d_in[5];
  const float* be1a   = (const float*)d_in[6];
  const float* w1b    = (const float*)d_in[7];
  const float* g1b    = (const float*)d_in[9];
  const float* be1b   = (const float*)d_in[10];
  const float* w2a    = (const float*)d_in[11];
  const float* g2a    = (const float*)d_in[13];
  const float* be2a   = (const float*)d_in[14];
  const float* w3a    = (const float*)d_in[15];
  const float* g3a    = (const float*)d_in[17];
  const float* be3a   = (const float*)d_in[18];
  const float* fc1w   = (const float*)d_in[19];
  const float* fc1b   = (const float*)d_in[20];
  const float* fc2w   = (const float*)d_in[21];
  const float* fc2b   = (const float*)d_in[22];
  const float* fc3w   = (const float*)d_in[23];
  const float* fc3b   = (const float*)d_in[24];
  float* out = (float*)d_out;

  char* base = (char*)d_ws;
  constexpr size_t ARENA = 62914560;
  char* arenaA = base;
  char* arenaB = base + ARENA;
  char* sm     = base + 2 * ARENA;

  float*          xd   = (float*)arenaA;
  unsigned short* A    = (unsigned short*)arenaA;  // pre1a NHWC [64][120][64][64] (raw)
  unsigned short* P1   = (unsigned short*)arenaA;  // [64][60][32][64]
  unsigned short* P2   = (unsigned short*)arenaA;  // [64][30][16][128]
  unsigned short* actT = (unsigned short*)arenaA;  // [64][30784] fp16

  float*          feat = (float*)arenaB;           // [64][120][64] fp32
  unsigned short* Bb   = (unsigned short*)arenaB;  // pre1b [64][120][64][64]
  unsigned short* C2   = (unsigned short*)arenaB;  // [64][60][32][128]
  unsigned short* D3   = (unsigned short*)arenaB;  // [64][30][16][256]

  float* in2T = (float*)sm;                    // 144,384 B
  float* in3T = (float*)(sm + 144384);         // 144,384 B
  float* z1p  = (float*)(sm + 288768);         // 128,000 B
  float* ACC  = (float*)(sm + 416768);         // 4,096 B
  float* S1A  = (float*)(sm + 420864);
  float* S1B  = (float*)(sm + 421376);
  float* S2A  = (float*)(sm + 421888);
  float* S3A  = (float*)(sm + 422912);
  unsigned short* WT1 = (unsigned short*)(sm + 424960);   // 204,800 B
  unsigned short* WT2 = (unsigned short*)(sm + 834560);   // 409,600 B
  unsigned short* WT3 = (unsigned short*)(sm + 1653760);  // 1,638,400 B

  k_qinit<<<130, 256, 0, stream>>>(qvec, actT, in2T, in3T, z1p, ACC);
  k_prepw<<<400, 256, 0, stream>>>(w1b, WT1, 64, 64);
  k_prepw<<<800, 256, 0, stream>>>(w2a, WT2, 128, 64);
  k_prepw<<<3200, 256, 0, stream>>>(w3a, WT3, 256, 128);

  k_dct<<<64 * 8, 256, 0, stream>>>(x, basis, xd);
  k_hist<<<4096, 256, 0, stream>>>(xd, feat);

  // conv1a (direct) -> A (raw pre-activations), stats over A
  k_conv1a<<<dim3(32, 64, 8), 256, 0, stream>>>(feat, w1a, A);
  k_bnstatsv<64><<<240, 256, 0, stream>>>(A, ACC, 64);
  k_bnfin<<<1, 64, 0, stream>>>(ACC, S1A, 64, 1.f / 491520.f);

  // conv1b (MFMA, PREBN applies BN1a+ReLU during staging) -> Bb
  k_convM<64, 120, 64, 4, 64, true><<<dim3(30, 64, 1), 256, 0, stream>>>(
      A, WT1, Bb, S1A, g1a, be1a);
  k_bnstatsv<64><<<240, 256, 0, stream>>>(Bb, ACC + 128, 64);
  k_bnfin<<<1, 64, 0, stream>>>(ACC + 128, S1B, 64, 1.f / 491520.f);
  k_brp<64, 120, 64><<<3840, 256, 0, stream>>>(Bb, P1, S1B, g1b, be1b);

  // conv2a -> C2, stats, pool -> P2
  k_convM<64, 60, 32, 4, 128, false><<<dim3(8, 64, 2), 256, 0, stream>>>(
      P1, WT2, C2, S1A, g1a, be1a);
  k_bnstatsv<128><<<240, 256, 0, stream>>>(C2, ACC + 256, 32);
  k_bnfin<<<1, 128, 0, stream>>>(ACC + 256, S2A, 128, 1.f / 122880.f);
  k_brp<128, 60, 32><<<1920, 256, 0, stream>>>(C2, P2, S2A, g2a, be2a);

  // conv3a (NT=2 => 1024 blocks) -> D3
  k_convM<128, 30, 16, 2, 256, false><<<dim3(4, 64, 4), 256, 0, stream>>>(
      P2, WT3, D3, S1A, g1a, be1a);
  k_bnstatsv<256><<<240, 256, 0, stream>>>(D3, ACC + 512, 16);
  k_bnfin<<<1, 256, 0, stream>>>(ACC + 512, S3A, 256, 1.f / 30720.f);
  k_qinit<<<130, 256, 0, stream>>>(qvec, actT, in2T, in3T, z1p, ACC);
  k_brp3t<<<120, 256, 0, stream>>>(D3, actT, S3A, g3a, be3a);

  // FC head
  k_fc1m<<<dim3(32, 8), 256, 0, stream>>>(actT, fc1w, z1p);
  k_fc1ep<<<125, 256, 0, stream>>>(z1p, fc1b, in2T);
  k_fc_small<<<500, 256, 0, stream>>>(in2T, fc2w, fc2b, in3T, 564, 0);
  k_fc_small<<<2, 256, 0, stream>>>(in3T, fc3w, fc3b, out, 564, 1);
}

// Round 7
// 922.827 us; speedup vs baseline: 1.1807x; 1.0096x over previous
//
#include <hip/hip_runtime.h>
#include <math.h>

// ============================================================================
// DoubleJpeg round 14 (base = round-12, 935us):
//  (1) conv1b TC=32 col-tiling (r4 template, verified): LDS 43520->34560
//      => 4 blocks/CU under launch_bounds(256,3) (r5 proved (256,3) stops
//      the 64-reg allocator squeeze that sank r2-r4). Depth-1 prefetch
//      (depth-2 was neutral, r6).
//  (2) k_hist rewrite: soft 121-threshold histogram == bucket count
//      (sigmoid(1e6 d) is exactly 0/1 in fp32 for |d|>2e-5). 1 atomicAdd/px
//      instead of 121 compares/px; exact sigmoid split for |px-v|<2e-5
//      (same threshold as the previously-passing kernel).
// ============================================================================

typedef __attribute__((ext_vector_type(8))) _Float16 f16x8;
typedef __attribute__((ext_vector_type(4))) float f32x4;

#define GAMMA_F 1.0e6f

__device__ __forceinline__ unsigned short f2h(float f) {
  _Float16 h = (_Float16)f;
  union { _Float16 h; unsigned short u; } x; x.h = h; return x.u;
}
__device__ __forceinline__ float h2f(unsigned short u) {
  union { unsigned short u; _Float16 h; } x; x.u = u; return (float)x.h;
}

// ---------------------------------------------------------------- DCT kernel
__global__ __launch_bounds__(256) void k_dct(const float* __restrict__ x,
                                             const float* __restrict__ basis,
                                             float* __restrict__ xd) {
  __shared__ float bT[4096];
  __shared__ float pix[4][64];
  int tid = threadIdx.x;
  for (int e = tid; e < 4096; e += 256)
    bT[e] = basis[(e & 63) * 64 + (e >> 6)];
  __syncthreads();
  int w = tid >> 6, lane = tid & 63;
  int b = blockIdx.x >> 3;
  int br = ((blockIdx.x & 7) << 2) + w;
  const float* xb = x + (size_t)b * 65536;
  float* xdb = xd + (size_t)b * 65536;
  for (int bc = 0; bc < 32; ++bc) {
    __syncthreads();
    pix[w][lane] = xb[(br * 8 + (lane >> 3)) * 256 + bc * 8 + (lane & 7)];
    __syncthreads();
    float acc = 0.f;
#pragma unroll
    for (int p = 0; p < 64; ++p)
      acc = fmaf(bT[p * 64 + lane], pix[w][p], acc);
    xdb[lane * 1024 + br * 32 + bc] = acc;
  }
}

// ---------------- soft histogram via bucket count + boundary sigmoid -> feat
// feat[b][j][c] = tot[j]-tot[j+1] = soft-count of px in (j-60, j-59].
// Hard bucket j = ceil(px+60)-1 for px not within 2e-5 of an integer
// (sigmoid(1e6*d) is exactly 0/1 in fp32 there); near-integer px splits
// (1-s)/s across the two adjacent buckets with s = sigmoid(1e6*(px-v)).
__global__ __launch_bounds__(256) void k_hist(const float* __restrict__ xd,
                                              float* __restrict__ feat) {
  __shared__ float h[120];
  int tid = threadIdx.x;
  int bc = blockIdx.x;
  int b = bc >> 6, c = bc & 63;
  if (tid < 120) h[tid] = 0.f;
  __syncthreads();
  const float4* p4 = (const float4*)(xd + (size_t)bc * 1024);
  float4 v4 = p4[tid];
#pragma unroll
  for (int k = 0; k < 4; ++k) {
    float pv = k == 0 ? v4.x : (k == 1 ? v4.y : (k == 2 ? v4.z : v4.w));
    float v = rintf(pv);
    float d = pv - v;
    if (fabsf(d) < 2e-5f && v >= -60.f && v <= 60.f) {
      float s = 1.f / (1.f + expf(-GAMMA_F * d));
      int vi = (int)v;
      if (vi >= -59) atomicAdd(&h[vi + 59], 1.f - s);
      if (vi <= 59)  atomicAdd(&h[vi + 60], s);
    } else {
      int j = (int)ceilf(pv + 60.f) - 1;
      if (j >= 0 && j <= 119) atomicAdd(&h[j], 1.f);
    }
  }
  __syncthreads();
  if (tid < 120)
    feat[((size_t)b * 120 + tid) * 64 + c] = h[tid] * (1.f / 1024.f);
}

// --------------- weight prep: fp32 -> fp16, fragment-major layout
// out: wt[((t*(OC/16)+mt)*(IC/32)+icb)*512 + l15*32 + q*8 + j]
//    = w[oc=mt*16+l15][ic=icb*32+q*8+j][t]
__global__ __launch_bounds__(256) void k_prepw(const float* __restrict__ w,
                                               unsigned short* __restrict__ wt,
                                               int OC, int IC) {
  int n = OC * IC * 25;
  int idx = blockIdx.x * 256 + threadIdx.x;
  if (idx >= n) return;
  int j = idx & 7;
  int q = (idx >> 3) & 3;
  int l15 = (idx >> 5) & 15;
  int r = idx >> 9;
  int icb = r % (IC / 32);
  int r2 = r / (IC / 32);
  int mt = r2 % (OC / 16);
  int t = r2 / (OC / 16);
  int oc = mt * 16 + l15;
  int ic = icb * 32 + q * 8 + j;
  wt[idx] = f2h(w[((size_t)oc * IC + ic) * 25 + t]);
}

// ----------------------------------------------- conv1a (CIN=1), direct fp32
__global__ __launch_bounds__(256) void k_conv1a(const float* __restrict__ in,
                                                const float* __restrict__ wgt,
                                                unsigned short* __restrict__ out) {
  __shared__ float tile[20 * 21];
  int tx = threadIdx.x & 15, ty = threadIdx.x >> 4;
  int tileX = (blockIdx.x & 3) * 16, tileY = (blockIdx.x >> 2) * 16;
  int b = blockIdx.y, ocb = blockIdx.z * 8;
  const float* inc = in + (size_t)b * 7680;
  for (int e = threadIdx.x; e < 400; e += 256) {
    int ly = e / 20, lx = e % 20;
    int gy = tileY - 2 + ly, gx = tileX - 2 + lx;
    float v = 0.f;
    if ((unsigned)gy < 120u && (unsigned)gx < 64u) v = inc[gy * 64 + gx];
    tile[ly * 21 + lx] = v;
  }
  __syncthreads();
  float tv[25];
#pragma unroll
  for (int dy = 0; dy < 5; ++dy)
#pragma unroll
    for (int dx = 0; dx < 5; ++dx)
      tv[dy * 5 + dx] = tile[(ty + dy) * 21 + tx + dx];
  float acc[8];
#pragma unroll
  for (int o = 0; o < 8; ++o) {
    const float* wo = wgt + (size_t)(ocb + o) * 25;
    float a = 0.f;
#pragma unroll
    for (int t = 0; t < 25; ++t) a = fmaf(tv[t], wo[t], a);
    acc[o] = a;
  }
  int oy = tileY + ty, ox = tileX + tx;
  if (oy < 120) {
    size_t base = (((size_t)b * 120 + oy) * 64 + ox) * 64 + ocb;
    ushort4 p0, p1;
    p0.x = f2h(acc[0]); p0.y = f2h(acc[1]); p0.z = f2h(acc[2]); p0.w = f2h(acc[3]);
    p1.x = f2h(acc[4]); p1.y = f2h(acc[5]); p1.z = f2h(acc[6]); p1.w = f2h(acc[7]);
    *(ushort4*)(out + base) = p0;
    *(ushort4*)(out + base + 4) = p1;
  }
}

// ---------------------------------------------- MFMA implicit-GEMM 5x5 conv
// NHWC fp16. Wave: 4 M-tiles (64 oc) x NT N-tiles (16 px each).
// Block covers WGR rows x TC cols (grid.x = ceil(H/WGR)*(W/TC)).
// LDS: 80B slot per pixel (slot=px*5+q4): B-reads (5px+q)%8 injective ->
// conflict-free; addresses fold to ds offset immediates.
// launch_bounds(256,3): ~170-reg budget — (256,4) was the r2-r4 spill trigger.
template <int CIN, int H, int W, int TC, int NT, int OC, bool PREBN>
__global__ __launch_bounds__(256, 3) void k_convM(const unsigned short* __restrict__ in,
                                                  const unsigned short* __restrict__ wt,
                                                  unsigned short* __restrict__ out,
                                                  const float* __restrict__ pst,
                                                  const float* __restrict__ pg,
                                                  const float* __restrict__ pbe) {
  constexpr int XC = TC / 16, RPW = NT / XC, WGR = 4 * RPW;
  constexpr int LW = TC + 4, LR = WGR + 4, NPX = LR * LW;
  constexpr int NXC = W / TC;
  constexpr int MTS = (CIN / 32) * 512;       // per-mt frag stride (halfwords)
  constexpr int TS = (OC / 16) * MTS;         // per-tap frag stride
  __shared__ unsigned short lds[NPX * 40];    // 80B per pixel
  int tid = threadIdx.x;
  int w = tid >> 6, lane = tid & 63, l15 = lane & 15, q = lane >> 4;
  int q4 = tid & 3;
  int ry = blockIdx.x / NXC, cx = blockIdx.x % NXC;
  int y0 = ry * WGR, x0 = cx * TC;
  int b = blockIdx.y, oc0 = blockIdx.z * 64;
  int z4 = blockIdx.z * 4;
  int lofs = (l15 * 4 + q) * 8;
  f32x4 acc[4][NT];
#pragma unroll
  for (int mt = 0; mt < 4; ++mt)
#pragma unroll
    for (int nt = 0; nt < NT; ++nt) acc[mt][nt] = 0.f;

  for (int icb = 0; icb < CIN / 32; ++icb) {
    float s8[8], a8[8];
    if (PREBN) {
      int cb = icb * 32 + q4 * 8;
#pragma unroll
      for (int j = 0; j < 8; ++j) {
        float m = pst[cb + j], iv = pst[CIN + cb + j];
        s8[j] = pg[cb + j] * iv;
        a8[j] = pbe[cb + j] - m * s8[j];
      }
    }
    __syncthreads();
    for (int e = tid; e < NPX * 4; e += 256) {
      int px = e >> 2;                 // e&3 == q4 (invariant per thread)
      int lr = px / LW, c = px % LW;
      int y = y0 - 2 + lr, x = x0 - 2 + c;
      f16x8 v = (f16x8)0;
      if ((unsigned)y < (unsigned)H && (unsigned)x < (unsigned)W) {
        v = *(const f16x8*)(in + (((size_t)b * H + y) * W + x) * CIN + icb * 32 + q4 * 8);
        if (PREBN) {
#pragma unroll
          for (int j = 0; j < 8; ++j) {
            float f = fmaf((float)v[j], s8[j], a8[j]);
            v[j] = (_Float16)(f > 0.f ? f : 0.f);
          }
        }
      }
      *(f16x8*)&lds[(size_t)(px * 5 + q4) * 8] = v;
    }
    __syncthreads();
    const unsigned short* wbase = wt + (size_t)icb * 512 + lofs;
    f16x8 avn[4];
#pragma unroll
    for (int mt = 0; mt < 4; ++mt)
      avn[mt] = *(const f16x8*)(wbase + (size_t)(z4 + mt) * MTS);
#pragma unroll
    for (int t = 0; t < 25; ++t) {
      int dy = t / 5, dx = t % 5;
      f16x8 avc[4];
#pragma unroll
      for (int mt = 0; mt < 4; ++mt) avc[mt] = avn[mt];
      if (t < 24) {
#pragma unroll
        for (int mt = 0; mt < 4; ++mt)
          avn[mt] = *(const f16x8*)(wbase + (size_t)(t + 1) * TS + (size_t)(z4 + mt) * MTS);
      }
#pragma unroll
      for (int nt = 0; nt < NT; ++nt) {
        int lr = w * RPW + nt / XC + dy;
        int c = (nt % XC) * 16 + l15 + dx;
        f16x8 bv = *(const f16x8*)&lds[(size_t)((lr * LW + c) * 5 + q) * 8];
#pragma unroll
        for (int mt = 0; mt < 4; ++mt)
          acc[mt][nt] = __builtin_amdgcn_mfma_f32_16x16x32_f16(avc[mt], bv, acc[mt][nt], 0, 0, 0);
      }
    }
  }
#pragma unroll
  for (int nt = 0; nt < NT; ++nt) {
    int y = y0 + w * RPW + nt / XC;
    if (y >= H) continue;
    int x = x0 + (nt % XC) * 16 + l15;
    size_t pbase = (((size_t)b * H + y) * W + x) * OC + oc0 + q * 4;
#pragma unroll
    for (int mt = 0; mt < 4; ++mt) {
      ushort4 pk;
      pk.x = f2h(acc[mt][nt][0]);
      pk.y = f2h(acc[mt][nt][1]);
      pk.z = f2h(acc[mt][nt][2]);
      pk.w = f2h(acc[mt][nt][3]);
      *(ushort4*)(out + pbase + mt * 16) = pk;
    }
  }
}

// ------------------- BN stats, vectorized f16x8 (fully coalesced 1KB/wave)
template <int C>
__global__ __launch_bounds__(256) void k_bnstatsv(const unsigned short* __restrict__ x,
                                                  float* __restrict__ acc,
                                                  int nIter) {
  constexpr int CV = C / 8, KPB = 256 / CV;
  __shared__ float r1[256][8], r2[256][8];
  int tid = threadIdx.x;
  int cv = tid % CV, kq = tid / CV;
  size_t row0 = (size_t)blockIdx.x * (KPB * nIter) + kq;
  const unsigned short* p = x + row0 * C + cv * 8;
  float s1[8], s2[8];
#pragma unroll
  for (int j = 0; j < 8; ++j) { s1[j] = 0.f; s2[j] = 0.f; }
  for (int it = 0; it < nIter; ++it) {
    f16x8 v = *(const f16x8*)(p + (size_t)it * KPB * C);
#pragma unroll
    for (int j = 0; j < 8; ++j) {
      float f = (float)v[j];
      s1[j] += f;
      s2[j] += f * f;
    }
  }
#pragma unroll
  for (int j = 0; j < 8; ++j) { r1[tid][j] = s1[j]; r2[tid][j] = s2[j]; }
  __syncthreads();
  if (tid < C) {
    int cv0 = tid >> 3, e = tid & 7;
    float t1 = 0.f, t2 = 0.f;
    for (int k = 0; k < KPB; ++k) {
      t1 += r1[k * CV + cv0][e];
      t2 += r2[k * CV + cv0][e];
    }
    atomicAdd(&acc[tid], t1);
    atomicAdd(&acc[C + tid], t2);
  }
}

__global__ __launch_bounds__(256) void k_bnfin(const float* __restrict__ acc,
                                               float* __restrict__ stats,
                                               int C, float invN) {
  int c = threadIdx.x + blockIdx.x * 256;
  if (c >= C) return;
  float m = acc[c] * invN;
  float v = acc[C + c] * invN - m * m;
  stats[c] = m;
  stats[C + c] = rsqrtf(v + 1e-5f);
}

// --------------------------------------- BN+ReLU+maxpool2 NHWC (x8 vec)
template <int C, int H, int W>
__global__ __launch_bounds__(256) void k_brp(const unsigned short* __restrict__ x,
                                             unsigned short* __restrict__ y,
                                             const float* __restrict__ stats,
                                             const float* __restrict__ g,
                                             const float* __restrict__ be) {
  constexpr int OH = H / 2, OW = W / 2, CV = C / 8;
  int idx = blockIdx.x * 256 + threadIdx.x;   // [b][oy][ox][cv]
  int cv = idx % CV;
  int t = idx / CV;
  int ox = t % OW; t /= OW;
  int oy = t % OH;
  int b = t / OH;
  int c0 = cv * 8;
  const unsigned short* p = x + ((size_t)(b * H + oy * 2) * W + ox * 2) * C + c0;
  f16x8 v00 = *(const f16x8*)p;
  f16x8 v01 = *(const f16x8*)(p + C);
  f16x8 v10 = *(const f16x8*)(p + (size_t)W * C);
  f16x8 v11 = *(const f16x8*)(p + (size_t)W * C + C);
  f16x8 r;
#pragma unroll
  for (int j = 0; j < 8; ++j) {
    int c = c0 + j;
    float m = stats[c], iv = stats[C + c], gg = g[c], bb = be[c];
    float f0 = gg * (((float)v00[j] - m) * iv) + bb;
    float f1 = gg * (((float)v01[j] - m) * iv) + bb;
    float f2 = gg * (((float)v10[j] - m) * iv) + bb;
    float f3 = gg * (((float)v11[j] - m) * iv) + bb;
    f0 = f0 > 0.f ? f0 : 0.f;
    f1 = f1 > 0.f ? f1 : 0.f;
    f2 = f2 > 0.f ? f2 : 0.f;
    f3 = f3 > 0.f ? f3 : 0.f;
    float r01 = f0 > f1 ? f0 : f1;
    float r23 = f2 > f3 ? f2 : f3;
    r[j] = (_Float16)(r01 > r23 ? r01 : r23);
  }
  *(f16x8*)(y + (size_t)idx * 8) = r;
}

// ---- stage-3 BN+ReLU+pool + write into batch-major fc1 activations (fp16)
__global__ __launch_bounds__(256) void k_brp3t(const unsigned short* __restrict__ x,
                                               unsigned short* __restrict__ actT,
                                               const float* __restrict__ stats,
                                               const float* __restrict__ g,
                                               const float* __restrict__ be) {
  __shared__ float tile[64 * 65];
  int s = blockIdx.x;
  int oy = s >> 3, ox = s & 7;
  int ci = threadIdx.x & 63, bq = threadIdx.x >> 6;
  for (int cs = 0; cs < 4; ++cs) {
    int c = cs * 64 + ci;
    float m = stats[c], iv = stats[256 + c], gg = g[c], bb = be[c];
    __syncthreads();
    for (int b = bq; b < 64; b += 4) {
      float mx = 0.f;
#pragma unroll
      for (int qq = 0; qq < 4; ++qq) {
        int yy = oy * 2 + (qq >> 1), xx = ox * 2 + (qq & 1);
        float v = h2f(x[((size_t)(b * 30 + yy) * 16 + xx) * 256 + c]);
        v = gg * ((v - m) * iv) + bb;
        v = v > 0.f ? v : 0.f;
        mx = v > mx ? v : mx;
      }
      tile[ci * 65 + b] = mx;
    }
    __syncthreads();
    for (int e = threadIdx.x; e < 4096; e += 256) {
      int cc = e >> 6, bb2 = e & 63;
      actT[(size_t)bb2 * 30784 + 64 + (cs * 64 + cc) * 120 + s] = f2h(tile[cc * 65 + bb2]);
    }
  }
}

// -------------------- q rows of fc inputs + zero fc1 accumulator + BN accums
__global__ __launch_bounds__(256) void k_qinit(const float* __restrict__ q,
                                               unsigned short* __restrict__ actT,
                                               float* __restrict__ in2T,
                                               float* __restrict__ in3T,
                                               float* __restrict__ z1pre,
                                               float* __restrict__ bnacc) {
  int idx = blockIdx.x * 256 + threadIdx.x;
  if (idx < 32000) z1pre[idx] = 0.f;
  else if (idx < 33024) bnacc[idx - 32000] = 0.f;
  if (idx >= 4096) return;
  int b = idx >> 6, i = idx & 63;
  float v = q[idx];
  actT[(size_t)b * 30784 + i] = f2h(v);
  in2T[i * 64 + b] = v;
  in3T[i * 64 + b] = v;
}

// --------------------------------------------------------- fc1 (MFMA GEMM)
__global__ __launch_bounds__(256) void k_fc1m(const unsigned short* __restrict__ actT,
                                              const float* __restrict__ wgt,
                                              float* __restrict__ z1pre) {
  constexpr int IN = 30784;
  constexpr int KSTEPS = IN / 32;   // 962
  __shared__ float part[4][16][64];
  int tid = threadIdx.x;
  int w = tid >> 6, lane = tid & 63, l15 = lane & 15, q = lane >> 4;
  int ob = blockIdx.x * 16;
  int row = ob + l15; if (row > 499) row = 499;
  int kw = blockIdx.y * 4 + w;      // 0..31
  f32x4 acc[4];
#pragma unroll
  for (int nt = 0; nt < 4; ++nt) acc[nt] = 0.f;
  for (int s = kw; s < KSTEPS; s += 32) {
    int k0 = s * 32;
    const float4* wp = (const float4*)(wgt + (size_t)row * IN + k0 + q * 8);
    float4 wa = wp[0], wb = wp[1];
    f16x8 a;
    a[0] = (_Float16)wa.x; a[1] = (_Float16)wa.y;
    a[2] = (_Float16)wa.z; a[3] = (_Float16)wa.w;
    a[4] = (_Float16)wb.x; a[5] = (_Float16)wb.y;
    a[6] = (_Float16)wb.z; a[7] = (_Float16)wb.w;
#pragma unroll
    for (int nt = 0; nt < 4; ++nt) {
      f16x8 bv = *(const f16x8*)(actT + (size_t)(nt * 16 + l15) * IN + k0 + q * 8);
      acc[nt] = __builtin_amdgcn_mfma_f32_16x16x32_f16(a, bv, acc[nt], 0, 0, 0);
    }
  }
#pragma unroll
  for (int nt = 0; nt < 4; ++nt)
#pragma unroll
    for (int reg = 0; reg < 4; ++reg)
      part[w][q * 4 + reg][nt * 16 + l15] = acc[nt][reg];
  __syncthreads();
  for (int e = tid; e < 1024; e += 256) {
    int m = e >> 6, n = e & 63;
    float sum = part[0][m][n] + part[1][m][n] + part[2][m][n] + part[3][m][n];
    int o = ob + m;
    if (o < 500) atomicAdd(&z1pre[o * 64 + n], sum);
  }
}

__global__ __launch_bounds__(256) void k_fc1ep(const float* __restrict__ z1pre,
                                               const float* __restrict__ bias,
                                               float* __restrict__ in2T) {
  int idx = blockIdx.x * 256 + threadIdx.x;
  if (idx >= 500 * 64) return;
  int o = idx >> 6;
  float v = z1pre[idx] + bias[o];
  in2T[idx + 64 * 64] = v > 0.f ? v : 0.f;
}

__global__ __launch_bounds__(256) void k_fc_small(const float* __restrict__ inT,
                                                  const float* __restrict__ wgt,
                                                  const float* __restrict__ bias,
                                                  float* __restrict__ out,
                                                  int IN, int mode) {
  __shared__ float part[4][64];
  int o = blockIdx.x;
  int lane = threadIdx.x & 63, w = threadIdx.x >> 6;
  float acc = 0.f;
  for (int i = w; i < IN; i += 4)
    acc = fmaf(inT[(size_t)i * 64 + lane], wgt[(size_t)o * IN + i], acc);
  part[w][lane] = acc;
  __syncthreads();
  if (threadIdx.x < 64) {
    float s = part[0][lane] + part[1][lane] + part[2][lane] + part[3][lane] + bias[o];
    if (mode == 0) {
      s = s > 0.f ? s : 0.f;
      out[(64 + o) * 64 + lane] = s;
    } else {
      out[lane * 2 + o] = s;
    }
  }
}

// ============================================================================
extern "C" void kernel_launch(void* const* d_in, const int* in_sizes, int n_in,
                              void* d_out, int out_size, void* d_ws, size_t ws_size,
                              hipStream_t stream) {
  const float* x      = (const float*)d_in[0];
  const float* qvec   = (const float*)d_in[1];
  const float* basis  = (const float*)d_in[2];
  const float* w1a    = (const float*)d_in[3];
  const float* g1a    = (const float*)d_in[5];
  const float* be1a   = (const float*)d_in[6];
  const float* w1b    = (const float*)d_in[7];
  const float* g1b    = (const float*)d_in[9];
  const float* be1b   = (const float*)d_in[10];
  const float* w2a    = (const float*)d_in[11];
  const float* g2a    = (const float*)d_in[13];
  const float* be2a   = (const float*)d_in[14];
  const float* w3a    = (const float*)d_in[15];
  const float* g3a    = (const float*)d_in[17];
  const float* be3a   = (const float*)d_in[18];
  const float* fc1w   = (const float*)d_in[19];
  const float* fc1b   = (const float*)d_in[20];
  const float* fc2w   = (const float*)d_in[21];
  const float* fc2b   = (const float*)d_in[22];
  const float* fc3w   = (const float*)d_in[23];
  const float* fc3b   = (const float*)d_in[24];
  float* out = (float*)d_out;

  char* base = (char*)d_ws;
  constexpr size_t ARENA = 62914560;
  char* arenaA = base;
  char* arenaB = base + ARENA;
  char* sm     = base + 2 * ARENA;

  float*          xd   = (float*)arenaA;
  unsigned short* A    = (unsigned short*)arenaA;  // pre1a NHWC [64][120][64][64] (raw)
  unsigned short* P1   = (unsigned short*)arenaA;  // [64][60][32][64]
  unsigned short* P2   = (unsigned short*)arenaA;  // [64][30][16][128]
  unsigned short* actT = (unsigned short*)arenaA;  // [64][30784] fp16

  float*          feat = (float*)arenaB;           // [64][120][64] fp32
  unsigned short* Bb   = (unsigned short*)arenaB;  // pre1b [64][120][64][64]
  unsigned short* C2   = (unsigned short*)arenaB;  // [64][60][32][128]
  unsigned short* D3   = (unsigned short*)arenaB;  // [64][30][16][256]

  float* in2T = (float*)sm;                    // 144,384 B
  float* in3T = (float*)(sm + 144384);         // 144,384 B
  float* z1p  = (float*)(sm + 288768);         // 128,000 B
  float* ACC  = (float*)(sm + 416768);         // 4,096 B
  float* S1A  = (float*)(sm + 420864);
  float* S1B  = (float*)(sm + 421376);
  float* S2A  = (float*)(sm + 421888);
  float* S3A  = (float*)(sm + 422912);
  unsigned short* WT1 = (unsigned short*)(sm + 424960);   // 204,800 B
  unsigned short* WT2 = (unsigned short*)(sm + 834560);   // 409,600 B
  unsigned short* WT3 = (unsigned short*)(sm + 1653760);  // 1,638,400 B

  k_qinit<<<130, 256, 0, stream>>>(qvec, actT, in2T, in3T, z1p, ACC);
  k_prepw<<<400, 256, 0, stream>>>(w1b, WT1, 64, 64);
  k_prepw<<<800, 256, 0, stream>>>(w2a, WT2, 128, 64);
  k_prepw<<<3200, 256, 0, stream>>>(w3a, WT3, 256, 128);

  k_dct<<<64 * 8, 256, 0, stream>>>(x, basis, xd);
  k_hist<<<4096, 256, 0, stream>>>(xd, feat);

  // conv1a (direct) -> A (raw pre-activations), stats over A
  k_conv1a<<<dim3(32, 64, 8), 256, 0, stream>>>(feat, w1a, A);
  k_bnstatsv<64><<<240, 256, 0, stream>>>(A, ACC, 64);
  k_bnfin<<<1, 64, 0, stream>>>(ACC, S1A, 64, 1.f / 491520.f);

  // conv1b (MFMA, TC=32: 8x32 tiles, LDS 34560 => 4 blocks/CU) -> Bb
  k_convM<64, 120, 64, 32, 4, 64, true><<<dim3(30, 64, 1), 256, 0, stream>>>(
      A, WT1, Bb, S1A, g1a, be1a);
  k_bnstatsv<64><<<240, 256, 0, stream>>>(Bb, ACC + 128, 64);
  k_bnfin<<<1, 64, 0, stream>>>(ACC + 128, S1B, 64, 1.f / 491520.f);
  k_brp<64, 120, 64><<<3840, 256, 0, stream>>>(Bb, P1, S1B, g1b, be1b);

  // conv2a -> C2, stats, pool -> P2
  k_convM<64, 60, 32, 32, 4, 128, false><<<dim3(8, 64, 2), 256, 0, stream>>>(
      P1, WT2, C2, S1A, g1a, be1a);
  k_bnstatsv<128><<<240, 256, 0, stream>>>(C2, ACC + 256, 32);
  k_bnfin<<<1, 128, 0, stream>>>(ACC + 256, S2A, 128, 1.f / 122880.f);
  k_brp<128, 60, 32><<<1920, 256, 0, stream>>>(C2, P2, S2A, g2a, be2a);

  // conv3a (NT=2 => 1024 blocks, LDS 19200) -> D3
  k_convM<128, 30, 16, 16, 2, 256, false><<<dim3(4, 64, 4), 256, 0, stream>>>(
      P2, WT3, D3, S1A, g1a, be1a);
  k_bnstatsv<256><<<240, 256, 0, stream>>>(D3, ACC + 512, 16);
  k_bnfin<<<1, 256, 0, stream>>>(ACC + 512, S3A, 256, 1.f / 30720.f);
  k_qinit<<<130, 256, 0, stream>>>(qvec, actT, in2T, in3T, z1p, ACC);
  k_brp3t<<<120, 256, 0, stream>>>(D3, actT, S3A, g3a, be3a);

  // FC head
  k_fc1m<<<dim3(32, 8), 256, 0, stream>>>(actT, fc1w, z1p);
  k_fc1ep<<<125, 256, 0, stream>>>(z1p, fc1b, in2T);
  k_fc_small<<<500, 256, 0, stream>>>(in2T, fc2w, fc2b, in3T, 564, 0);
  k_fc_small<<<2, 256, 0, stream>>>(in3T, fc3w, fc3b, out, 564, 1);
}

// Round 8
// 889.337 us; speedup vs baseline: 1.2252x; 1.0377x over previous
//
#include <hip/hip_runtime.h>
#include <math.h>

// ============================================================================
// DoubleJpeg round 15 (base = round-14, 922.8us):
//  - conv1b reverted to W=64 full-width tiles (TC=64): r7 proved the 8x32
//    tile regresses (190 vs 158us: FETCH +40MB, WRITE 2x, occupancy flat —
//    L2-sector-hostile write pattern; occupancy thesis falsified at every
//    register budget: r4 244us @(256,4), r7 190us @(256,3), W=64 158us).
//  - keep: k_hist bucket-count rewrite (confirmed ~-40us, absmax unchanged),
//    launch_bounds(256,3) everywhere (r5: stops 64-reg allocator squeeze),
//    conv3a NT=2 grid(4,64,4).
// ============================================================================

typedef __attribute__((ext_vector_type(8))) _Float16 f16x8;
typedef __attribute__((ext_vector_type(4))) float f32x4;

#define GAMMA_F 1.0e6f

__device__ __forceinline__ unsigned short f2h(float f) {
  _Float16 h = (_Float16)f;
  union { _Float16 h; unsigned short u; } x; x.h = h; return x.u;
}
__device__ __forceinline__ float h2f(unsigned short u) {
  union { unsigned short u; _Float16 h; } x; x.u = u; return (float)x.h;
}

// ---------------------------------------------------------------- DCT kernel
__global__ __launch_bounds__(256) void k_dct(const float* __restrict__ x,
                                             const float* __restrict__ basis,
                                             float* __restrict__ xd) {
  __shared__ float bT[4096];
  __shared__ float pix[4][64];
  int tid = threadIdx.x;
  for (int e = tid; e < 4096; e += 256)
    bT[e] = basis[(e & 63) * 64 + (e >> 6)];
  __syncthreads();
  int w = tid >> 6, lane = tid & 63;
  int b = blockIdx.x >> 3;
  int br = ((blockIdx.x & 7) << 2) + w;
  const float* xb = x + (size_t)b * 65536;
  float* xdb = xd + (size_t)b * 65536;
  for (int bc = 0; bc < 32; ++bc) {
    __syncthreads();
    pix[w][lane] = xb[(br * 8 + (lane >> 3)) * 256 + bc * 8 + (lane & 7)];
    __syncthreads();
    float acc = 0.f;
#pragma unroll
    for (int p = 0; p < 64; ++p)
      acc = fmaf(bT[p * 64 + lane], pix[w][p], acc);
    xdb[lane * 1024 + br * 32 + bc] = acc;
  }
}

// ---------------- soft histogram via bucket count + boundary sigmoid -> feat
// feat[b][j][c] = tot[j]-tot[j+1] = soft-count of px in (j-60, j-59].
// Hard bucket j = ceil(px+60)-1 for px not within 2e-5 of an integer
// (sigmoid(1e6*d) is exactly 0/1 in fp32 there); near-integer px splits
// (1-s)/s across the two adjacent buckets with s = sigmoid(1e6*(px-v)).
__global__ __launch_bounds__(256) void k_hist(const float* __restrict__ xd,
                                              float* __restrict__ feat) {
  __shared__ float h[120];
  int tid = threadIdx.x;
  int bc = blockIdx.x;
  int b = bc >> 6, c = bc & 63;
  if (tid < 120) h[tid] = 0.f;
  __syncthreads();
  const float4* p4 = (const float4*)(xd + (size_t)bc * 1024);
  float4 v4 = p4[tid];
#pragma unroll
  for (int k = 0; k < 4; ++k) {
    float pv = k == 0 ? v4.x : (k == 1 ? v4.y : (k == 2 ? v4.z : v4.w));
    float v = rintf(pv);
    float d = pv - v;
    if (fabsf(d) < 2e-5f && v >= -60.f && v <= 60.f) {
      float s = 1.f / (1.f + expf(-GAMMA_F * d));
      int vi = (int)v;
      if (vi >= -59) atomicAdd(&h[vi + 59], 1.f - s);
      if (vi <= 59)  atomicAdd(&h[vi + 60], s);
    } else {
      int j = (int)ceilf(pv + 60.f) - 1;
      if (j >= 0 && j <= 119) atomicAdd(&h[j], 1.f);
    }
  }
  __syncthreads();
  if (tid < 120)
    feat[((size_t)b * 120 + tid) * 64 + c] = h[tid] * (1.f / 1024.f);
}

// --------------- weight prep: fp32 -> fp16, fragment-major layout
// out: wt[((t*(OC/16)+mt)*(IC/32)+icb)*512 + l15*32 + q*8 + j]
//    = w[oc=mt*16+l15][ic=icb*32+q*8+j][t]
__global__ __launch_bounds__(256) void k_prepw(const float* __restrict__ w,
                                               unsigned short* __restrict__ wt,
                                               int OC, int IC) {
  int n = OC * IC * 25;
  int idx = blockIdx.x * 256 + threadIdx.x;
  if (idx >= n) return;
  int j = idx & 7;
  int q = (idx >> 3) & 3;
  int l15 = (idx >> 5) & 15;
  int r = idx >> 9;
  int icb = r % (IC / 32);
  int r2 = r / (IC / 32);
  int mt = r2 % (OC / 16);
  int t = r2 / (OC / 16);
  int oc = mt * 16 + l15;
  int ic = icb * 32 + q * 8 + j;
  wt[idx] = f2h(w[((size_t)oc * IC + ic) * 25 + t]);
}

// ----------------------------------------------- conv1a (CIN=1), direct fp32
__global__ __launch_bounds__(256) void k_conv1a(const float* __restrict__ in,
                                                const float* __restrict__ wgt,
                                                unsigned short* __restrict__ out) {
  __shared__ float tile[20 * 21];
  int tx = threadIdx.x & 15, ty = threadIdx.x >> 4;
  int tileX = (blockIdx.x & 3) * 16, tileY = (blockIdx.x >> 2) * 16;
  int b = blockIdx.y, ocb = blockIdx.z * 8;
  const float* inc = in + (size_t)b * 7680;
  for (int e = threadIdx.x; e < 400; e += 256) {
    int ly = e / 20, lx = e % 20;
    int gy = tileY - 2 + ly, gx = tileX - 2 + lx;
    float v = 0.f;
    if ((unsigned)gy < 120u && (unsigned)gx < 64u) v = inc[gy * 64 + gx];
    tile[ly * 21 + lx] = v;
  }
  __syncthreads();
  float tv[25];
#pragma unroll
  for (int dy = 0; dy < 5; ++dy)
#pragma unroll
    for (int dx = 0; dx < 5; ++dx)
      tv[dy * 5 + dx] = tile[(ty + dy) * 21 + tx + dx];
  float acc[8];
#pragma unroll
  for (int o = 0; o < 8; ++o) {
    const float* wo = wgt + (size_t)(ocb + o) * 25;
    float a = 0.f;
#pragma unroll
    for (int t = 0; t < 25; ++t) a = fmaf(tv[t], wo[t], a);
    acc[o] = a;
  }
  int oy = tileY + ty, ox = tileX + tx;
  if (oy < 120) {
    size_t base = (((size_t)b * 120 + oy) * 64 + ox) * 64 + ocb;
    ushort4 p0, p1;
    p0.x = f2h(acc[0]); p0.y = f2h(acc[1]); p0.z = f2h(acc[2]); p0.w = f2h(acc[3]);
    p1.x = f2h(acc[4]); p1.y = f2h(acc[5]); p1.z = f2h(acc[6]); p1.w = f2h(acc[7]);
    *(ushort4*)(out + base) = p0;
    *(ushort4*)(out + base + 4) = p1;
  }
}

// ---------------------------------------------- MFMA implicit-GEMM 5x5 conv
// NHWC fp16. Wave: 4 M-tiles (64 oc) x NT N-tiles (16 px each).
// Block covers WGR rows x TC cols (grid.x = ceil(H/WGR)*(W/TC)).
// LDS: 80B slot per pixel (slot=px*5+q4): B-reads (5px+q)%8 injective ->
// conflict-free; addresses fold to ds offset immediates.
// launch_bounds(256,3): ~170-reg budget — (256,4) was the r2-r4 spill trigger.
// TC < W regresses (r7): use TC=W (full-width tiles) for all instantiations.
template <int CIN, int H, int W, int TC, int NT, int OC, bool PREBN>
__global__ __launch_bounds__(256, 3) void k_convM(const unsigned short* __restrict__ in,
                                                  const unsigned short* __restrict__ wt,
                                                  unsigned short* __restrict__ out,
                                                  const float* __restrict__ pst,
                                                  const float* __restrict__ pg,
                                                  const float* __restrict__ pbe) {
  constexpr int XC = TC / 16, RPW = NT / XC, WGR = 4 * RPW;
  constexpr int LW = TC + 4, LR = WGR + 4, NPX = LR * LW;
  constexpr int NXC = W / TC;
  constexpr int MTS = (CIN / 32) * 512;       // per-mt frag stride (halfwords)
  constexpr int TS = (OC / 16) * MTS;         // per-tap frag stride
  __shared__ unsigned short lds[NPX * 40];    // 80B per pixel
  int tid = threadIdx.x;
  int w = tid >> 6, lane = tid & 63, l15 = lane & 15, q = lane >> 4;
  int q4 = tid & 3;
  int ry = blockIdx.x / NXC, cx = blockIdx.x % NXC;
  int y0 = ry * WGR, x0 = cx * TC;
  int b = blockIdx.y, oc0 = blockIdx.z * 64;
  int z4 = blockIdx.z * 4;
  int lofs = (l15 * 4 + q) * 8;
  f32x4 acc[4][NT];
#pragma unroll
  for (int mt = 0; mt < 4; ++mt)
#pragma unroll
    for (int nt = 0; nt < NT; ++nt) acc[mt][nt] = 0.f;

  for (int icb = 0; icb < CIN / 32; ++icb) {
    float s8[8], a8[8];
    if (PREBN) {
      int cb = icb * 32 + q4 * 8;
#pragma unroll
      for (int j = 0; j < 8; ++j) {
        float m = pst[cb + j], iv = pst[CIN + cb + j];
        s8[j] = pg[cb + j] * iv;
        a8[j] = pbe[cb + j] - m * s8[j];
      }
    }
    __syncthreads();
    for (int e = tid; e < NPX * 4; e += 256) {
      int px = e >> 2;                 // e&3 == q4 (invariant per thread)
      int lr = px / LW, c = px % LW;
      int y = y0 - 2 + lr, x = x0 - 2 + c;
      f16x8 v = (f16x8)0;
      if ((unsigned)y < (unsigned)H && (unsigned)x < (unsigned)W) {
        v = *(const f16x8*)(in + (((size_t)b * H + y) * W + x) * CIN + icb * 32 + q4 * 8);
        if (PREBN) {
#pragma unroll
          for (int j = 0; j < 8; ++j) {
            float f = fmaf((float)v[j], s8[j], a8[j]);
            v[j] = (_Float16)(f > 0.f ? f : 0.f);
          }
        }
      }
      *(f16x8*)&lds[(size_t)(px * 5 + q4) * 8] = v;
    }
    __syncthreads();
    const unsigned short* wbase = wt + (size_t)icb * 512 + lofs;
    f16x8 avn[4];
#pragma unroll
    for (int mt = 0; mt < 4; ++mt)
      avn[mt] = *(const f16x8*)(wbase + (size_t)(z4 + mt) * MTS);
#pragma unroll
    for (int t = 0; t < 25; ++t) {
      int dy = t / 5, dx = t % 5;
      f16x8 avc[4];
#pragma unroll
      for (int mt = 0; mt < 4; ++mt) avc[mt] = avn[mt];
      if (t < 24) {
#pragma unroll
        for (int mt = 0; mt < 4; ++mt)
          avn[mt] = *(const f16x8*)(wbase + (size_t)(t + 1) * TS + (size_t)(z4 + mt) * MTS);
      }
#pragma unroll
      for (int nt = 0; nt < NT; ++nt) {
        int lr = w * RPW + nt / XC + dy;
        int c = (nt % XC) * 16 + l15 + dx;
        f16x8 bv = *(const f16x8*)&lds[(size_t)((lr * LW + c) * 5 + q) * 8];
#pragma unroll
        for (int mt = 0; mt < 4; ++mt)
          acc[mt][nt] = __builtin_amdgcn_mfma_f32_16x16x32_f16(avc[mt], bv, acc[mt][nt], 0, 0, 0);
      }
    }
  }
#pragma unroll
  for (int nt = 0; nt < NT; ++nt) {
    int y = y0 + w * RPW + nt / XC;
    if (y >= H) continue;
    int x = x0 + (nt % XC) * 16 + l15;
    size_t pbase = (((size_t)b * H + y) * W + x) * OC + oc0 + q * 4;
#pragma unroll
    for (int mt = 0; mt < 4; ++mt) {
      ushort4 pk;
      pk.x = f2h(acc[mt][nt][0]);
      pk.y = f2h(acc[mt][nt][1]);
      pk.z = f2h(acc[mt][nt][2]);
      pk.w = f2h(acc[mt][nt][3]);
      *(ushort4*)(out + pbase + mt * 16) = pk;
    }
  }
}

// ------------------- BN stats, vectorized f16x8 (fully coalesced 1KB/wave)
template <int C>
__global__ __launch_bounds__(256) void k_bnstatsv(const unsigned short* __restrict__ x,
                                                  float* __restrict__ acc,
                                                  int nIter) {
  constexpr int CV = C / 8, KPB = 256 / CV;
  __shared__ float r1[256][8], r2[256][8];
  int tid = threadIdx.x;
  int cv = tid % CV, kq = tid / CV;
  size_t row0 = (size_t)blockIdx.x * (KPB * nIter) + kq;
  const unsigned short* p = x + row0 * C + cv * 8;
  float s1[8], s2[8];
#pragma unroll
  for (int j = 0; j < 8; ++j) { s1[j] = 0.f; s2[j] = 0.f; }
  for (int it = 0; it < nIter; ++it) {
    f16x8 v = *(const f16x8*)(p + (size_t)it * KPB * C);
#pragma unroll
    for (int j = 0; j < 8; ++j) {
      float f = (float)v[j];
      s1[j] += f;
      s2[j] += f * f;
    }
  }
#pragma unroll
  for (int j = 0; j < 8; ++j) { r1[tid][j] = s1[j]; r2[tid][j] = s2[j]; }
  __syncthreads();
  if (tid < C) {
    int cv0 = tid >> 3, e = tid & 7;
    float t1 = 0.f, t2 = 0.f;
    for (int k = 0; k < KPB; ++k) {
      t1 += r1[k * CV + cv0][e];
      t2 += r2[k * CV + cv0][e];
    }
    atomicAdd(&acc[tid], t1);
    atomicAdd(&acc[C + tid], t2);
  }
}

__global__ __launch_bounds__(256) void k_bnfin(const float* __restrict__ acc,
                                               float* __restrict__ stats,
                                               int C, float invN) {
  int c = threadIdx.x + blockIdx.x * 256;
  if (c >= C) return;
  float m = acc[c] * invN;
  float v = acc[C + c] * invN - m * m;
  stats[c] = m;
  stats[C + c] = rsqrtf(v + 1e-5f);
}

// --------------------------------------- BN+ReLU+maxpool2 NHWC (x8 vec)
template <int C, int H, int W>
__global__ __launch_bounds__(256) void k_brp(const unsigned short* __restrict__ x,
                                             unsigned short* __restrict__ y,
                                             const float* __restrict__ stats,
                                             const float* __restrict__ g,
                                             const float* __restrict__ be) {
  constexpr int OH = H / 2, OW = W / 2, CV = C / 8;
  int idx = blockIdx.x * 256 + threadIdx.x;   // [b][oy][ox][cv]
  int cv = idx % CV;
  int t = idx / CV;
  int ox = t % OW; t /= OW;
  int oy = t % OH;
  int b = t / OH;
  int c0 = cv * 8;
  const unsigned short* p = x + ((size_t)(b * H + oy * 2) * W + ox * 2) * C + c0;
  f16x8 v00 = *(const f16x8*)p;
  f16x8 v01 = *(const f16x8*)(p + C);
  f16x8 v10 = *(const f16x8*)(p + (size_t)W * C);
  f16x8 v11 = *(const f16x8*)(p + (size_t)W * C + C);
  f16x8 r;
#pragma unroll
  for (int j = 0; j < 8; ++j) {
    int c = c0 + j;
    float m = stats[c], iv = stats[C + c], gg = g[c], bb = be[c];
    float f0 = gg * (((float)v00[j] - m) * iv) + bb;
    float f1 = gg * (((float)v01[j] - m) * iv) + bb;
    float f2 = gg * (((float)v10[j] - m) * iv) + bb;
    float f3 = gg * (((float)v11[j] - m) * iv) + bb;
    f0 = f0 > 0.f ? f0 : 0.f;
    f1 = f1 > 0.f ? f1 : 0.f;
    f2 = f2 > 0.f ? f2 : 0.f;
    f3 = f3 > 0.f ? f3 : 0.f;
    float r01 = f0 > f1 ? f0 : f1;
    float r23 = f2 > f3 ? f2 : f3;
    r[j] = (_Float16)(r01 > r23 ? r01 : r23);
  }
  *(f16x8*)(y + (size_t)idx * 8) = r;
}

// ---- stage-3 BN+ReLU+pool + write into batch-major fc1 activations (fp16)
__global__ __launch_bounds__(256) void k_brp3t(const unsigned short* __restrict__ x,
                                               unsigned short* __restrict__ actT,
                                               const float* __restrict__ stats,
                                               const float* __restrict__ g,
                                               const float* __restrict__ be) {
  __shared__ float tile[64 * 65];
  int s = blockIdx.x;
  int oy = s >> 3, ox = s & 7;
  int ci = threadIdx.x & 63, bq = threadIdx.x >> 6;
  for (int cs = 0; cs < 4; ++cs) {
    int c = cs * 64 + ci;
    float m = stats[c], iv = stats[256 + c], gg = g[c], bb = be[c];
    __syncthreads();
    for (int b = bq; b < 64; b += 4) {
      float mx = 0.f;
#pragma unroll
      for (int qq = 0; qq < 4; ++qq) {
        int yy = oy * 2 + (qq >> 1), xx = ox * 2 + (qq & 1);
        float v = h2f(x[((size_t)(b * 30 + yy) * 16 + xx) * 256 + c]);
        v = gg * ((v - m) * iv) + bb;
        v = v > 0.f ? v : 0.f;
        mx = v > mx ? v : mx;
      }
      tile[ci * 65 + b] = mx;
    }
    __syncthreads();
    for (int e = threadIdx.x; e < 4096; e += 256) {
      int cc = e >> 6, bb2 = e & 63;
      actT[(size_t)bb2 * 30784 + 64 + (cs * 64 + cc) * 120 + s] = f2h(tile[cc * 65 + bb2]);
    }
  }
}

// -------------------- q rows of fc inputs + zero fc1 accumulator + BN accums
__global__ __launch_bounds__(256) void k_qinit(const float* __restrict__ q,
                                               unsigned short* __restrict__ actT,
                                               float* __restrict__ in2T,
                                               float* __restrict__ in3T,
                                               float* __restrict__ z1pre,
                                               float* __restrict__ bnacc) {
  int idx = blockIdx.x * 256 + threadIdx.x;
  if (idx < 32000) z1pre[idx] = 0.f;
  else if (idx < 33024) bnacc[idx - 32000] = 0.f;
  if (idx >= 4096) return;
  int b = idx >> 6, i = idx & 63;
  float v = q[idx];
  actT[(size_t)b * 30784 + i] = f2h(v);
  in2T[i * 64 + b] = v;
  in3T[i * 64 + b] = v;
}

// --------------------------------------------------------- fc1 (MFMA GEMM)
__global__ __launch_bounds__(256) void k_fc1m(const unsigned short* __restrict__ actT,
                                              const float* __restrict__ wgt,
                                              float* __restrict__ z1pre) {
  constexpr int IN = 30784;
  constexpr int KSTEPS = IN / 32;   // 962
  __shared__ float part[4][16][64];
  int tid = threadIdx.x;
  int w = tid >> 6, lane = tid & 63, l15 = lane & 15, q = lane >> 4;
  int ob = blockIdx.x * 16;
  int row = ob + l15; if (row > 499) row = 499;
  int kw = blockIdx.y * 4 + w;      // 0..31
  f32x4 acc[4];
#pragma unroll
  for (int nt = 0; nt < 4; ++nt) acc[nt] = 0.f;
  for (int s = kw; s < KSTEPS; s += 32) {
    int k0 = s * 32;
    const float4* wp = (const float4*)(wgt + (size_t)row * IN + k0 + q * 8);
    float4 wa = wp[0], wb = wp[1];
    f16x8 a;
    a[0] = (_Float16)wa.x; a[1] = (_Float16)wa.y;
    a[2] = (_Float16)wa.z; a[3] = (_Float16)wa.w;
    a[4] = (_Float16)wb.x; a[5] = (_Float16)wb.y;
    a[6] = (_Float16)wb.z; a[7] = (_Float16)wb.w;
#pragma unroll
    for (int nt = 0; nt < 4; ++nt) {
      f16x8 bv = *(const f16x8*)(actT + (size_t)(nt * 16 + l15) * IN + k0 + q * 8);
      acc[nt] = __builtin_amdgcn_mfma_f32_16x16x32_f16(a, bv, acc[nt], 0, 0, 0);
    }
  }
#pragma unroll
  for (int nt = 0; nt < 4; ++nt)
#pragma unroll
    for (int reg = 0; reg < 4; ++reg)
      part[w][q * 4 + reg][nt * 16 + l15] = acc[nt][reg];
  __syncthreads();
  for (int e = tid; e < 1024; e += 256) {
    int m = e >> 6, n = e & 63;
    float sum = part[0][m][n] + part[1][m][n] + part[2][m][n] + part[3][m][n];
    int o = ob + m;
    if (o < 500) atomicAdd(&z1pre[o * 64 + n], sum);
  }
}

__global__ __launch_bounds__(256) void k_fc1ep(const float* __restrict__ z1pre,
                                               const float* __restrict__ bias,
                                               float* __restrict__ in2T) {
  int idx = blockIdx.x * 256 + threadIdx.x;
  if (idx >= 500 * 64) return;
  int o = idx >> 6;
  float v = z1pre[idx] + bias[o];
  in2T[idx + 64 * 64] = v > 0.f ? v : 0.f;
}

__global__ __launch_bounds__(256) void k_fc_small(const float* __restrict__ inT,
                                                  const float* __restrict__ wgt,
                                                  const float* __restrict__ bias,
                                                  float* __restrict__ out,
                                                  int IN, int mode) {
  __shared__ float part[4][64];
  int o = blockIdx.x;
  int lane = threadIdx.x & 63, w = threadIdx.x >> 6;
  float acc = 0.f;
  for (int i = w; i < IN; i += 4)
    acc = fmaf(inT[(size_t)i * 64 + lane], wgt[(size_t)o * IN + i], acc);
  part[w][lane] = acc;
  __syncthreads();
  if (threadIdx.x < 64) {
    float s = part[0][lane] + part[1][lane] + part[2][lane] + part[3][lane] + bias[o];
    if (mode == 0) {
      s = s > 0.f ? s : 0.f;
      out[(64 + o) * 64 + lane] = s;
    } else {
      out[lane * 2 + o] = s;
    }
  }
}

// ============================================================================
extern "C" void kernel_launch(void* const* d_in, const int* in_sizes, int n_in,
                              void* d_out, int out_size, void* d_ws, size_t ws_size,
                              hipStream_t stream) {
  const float* x      = (const float*)d_in[0];
  const float* qvec   = (const float*)d_in[1];
  const float* basis  = (const float*)d_in[2];
  const float* w1a    = (const float*)d_in[3];
  const float* g1a    = (const float*)d_in[5];
  const float* be1a   = (const float*)d_in[6];
  const float* w1b    = (const float*)d_in[7];
  const float* g1b    = (const float*)d_in[9];
  const float* be1b   = (const float*)d_in[10];
  const float* w2a    = (const float*)d_in[11];
  const float* g2a    = (const float*)d_in[13];
  const float* be2a   = (const float*)d_in[14];
  const float* w3a    = (const float*)d_in[15];
  const float* g3a    = (const float*)d_in[17];
  const float* be3a   = (const float*)d_in[18];
  const float* fc1w   = (const float*)d_in[19];
  const float* fc1b   = (const float*)d_in[20];
  const float* fc2w   = (const float*)d_in[21];
  const float* fc2b   = (const float*)d_in[22];
  const float* fc3w   = (const float*)d_in[23];
  const float* fc3b   = (const float*)d_in[24];
  float* out = (float*)d_out;

  char* base = (char*)d_ws;
  constexpr size_t ARENA = 62914560;
  char* arenaA = base;
  char* arenaB = base + ARENA;
  char* sm     = base + 2 * ARENA;

  float*          xd   = (float*)arenaA;
  unsigned short* A    = (unsigned short*)arenaA;  // pre1a NHWC [64][120][64][64] (raw)
  unsigned short* P1   = (unsigned short*)arenaA;  // [64][60][32][64]
  unsigned short* P2   = (unsigned short*)arenaA;  // [64][30][16][128]
  unsigned short* actT = (unsigned short*)arenaA;  // [64][30784] fp16

  float*          feat = (float*)arenaB;           // [64][120][64] fp32
  unsigned short* Bb   = (unsigned short*)arenaB;  // pre1b [64][120][64][64]
  unsigned short* C2   = (unsigned short*)arenaB;  // [64][60][32][128]
  unsigned short* D3   = (unsigned short*)arenaB;  // [64][30][16][256]

  float* in2T = (float*)sm;                    // 144,384 B
  float* in3T = (float*)(sm + 144384);         // 144,384 B
  float* z1p  = (float*)(sm + 288768);         // 128,000 B
  float* ACC  = (float*)(sm + 416768);         // 4,096 B
  float* S1A  = (float*)(sm + 420864);
  float* S1B  = (float*)(sm + 421376);
  float* S2A  = (float*)(sm + 421888);
  float* S3A  = (float*)(sm + 422912);
  unsigned short* WT1 = (unsigned short*)(sm + 424960);   // 204,800 B
  unsigned short* WT2 = (unsigned short*)(sm + 834560);   // 409,600 B
  unsigned short* WT3 = (unsigned short*)(sm + 1653760);  // 1,638,400 B

  k_qinit<<<130, 256, 0, stream>>>(qvec, actT, in2T, in3T, z1p, ACC);
  k_prepw<<<400, 256, 0, stream>>>(w1b, WT1, 64, 64);
  k_prepw<<<800, 256, 0, stream>>>(w2a, WT2, 128, 64);
  k_prepw<<<3200, 256, 0, stream>>>(w3a, WT3, 256, 128);

  k_dct<<<64 * 8, 256, 0, stream>>>(x, basis, xd);
  k_hist<<<4096, 256, 0, stream>>>(xd, feat);

  // conv1a (direct) -> A (raw pre-activations), stats over A
  k_conv1a<<<dim3(32, 64, 8), 256, 0, stream>>>(feat, w1a, A);
  k_bnstatsv<64><<<240, 256, 0, stream>>>(A, ACC, 64);
  k_bnfin<<<1, 64, 0, stream>>>(ACC, S1A, 64, 1.f / 491520.f);

  // conv1b (MFMA, W=64 full-width tiles — r7 proved TC<W regresses) -> Bb
  k_convM<64, 120, 64, 64, 4, 64, true><<<dim3(30, 64, 1), 256, 0, stream>>>(
      A, WT1, Bb, S1A, g1a, be1a);
  k_bnstatsv<64><<<240, 256, 0, stream>>>(Bb, ACC + 128, 64);
  k_bnfin<<<1, 64, 0, stream>>>(ACC + 128, S1B, 64, 1.f / 491520.f);
  k_brp<64, 120, 64><<<3840, 256, 0, stream>>>(Bb, P1, S1B, g1b, be1b);

  // conv2a -> C2, stats, pool -> P2
  k_convM<64, 60, 32, 32, 4, 128, false><<<dim3(8, 64, 2), 256, 0, stream>>>(
      P1, WT2, C2, S1A, g1a, be1a);
  k_bnstatsv<128><<<240, 256, 0, stream>>>(C2, ACC + 256, 32);
  k_bnfin<<<1, 128, 0, stream>>>(ACC + 256, S2A, 128, 1.f / 122880.f);
  k_brp<128, 60, 32><<<1920, 256, 0, stream>>>(C2, P2, S2A, g2a, be2a);

  // conv3a (NT=2 => 1024 blocks, LDS 19200) -> D3
  k_convM<128, 30, 16, 16, 2, 256, false><<<dim3(4, 64, 4), 256, 0, stream>>>(
      P2, WT3, D3, S1A, g1a, be1a);
  k_bnstatsv<256><<<240, 256, 0, stream>>>(D3, ACC + 512, 16);
  k_bnfin<<<1, 256, 0, stream>>>(ACC + 512, S3A, 256, 1.f / 30720.f);
  k_qinit<<<130, 256, 0, stream>>>(qvec, actT, in2T, in3T, z1p, ACC);
  k_brp3t<<<120, 256, 0, stream>>>(D3, actT, S3A, g3a, be3a);

  // FC head
  k_fc1m<<<dim3(32, 8), 256, 0, stream>>>(actT, fc1w, z1p);
  k_fc1ep<<<125, 256, 0, stream>>>(z1p, fc1b, in2T);
  k_fc_small<<<500, 256, 0, stream>>>(in2T, fc2w, fc2b, in3T, 564, 0);
  k_fc_small<<<2, 256, 0, stream>>>(in3T, fc3w, fc3b, out, 564, 1);
}